// Round 5
// baseline (1587.375 us; speedup 1.0000x reference)
//
#include <hip/hip_runtime.h>
#include <cfloat>
#include <cstddef>
#include <climits>

// Problem constants
#define N_A   4096
#define N_B   4096
#define G_A   3000
#define G_B   3000
#define NCA   30
#define NCB   25
#define KNBR  20
#define KPAD  3072   // K/N padding for MFMA tiles (multiple of 128)
#define KMLP  6144   // padded MLP K ( = 2*KPAD )

typedef unsigned short u16;
typedef unsigned int u32;
typedef unsigned long long u64;
typedef __bf16 bf16x8 __attribute__((ext_vector_type(8)));
typedef float f32x4 __attribute__((ext_vector_type(4)));
typedef __attribute__((address_space(1))) const void* as1_cvp;
typedef __attribute__((address_space(3))) void* as3_vp;

static __device__ __forceinline__ u16 f2bf(float f) {
    union { float f; unsigned u; } v; v.f = f;
    unsigned r = v.u + 0x7fffu + ((v.u >> 16) & 1u);   // RTNE
    return (u16)(r >> 16);
}

// monotonic float -> u32 key (ascending float == ascending unsigned)
static __device__ __forceinline__ u32 fkey(float f) {
    union { float f; u32 u; } v; v.f = f;
    return (v.u & 0x80000000u) ? ~v.u : (v.u | 0x80000000u);
}

static __device__ __forceinline__ u64 shflxor64(u64 x, int m) {
    u32 lo = (u32)x, hi = (u32)(x >> 32);
    lo = __shfl_xor(lo, m, 64);
    hi = __shfl_xor(hi, m, 64);
    return ((u64)hi << 32) | lo;
}

// ---------------------------------------------------------------------------
// normalizers
__global__ __launch_bounds__(256) void row_sum_kernel(const float* __restrict__ G,
                                                      float* __restrict__ normA) {
    int row = blockIdx.x;
    __shared__ float red[256];
    float s = 0.f;
    for (int j = threadIdx.x; j < G_B; j += 256) s += G[(size_t)row * G_B + j];
    red[threadIdx.x] = s;
    __syncthreads();
    for (int off = 128; off > 0; off >>= 1) {
        if (threadIdx.x < off) red[threadIdx.x] += red[threadIdx.x + off];
        __syncthreads();
    }
    if (threadIdx.x == 0) {
        float v = red[0];
        normA[row] = (v == 0.f) ? 1.f : v;
    }
}

__global__ __launch_bounds__(256) void col_partial_kernel(const float* __restrict__ G,
                                                          float* __restrict__ part) {
    int j = blockIdx.x * 256 + threadIdx.x;
    if (j >= G_B) return;
    int r0 = blockIdx.y * 120;
    float s = 0.f;
    for (int i = r0; i < r0 + 120; ++i) s += G[(size_t)i * G_B + j];
    part[(size_t)blockIdx.y * G_B + j] = s;
}

__global__ __launch_bounds__(256) void col_final_kernel(const float* __restrict__ part,
                                                        float* __restrict__ normB) {
    int j = blockIdx.x * 256 + threadIdx.x;
    if (j >= G_B) return;
    float s = 0.f;
    for (int c = 0; c < 25; ++c) s += part[(size_t)c * G_B + j];
    normB[j] = (s == 0.f) ? 1.f : s;
}

// ---------------------------------------------------------------------------
// f32 -> bf16 convert with zero padding
__global__ __launch_bounds__(256) void convert_pad_kernel(const float* __restrict__ in,
                                                          u16* __restrict__ out,
                                                          int in_rows, int in_cols,
                                                          int out_cols) {
    int idx = blockIdx.x * 256 + threadIdx.x;
    int cpr = out_cols >> 3;
    int r = idx / cpr, c0 = (idx % cpr) << 3;
    u16 res[8] = {0, 0, 0, 0, 0, 0, 0, 0};
    if (r < in_rows && c0 + 8 <= in_cols) {
        float4 v0 = *(const float4*)(in + (size_t)r * in_cols + c0);
        float4 v1 = *(const float4*)(in + (size_t)r * in_cols + c0 + 4);
        res[0] = f2bf(v0.x); res[1] = f2bf(v0.y); res[2] = f2bf(v0.z); res[3] = f2bf(v0.w);
        res[4] = f2bf(v1.x); res[5] = f2bf(v1.y); res[6] = f2bf(v1.z); res[7] = f2bf(v1.w);
    }
    uint4 pack;
    pack.x = (unsigned)res[0] | ((unsigned)res[1] << 16);
    pack.y = (unsigned)res[2] | ((unsigned)res[3] << 16);
    pack.z = (unsigned)res[4] | ((unsigned)res[5] << 16);
    pack.w = (unsigned)res[6] | ((unsigned)res[7] << 16);
    *(uint4*)(out + (size_t)r * out_cols + c0) = pack;
}

// Gt[j][k] = bf16(G[k][j]) padded to [KPAD][KPAD]
__global__ __launch_bounds__(256) void transpose_convert_kernel(const float* __restrict__ G,
                                                                u16* __restrict__ Gt) {
    __shared__ float t[32][33];
    int j0 = blockIdx.x * 32, k0 = blockIdx.y * 32;
    int lx = threadIdx.x & 31, ly = threadIdx.x >> 5;
#pragma unroll
    for (int i = 0; i < 4; ++i) {
        int k = k0 + ly + i * 8, j = j0 + lx;
        t[ly + i * 8][lx] = (k < G_A && j < G_B) ? G[(size_t)k * G_B + j] : 0.f;
    }
    __syncthreads();
#pragma unroll
    for (int i = 0; i < 4; ++i) {
        int j = j0 + ly + i * 8, k = k0 + lx;
        Gt[(size_t)j * KPAD + k] = f2bf(t[lx][ly + i * 8]);
    }
}

// W1 [6000][64] f32 -> W1t [64][KMLP] bf16
__global__ __launch_bounds__(256) void w1t_kernel(const float* __restrict__ W1,
                                                  u16* __restrict__ W1t) {
    int idx = blockIdx.x * 256 + threadIdx.x;
    int n = idx / KMLP, kp = idx % KMLP;
    int seg = kp >= KPAD;
    int k = kp - (seg ? KPAD : 0);
    float v = (k < 3000) ? W1[(size_t)(seg * 3000 + k) * 64 + n] : 0.f;
    W1t[(size_t)n * KMLP + kp] = f2bf(v);
}

// ---------------------------------------------------------------------------
// bf16 MFMA GEMM: out[i][j] = (sum_k A[i][k] * Bt[j][k]) / norm[j]
__global__ __launch_bounds__(256) void mfma_impute_gemm(const u16* __restrict__ A,
                                                        const u16* __restrict__ Bt,
                                                        const float* __restrict__ norm,
                                                        float* __restrict__ out,
                                                        u16* __restrict__ outbf) {
    __shared__ __align__(16) u16 lAs[128 * 64];
    __shared__ __align__(16) u16 lBs[128 * 64];

    const int tid = threadIdx.x;
    const int w = tid >> 6, lane = tid & 63;
    const int row_base = blockIdx.y * 128;
    const int col_base = blockIdx.x * 128;
    const int wr = (w >> 1) * 64, wc = (w & 1) * 64;

    f32x4 acc[4][4] = {};

    int s_r[4], s_off[4];
#pragma unroll
    for (int i = 0; i < 4; ++i) {
        int slin = (w * 4 + i) * 64 + lane;
        int r = slin >> 3, s = slin & 7;
        s_r[i] = r;
        s_off[i] = (s ^ (r & 7)) * 8;
    }

    for (int k0 = 0; k0 < KPAD; k0 += 64) {
#pragma unroll
        for (int i = 0; i < 4; ++i) {
            const u16* ga = A + (size_t)(row_base + s_r[i]) * KPAD + k0 + s_off[i];
            __builtin_amdgcn_global_load_lds((as1_cvp)ga,
                (as3_vp)(lAs + (size_t)(w * 4 + i) * 512), 16, 0, 0);
        }
#pragma unroll
        for (int i = 0; i < 4; ++i) {
            const u16* gb = Bt + (size_t)(col_base + s_r[i]) * KPAD + k0 + s_off[i];
            __builtin_amdgcn_global_load_lds((as1_cvp)gb,
                (as3_vp)(lBs + (size_t)(w * 4 + i) * 512), 16, 0, 0);
        }
        __syncthreads();

#pragma unroll
        for (int kk = 0; kk < 2; ++kk) {
            bf16x8 a[4], b[4];
#pragma unroll
            for (int m = 0; m < 4; ++m) {
                int row = wr + m * 16 + (lane & 15);
                int slot = (kk * 4 + (lane >> 4)) ^ (row & 7);
                a[m] = *(const bf16x8*)(lAs + row * 64 + slot * 8);
            }
#pragma unroll
            for (int n = 0; n < 4; ++n) {
                int row = wc + n * 16 + (lane & 15);
                int slot = (kk * 4 + (lane >> 4)) ^ (row & 7);
                b[n] = *(const bf16x8*)(lBs + row * 64 + slot * 8);
            }
#pragma unroll
            for (int m = 0; m < 4; ++m)
#pragma unroll
                for (int n = 0; n < 4; ++n)
                    acc[m][n] = __builtin_amdgcn_mfma_f32_16x16x32_bf16(a[m], b[n], acc[m][n], 0, 0, 0);
        }
        __syncthreads();
    }

#pragma unroll
    for (int n = 0; n < 4; ++n) {
        int col = col_base + wc + n * 16 + (lane & 15);
        bool valid = col < G_B;
        float rn = valid ? 1.0f / norm[col] : 0.f;
#pragma unroll
        for (int m = 0; m < 4; ++m) {
            int row = row_base + wr + m * 16 + (lane >> 4) * 4;
#pragma unroll
            for (int r = 0; r < 4; ++r) {
                float v = acc[m][n][r] * rn;
                if (valid) out[(size_t)(row + r) * G_B + col] = v;
                outbf[(size_t)(row + r) * KPAD + col] = f2bf(v);
            }
        }
    }
}

// ---------------------------------------------------------------------------
// MLP layer 1 (bf16 MFMA, K-split)
__global__ __launch_bounds__(256) void mlp1_kernel(const u16* __restrict__ xAbf,
                                                   const u16* __restrict__ ximpAbf,
                                                   const u16* __restrict__ ximpBbf,
                                                   const u16* __restrict__ xBbf,
                                                   const u16* __restrict__ W1t,
                                                   float* __restrict__ partial) {
    const int chunk = blockIdx.x;
    const int rb = blockIdx.y;
    const int side = rb >> 6;
    const int r0 = (rb & 63) * 64;
    const int seg = chunk >> 1;
    const u16* src = side ? (seg ? xBbf : ximpBbf) : (seg ? ximpAbf : xAbf);
    const int k0base = (chunk & 1) * 1536;

    __shared__ __align__(16) u16 lAs[64 * 64];
    __shared__ __align__(16) u16 lBs[64 * 64];

    const int tid = threadIdx.x;
    const int w = tid >> 6, lane = tid & 63;

    int s_r[2], s_off[2];
#pragma unroll
    for (int i = 0; i < 2; ++i) {
        int slin = (w * 2 + i) * 64 + lane;
        int r = slin >> 3, s = slin & 7;
        s_r[i] = r;
        s_off[i] = (s ^ (r & 7)) * 8;
    }

    f32x4 acc[4] = {};

    for (int k0 = 0; k0 < 1536; k0 += 64) {
#pragma unroll
        for (int i = 0; i < 2; ++i) {
            const u16* ga = src + (size_t)(r0 + s_r[i]) * KPAD + k0base + k0 + s_off[i];
            __builtin_amdgcn_global_load_lds((as1_cvp)ga,
                (as3_vp)(lAs + (size_t)(w * 2 + i) * 512), 16, 0, 0);
        }
#pragma unroll
        for (int i = 0; i < 2; ++i) {
            const u16* gb = W1t + (size_t)s_r[i] * KMLP + chunk * 1536 + k0 + s_off[i];
            __builtin_amdgcn_global_load_lds((as1_cvp)gb,
                (as3_vp)(lBs + (size_t)(w * 2 + i) * 512), 16, 0, 0);
        }
        __syncthreads();

#pragma unroll
        for (int kk = 0; kk < 2; ++kk) {
            int arow = w * 16 + (lane & 15);
            int aslot = (kk * 4 + (lane >> 4)) ^ (arow & 7);
            bf16x8 a = *(const bf16x8*)(lAs + arow * 64 + aslot * 8);
#pragma unroll
            for (int n = 0; n < 4; ++n) {
                int brow = n * 16 + (lane & 15);
                int bslot = (kk * 4 + (lane >> 4)) ^ (brow & 7);
                bf16x8 b = *(const bf16x8*)(lBs + brow * 64 + bslot * 8);
                acc[n] = __builtin_amdgcn_mfma_f32_16x16x32_bf16(a, b, acc[n], 0, 0, 0);
            }
        }
        __syncthreads();
    }

    const size_t grow0 = (size_t)rb * 64;
#pragma unroll
    for (int n = 0; n < 4; ++n) {
        int col = n * 16 + (lane & 15);
        int rowl = w * 16 + (lane >> 4) * 4;
#pragma unroll
        for (int r = 0; r < 4; ++r)
            partial[((size_t)chunk * 8192 + grow0 + rowl + r) * 64 + col] = acc[n][r];
    }
}

// MLP reduce + layer 2 + fused sqnorm
__global__ __launch_bounds__(256) void mlp2_kernel(const float* __restrict__ partial,
                                                   const float* __restrict__ b1,
                                                   const float* __restrict__ W2,
                                                   const float* __restrict__ b2,
                                                   float* __restrict__ embA,
                                                   float* __restrict__ embB,
                                                   float* __restrict__ sqA,
                                                   float* __restrict__ sqB) {
    const int rb = blockIdx.x;
    const int side = rb >> 6;
    const size_t grow0 = (size_t)rb * 64;
    const int r0 = (rb & 63) * 64;
    float* emb = side ? embB : embA;
    float* sq = side ? sqB : sqA;

    __shared__ float Hs[64][65];
    __shared__ float W2s[64][32];
    const int tid = threadIdx.x;

    {
        const float4* srcw = (const float4*)W2;
        float4* dst = (float4*)&W2s[0][0];
        for (int i = tid; i < 512; i += 256) dst[i] = srcw[i];
    }

    for (int v = tid; v < 1024; v += 256) {
        int row = v >> 4, c4 = v & 15;
        float4 s = {0.f, 0.f, 0.f, 0.f};
#pragma unroll
        for (int c = 0; c < 4; ++c) {
            const float4 p = *(const float4*)(partial + ((size_t)c * 8192 + grow0 + row) * 64 + c4 * 4);
            s.x += p.x; s.y += p.y; s.z += p.z; s.w += p.w;
        }
        const float4 bb = *(const float4*)(b1 + c4 * 4);
        Hs[row][c4 * 4 + 0] = fmaxf(s.x + bb.x, 0.f);
        Hs[row][c4 * 4 + 1] = fmaxf(s.y + bb.y, 0.f);
        Hs[row][c4 * 4 + 2] = fmaxf(s.z + bb.z, 0.f);
        Hs[row][c4 * 4 + 3] = fmaxf(s.w + bb.w, 0.f);
    }
    __syncthreads();

    const int c2 = tid & 31, rg = tid >> 5;
    float acc2[8] = {};
    for (int k = 0; k < 64; ++k) {
        float wv = W2s[k][c2];
#pragma unroll
        for (int i = 0; i < 8; ++i) acc2[i] += Hs[rg * 8 + i][k] * wv;
    }
    float bb = b2[c2];
    float e[8];
#pragma unroll
    for (int i = 0; i < 8; ++i) {
        e[i] = fmaxf(acc2[i] + bb, 0.f);
        emb[(size_t)(r0 + rg * 8 + i) * 32 + c2] = e[i];
    }
#pragma unroll
    for (int i = 0; i < 8; ++i) {
        float v = e[i] * e[i];
#pragma unroll
        for (int off = 16; off > 0; off >>= 1) v += __shfl_xor(v, off, 32);
        if (c2 == 0) sq[r0 + rg * 8 + i] = v;
    }
}

// ---------------------------------------------------------------------------
// Fallback f32 GEMM
template <bool TRANSB>
__global__ __launch_bounds__(256) void impute_gemm(const float* __restrict__ X,
                                                   const float* __restrict__ G,
                                                   const float* __restrict__ norm,
                                                   float* __restrict__ out) {
    __shared__ float As[8][128];
    __shared__ float Bs[8][128];
    const int tid = threadIdx.x;
    const int col_base = blockIdx.x * 128;
    const int row_base = blockIdx.y * 128;
    const int tx = tid & 15;
    const int ty = tid >> 4;
    float acc[8][8] = {};
    const int a_row = tid >> 1;
    const int a_k   = (tid & 1) * 4;
    for (int k0 = 0; k0 < G_B; k0 += 8) {
        {
            float4 av = *(const float4*)(X + (size_t)(row_base + a_row) * G_B + k0 + a_k);
            As[a_k + 0][a_row] = av.x;
            As[a_k + 1][a_row] = av.y;
            As[a_k + 2][a_row] = av.z;
            As[a_k + 3][a_row] = av.w;
        }
        if (!TRANSB) {
            const int bk = tid >> 5;
            const int bc = (tid & 31) * 4;
            float4 bv = {0.f, 0.f, 0.f, 0.f};
            if (col_base + bc < G_B)
                bv = *(const float4*)(G + (size_t)(k0 + bk) * G_B + col_base + bc);
            *(float4*)&Bs[bk][bc] = bv;
        } else {
            const int bj = tid >> 1;
            const int bk = (tid & 1) * 4;
            float4 bv = {0.f, 0.f, 0.f, 0.f};
            if (col_base + bj < G_B)
                bv = *(const float4*)(G + (size_t)(col_base + bj) * G_B + k0 + bk);
            Bs[bk + 0][bj] = bv.x;
            Bs[bk + 1][bj] = bv.y;
            Bs[bk + 2][bj] = bv.z;
            Bs[bk + 3][bj] = bv.w;
        }
        __syncthreads();
#pragma unroll
        for (int kk = 0; kk < 8; ++kk) {
            float4 a0 = *(const float4*)&As[kk][ty * 8];
            float4 a1 = *(const float4*)&As[kk][ty * 8 + 4];
            float4 b0 = *(const float4*)&Bs[kk][tx * 8];
            float4 b1 = *(const float4*)&Bs[kk][tx * 8 + 4];
            float a_[8] = {a0.x, a0.y, a0.z, a0.w, a1.x, a1.y, a1.z, a1.w};
            float b_[8] = {b0.x, b0.y, b0.z, b0.w, b1.x, b1.y, b1.z, b1.w};
#pragma unroll
            for (int i = 0; i < 8; ++i)
#pragma unroll
                for (int j = 0; j < 8; ++j) acc[i][j] += a_[i] * b_[j];
        }
        __syncthreads();
    }
    const int cg = col_base + tx * 8;
    if (cg < G_B) {
        float rn[8];
#pragma unroll
        for (int j = 0; j < 8; ++j) rn[j] = 1.0f / norm[cg + j];
#pragma unroll
        for (int i = 0; i < 8; ++i) {
            float4 o0 = {acc[i][0] * rn[0], acc[i][1] * rn[1], acc[i][2] * rn[2], acc[i][3] * rn[3]};
            float4 o1 = {acc[i][4] * rn[4], acc[i][5] * rn[5], acc[i][6] * rn[6], acc[i][7] * rn[7]};
            size_t o = (size_t)(row_base + ty * 8 + i) * G_B + cg;
            *(float4*)(out + o) = o0;
            *(float4*)(out + o + 4) = o1;
        }
    }
}

// Fallback MLP (f32)
#define MLP_TK 24
__global__ __launch_bounds__(256) void mlp_kernel(const float* __restrict__ xA,
                                                  const float* __restrict__ ximpA,
                                                  const float* __restrict__ ximpB,
                                                  const float* __restrict__ xB,
                                                  const float* __restrict__ W1,
                                                  const float* __restrict__ b1,
                                                  const float* __restrict__ W2,
                                                  const float* __restrict__ b2,
                                                  float* __restrict__ embA,
                                                  float* __restrict__ embB) {
    __shared__ float Xs[MLP_TK][64];
    __shared__ float Ws[MLP_TK][64];
    __shared__ float Hs[64][65];
    __shared__ float W2s[64][32];

    const int side = blockIdx.x >> 6;
    const int row0 = (blockIdx.x & 63) * 64;
    const float* srcL = side ? ximpB : xA;
    const float* srcR = side ? xB : ximpA;
    float* emb = side ? embB : embA;

    const int tid = threadIdx.x;
    {
        const float4* src = (const float4*)W2;
        float4* dst = (float4*)&W2s[0][0];
        for (int i = tid; i < 512; i += 256) dst[i] = src[i];
    }

    const int tx = tid & 15;
    const int ty = tid >> 4;
    float acc[4][4] = {};
    const int lrow = tid >> 2;
    const int lk6  = (tid & 3) * 6;

    for (int k0 = 0; k0 < 6000; k0 += MLP_TK) {
        const float* src = (k0 < 3000) ? srcL : srcR;
        const int kbase = (k0 < 3000) ? k0 : (k0 - 3000);
        {
            const float* p = src + (size_t)(row0 + lrow) * 3000 + kbase + lk6;
#pragma unroll
            for (int e = 0; e < 6; ++e) Xs[lk6 + e][lrow] = p[e];
        }
        {
#pragma unroll
            for (int e = 0; e < 6; ++e) {
                int idx = tid * 6 + e;
                int kk = idx >> 6, cc = idx & 63;
                Ws[kk][cc] = W1[(size_t)(k0 + kk) * 64 + cc];
            }
        }
        __syncthreads();
#pragma unroll
        for (int kk = 0; kk < MLP_TK; ++kk) {
            float4 a = *(const float4*)&Xs[kk][ty * 4];
            float4 wv = *(const float4*)&Ws[kk][tx * 4];
            float a_[4] = {a.x, a.y, a.z, a.w};
            float w_[4] = {wv.x, wv.y, wv.z, wv.w};
#pragma unroll
            for (int i = 0; i < 4; ++i)
#pragma unroll
                for (int j = 0; j < 4; ++j) acc[i][j] += a_[i] * w_[j];
        }
        __syncthreads();
    }

#pragma unroll
    for (int j = 0; j < 4; ++j) {
        float bj = b1[tx * 4 + j];
#pragma unroll
        for (int i = 0; i < 4; ++i) {
            float h = acc[i][j] + bj;
            Hs[ty * 4 + i][tx * 4 + j] = h > 0.f ? h : 0.f;
        }
    }
    __syncthreads();

    const int c2 = tid & 31;
    const int rg = tid >> 5;
    float acc2[8] = {};
    for (int k = 0; k < 64; ++k) {
        float wv = W2s[k][c2];
#pragma unroll
        for (int i = 0; i < 8; ++i) acc2[i] += Hs[rg * 8 + i][k] * wv;
    }
    float bb = b2[c2];
#pragma unroll
    for (int i = 0; i < 8; ++i) {
        float h = acc2[i] + bb;
        emb[(size_t)(row0 + rg * 8 + i) * 32 + c2] = h > 0.f ? h : 0.f;
    }
}

__global__ __launch_bounds__(256) void sqnorm_kernel(const float* __restrict__ emb,
                                                     float* __restrict__ sq) {
    int i = blockIdx.x * 256 + threadIdx.x;
    if (i >= N_A) return;
    const float4* e = (const float4*)(emb + (size_t)i * 32);
    float s = 0.f;
#pragma unroll
    for (int q = 0; q < 8; ++q) {
        float4 v = e[q];
        s += v.x * v.x + v.y * v.y + v.z * v.z + v.w * v.w;
    }
    sq[i] = s;
}

__global__ __launch_bounds__(256) void preds_kernel(const float* __restrict__ emb,
                                                    const float* __restrict__ Wc,
                                                    const float* __restrict__ bc,
                                                    float* __restrict__ out,
                                                    int ncls) {
    int idx = blockIdx.x * 256 + threadIdx.x;
    int row = idx / ncls, c = idx % ncls;
    const float* e = emb + (size_t)row * 32;
    float s = bc[c];
#pragma unroll
    for (int k = 0; k < 32; ++k) s += e[k] * Wc[k * ncls + c];
    out[idx] = s;
}

// ---------------------------------------------------------------------------
// Fused d2 + top-20 via register-resident tournament select.
// Each thread holds 16 candidates packed as u64 ((fkey(d2)<<12)|j) and a
// running register min. 20 rounds of {wave shfl-min + 1 barrier cross-wave
// merge}; the unique winner clears its slot (static-indexed) and recomputes.
// Ordering written = ascending (d2, j) — identical to reference top_k ties.
// grid = 8192: blocks 0..4095 -> A-side queries, 4096..8191 -> B-side.
__global__ __launch_bounds__(256) void topk_all_kernel(const float* __restrict__ embA,
                                                       const float* __restrict__ sqA,
                                                       const float* __restrict__ embB,
                                                       const float* __restrict__ sqB,
                                                       int* __restrict__ nnA,
                                                       int* __restrict__ nnB) {
    const int side = blockIdx.x >> 12;
    const int q = blockIdx.x & 4095;
    const float* embQ = side ? embB : embA;
    const float* sqQ  = side ? sqB : sqA;
    const float* embC = side ? embA : embB;
    const float* sqC  = side ? sqA : sqB;
    int* nn = (side ? nnB : nnA) + (size_t)q * KNBR;

    const int tid = threadIdx.x;
    const int lane = tid & 63, w = tid >> 6;

    __shared__ u64 wmin[2][4];

    // ---- compute phase: 16 candidates per thread, packed keys in registers
    float4 qv[8];
    const float4* eq = (const float4*)(embQ + (size_t)q * 32);
#pragma unroll
    for (int t = 0; t < 8; ++t) qv[t] = eq[t];
    float sqq = sqQ[q];

    u64 pk[16];
#pragma unroll
    for (int i = 0; i < 16; ++i) {
        int j = tid + (i << 8);
        const float4* ec = (const float4*)(embC + (size_t)j * 32);
        float dot = 0.f;
#pragma unroll
        for (int t = 0; t < 8; ++t) {
            float4 c = ec[t];
            dot += qv[t].x * c.x + qv[t].y * c.y + qv[t].z * c.z + qv[t].w * c.w;
        }
        pk[i] = ((u64)fkey(sqq + sqC[j] - 2.f * dot) << 12) | (u32)j;
    }

    u64 lmin = pk[0];
#pragma unroll
    for (int i = 1; i < 16; ++i) lmin = pk[i] < lmin ? pk[i] : lmin;

    // ---- 20 tournament rounds, 1 barrier each
    int cur = 0;
    for (int r = 0; r < KNBR; ++r) {
        u64 v = lmin;
#pragma unroll
        for (int off = 1; off < 64; off <<= 1) {
            u64 o = shflxor64(v, off);
            v = o < v ? o : v;
        }
        if (lane == 0) wmin[cur][w] = v;
        __syncthreads();
        u64 gm = wmin[cur][0];
#pragma unroll
        for (int k = 1; k < 4; ++k) { u64 t = wmin[cur][k]; gm = t < gm ? t : gm; }
        if (tid == 0) nn[r] = (int)(gm & 0xFFFu);
        if (lmin == gm) {
            // unique winner: clear slot (static indexing), recompute register min
#pragma unroll
            for (int i = 0; i < 16; ++i) if (pk[i] == gm) pk[i] = ~0ull;
            lmin = pk[0];
#pragma unroll
            for (int i = 1; i < 16; ++i) lmin = pk[i] < lmin ? pk[i] : lmin;
        }
        cur ^= 1;
    }
}

// ---------------------------------------------------------------------------
__global__ __launch_bounds__(256) void predloss_kernel(const int* __restrict__ nn,
                                                       const float* __restrict__ ximp,
                                                       const float* __restrict__ xtrue,
                                                       float* __restrict__ partial) {
    int q = blockIdx.x;
    __shared__ int nns[KNBR];
    __shared__ float red[256];
    if (threadIdx.x < KNBR) nns[threadIdx.x] = nn[(size_t)q * KNBR + threadIdx.x];
    __syncthreads();

    int nr[KNBR];
#pragma unroll
    for (int t = 0; t < KNBR; ++t) nr[t] = nns[t];

    const float inv = 1.0f / KNBR;
    float sse = 0.f;
    for (int v = threadIdx.x; v < 750; v += 256) {
        float4 acc = {0.f, 0.f, 0.f, 0.f};
#pragma unroll
        for (int t = 0; t < KNBR; ++t) {
            const float4 w = *(const float4*)(ximp + (size_t)nr[t] * 3000 + v * 4);
            acc.x += w.x; acc.y += w.y; acc.z += w.z; acc.w += w.w;
        }
        const float4 xt = *(const float4*)(xtrue + (size_t)q * 3000 + v * 4);
        float dx = acc.x * inv - xt.x;
        float dy = acc.y * inv - xt.y;
        float dz = acc.z * inv - xt.z;
        float dw = acc.w * inv - xt.w;
        sse += dx * dx + dy * dy + dz * dz + dw * dw;
    }
    red[threadIdx.x] = sse;
    __syncthreads();
    for (int off = 128; off > 0; off >>= 1) {
        if (threadIdx.x < off) red[threadIdx.x] += red[threadIdx.x + off];
        __syncthreads();
    }
    if (threadIdx.x == 0) partial[q] = red[0];
}

__global__ __launch_bounds__(256) void loss_final_kernel(const float* __restrict__ pA,
                                                         const float* __restrict__ pB,
                                                         float* __restrict__ out) {
    __shared__ double red[256];
    double sa = 0.0, sb = 0.0;
    for (int i = threadIdx.x; i < 4096; i += 256) {
        sa += (double)pA[i];
        sb += (double)pB[i];
    }
    red[threadIdx.x] = sa;
    __syncthreads();
    for (int off = 128; off > 0; off >>= 1) {
        if (threadIdx.x < off) red[threadIdx.x] += red[threadIdx.x + off];
        __syncthreads();
    }
    double totA = red[0];
    __syncthreads();
    red[threadIdx.x] = sb;
    __syncthreads();
    for (int off = 128; off > 0; off >>= 1) {
        if (threadIdx.x < off) red[threadIdx.x] += red[threadIdx.x + off];
        __syncthreads();
    }
    if (threadIdx.x == 0) {
        double denom = 4096.0 * 3000.0;
        out[0] = (float)(totA / denom + red[0] / denom);
    }
}

// ---------------------------------------------------------------------------
extern "C" void kernel_launch(void* const* d_in, const int* in_sizes, int n_in,
                              void* d_out, int out_size, void* d_ws, size_t ws_size,
                              hipStream_t stream) {
    const float* x_A = (const float*)d_in[0];
    const float* x_B = (const float*)d_in[1];
    const float* G   = (const float*)d_in[2];
    const float* W1  = (const float*)d_in[3];
    const float* b1  = (const float*)d_in[4];
    const float* W2  = (const float*)d_in[5];
    const float* b2  = (const float*)d_in[6];
    const float* WcA = (const float*)d_in[7];
    const float* bcA = (const float*)d_in[8];
    const float* WcB = (const float*)d_in[9];
    const float* bcB = (const float*)d_in[10];

    float* outp = (float*)d_out;

    size_t off = 0;
    char* base = (char*)d_ws;
    auto carve = [&](size_t bytes) -> void* {
        void* p = base + off;
        off = (off + bytes + 255) & ~(size_t)255;
        return p;
    };
    float* ximpA = (float*)carve((size_t)N_A * G_B * 4);
    float* ximpB = (float*)carve((size_t)N_B * G_A * 4);
    float* normA = (float*)carve(G_A * 4);
    float* normB = (float*)carve(G_B * 4);
    float* colpart = (float*)carve(25 * G_B * 4);
    float* embA = (float*)carve((size_t)N_A * 32 * 4);
    float* embB = (float*)carve((size_t)N_B * 32 * 4);
    float* sqA = (float*)carve(N_A * 4);
    float* sqB = (float*)carve(N_B * 4);
    float* partA = (float*)carve(N_A * 4);
    float* partB = (float*)carve(N_B * 4);
    int* nnA = (int*)carve((size_t)N_A * KNBR * 4);
    int* nnB = (int*)carve((size_t)N_B * KNBR * 4);
    u16* xAbf = (u16*)carve((size_t)N_A * KPAD * 2);
    u16* xBbf = (u16*)carve((size_t)N_B * KPAD * 2);
    u16* Gbf  = (u16*)carve((size_t)KPAD * KPAD * 2);
    u16* Gtbf = (u16*)carve((size_t)KPAD * KPAD * 2);
    size_t r2_needed = off;
    u16* ximpAbf = (u16*)carve((size_t)N_A * KPAD * 2);
    u16* ximpBbf = (u16*)carve((size_t)N_B * KPAD * 2);
    u16* W1tbf   = (u16*)carve((size_t)64 * KMLP * 2);
    float* mlppart = (float*)carve((size_t)4 * 8192 * 64 * 4);
    size_t full_needed = off;

    const bool use_mfma = (ws_size >= r2_needed);
    const bool use_mlp_mfma = (ws_size >= full_needed);

    // 1) normalizers
    row_sum_kernel<<<G_A, 256, 0, stream>>>(G, normA);
    col_partial_kernel<<<dim3(12, 25), 256, 0, stream>>>(G, colpart);
    col_final_kernel<<<12, 256, 0, stream>>>(colpart, normB);

    // 2) imputation GEMMs (+ bf16 copies)
    if (use_mfma && use_mlp_mfma) {
        convert_pad_kernel<<<(N_A * (KPAD / 8)) / 256, 256, 0, stream>>>(x_A, xAbf, N_A, G_A, KPAD);
        convert_pad_kernel<<<(N_B * (KPAD / 8)) / 256, 256, 0, stream>>>(x_B, xBbf, N_B, G_B, KPAD);
        convert_pad_kernel<<<(KPAD * (KPAD / 8)) / 256, 256, 0, stream>>>(G, Gbf, G_A, G_B, KPAD);
        transpose_convert_kernel<<<dim3(96, 96), 256, 0, stream>>>(G, Gtbf);
        w1t_kernel<<<(64 * KMLP) / 256, 256, 0, stream>>>(W1, W1tbf);

        dim3 ggrid(KPAD / 128, N_A / 128);
        mfma_impute_gemm<<<ggrid, 256, 0, stream>>>(xAbf, Gtbf, normB, ximpA, ximpAbf);
        mfma_impute_gemm<<<ggrid, 256, 0, stream>>>(xBbf, Gbf, normA, ximpB, ximpBbf);

        // 3) MLP via MFMA + K-split
        mlp1_kernel<<<dim3(4, 128), 256, 0, stream>>>(xAbf, ximpAbf, ximpBbf, xBbf, W1tbf, mlppart);
        mlp2_kernel<<<128, 256, 0, stream>>>(mlppart, b1, W2, b2, embA, embB, sqA, sqB);
    } else {
        dim3 ggrid(24, 32);
        impute_gemm<false><<<ggrid, 256, 0, stream>>>(x_A, G, normB, ximpA);
        impute_gemm<true><<<ggrid, 256, 0, stream>>>(x_B, G, normA, ximpB);
        mlp_kernel<<<128, 256, 0, stream>>>(x_A, ximpA, ximpB, x_B, W1, b1, W2, b2, embA, embB);
        sqnorm_kernel<<<16, 256, 0, stream>>>(embA, sqA);
        sqnorm_kernel<<<16, 256, 0, stream>>>(embB, sqB);
    }

    // 5) class predictions -> d_out
    preds_kernel<<<(N_A * NCA) / 256, 256, 0, stream>>>(embA, WcA, bcA, outp, NCA);
    preds_kernel<<<(N_B * NCB) / 256, 256, 0, stream>>>(embB, WcB, bcB, outp + (size_t)N_A * NCA, NCB);

    // 6) top-20 neighbors, both sides in one launch (tournament select)
    topk_all_kernel<<<8192, 256, 0, stream>>>(embA, sqA, embB, sqB, nnA, nnB);

    // 7) fused gather-mean + MSE partials
    predloss_kernel<<<N_A, 256, 0, stream>>>(nnA, ximpB, x_A, partA);
    predloss_kernel<<<N_B, 256, 0, stream>>>(nnB, ximpA, x_B, partB);

    // 8) final loss
    loss_final_kernel<<<1, 256, 0, stream>>>(partA, partB, outp + (size_t)N_A * NCA + (size_t)N_B * NCB);

    (void)in_sizes; (void)n_in; (void)out_size;
}

// Round 6
// 913.494 us; speedup vs baseline: 1.7377x; 1.7377x over previous
//
#include <hip/hip_runtime.h>
#include <cfloat>
#include <cstddef>
#include <climits>

// Problem constants
#define N_A   4096
#define N_B   4096
#define G_A   3000
#define G_B   3000
#define NCA   30
#define NCB   25
#define KNBR  20
#define KPAD  3072   // K/N padding for MFMA tiles (multiple of 128)
#define KMLP  6144   // padded MLP K ( = 2*KPAD )

typedef unsigned short u16;
typedef unsigned int u32;
typedef unsigned long long u64;
typedef __bf16 bf16x8 __attribute__((ext_vector_type(8)));
typedef float f32x4 __attribute__((ext_vector_type(4)));
typedef __attribute__((address_space(1))) const void* as1_cvp;
typedef __attribute__((address_space(3))) void* as3_vp;

static __device__ __forceinline__ u16 f2bf(float f) {
    union { float f; unsigned u; } v; v.f = f;
    unsigned r = v.u + 0x7fffu + ((v.u >> 16) & 1u);   // RTNE
    return (u16)(r >> 16);
}

// monotonic float -> u32 key (ascending float == ascending unsigned)
static __device__ __forceinline__ u32 fkey(float f) {
    union { float f; u32 u; } v; v.f = f;
    return (v.u & 0x80000000u) ? ~v.u : (v.u | 0x80000000u);
}

// 64-lane min-reduce via DPP (VALU, no LDS) + broadcast through readlane.
// row_shr 1/2/4/8 accumulate row minima at lanes 15/31/47/63; row_bcast15
// then row_bcast31 fold rows; lane 63 holds the global min.
static __device__ __forceinline__ u32 wave_min_u32_bcast(u32 v) {
    u32 t;
    t = (u32)__builtin_amdgcn_update_dpp((int)v, (int)v, 0x111, 0xf, 0xf, false); v = t < v ? t : v;
    t = (u32)__builtin_amdgcn_update_dpp((int)v, (int)v, 0x112, 0xf, 0xf, false); v = t < v ? t : v;
    t = (u32)__builtin_amdgcn_update_dpp((int)v, (int)v, 0x114, 0xf, 0xf, false); v = t < v ? t : v;
    t = (u32)__builtin_amdgcn_update_dpp((int)v, (int)v, 0x118, 0xf, 0xf, false); v = t < v ? t : v;
    t = (u32)__builtin_amdgcn_update_dpp((int)v, (int)v, 0x142, 0xf, 0xf, false); v = t < v ? t : v;
    t = (u32)__builtin_amdgcn_update_dpp((int)v, (int)v, 0x143, 0xf, 0xf, false); v = t < v ? t : v;
    return (u32)__builtin_amdgcn_readlane((int)v, 63);
}

// ---------------------------------------------------------------------------
// normalizers
__global__ __launch_bounds__(256) void row_sum_kernel(const float* __restrict__ G,
                                                      float* __restrict__ normA) {
    int row = blockIdx.x;
    __shared__ float red[256];
    float s = 0.f;
    for (int j = threadIdx.x; j < G_B; j += 256) s += G[(size_t)row * G_B + j];
    red[threadIdx.x] = s;
    __syncthreads();
    for (int off = 128; off > 0; off >>= 1) {
        if (threadIdx.x < off) red[threadIdx.x] += red[threadIdx.x + off];
        __syncthreads();
    }
    if (threadIdx.x == 0) {
        float v = red[0];
        normA[row] = (v == 0.f) ? 1.f : v;
    }
}

__global__ __launch_bounds__(256) void col_partial_kernel(const float* __restrict__ G,
                                                          float* __restrict__ part) {
    int j = blockIdx.x * 256 + threadIdx.x;
    if (j >= G_B) return;
    int r0 = blockIdx.y * 120;
    float s = 0.f;
    for (int i = r0; i < r0 + 120; ++i) s += G[(size_t)i * G_B + j];
    part[(size_t)blockIdx.y * G_B + j] = s;
}

__global__ __launch_bounds__(256) void col_final_kernel(const float* __restrict__ part,
                                                        float* __restrict__ normB) {
    int j = blockIdx.x * 256 + threadIdx.x;
    if (j >= G_B) return;
    float s = 0.f;
    for (int c = 0; c < 25; ++c) s += part[(size_t)c * G_B + j];
    normB[j] = (s == 0.f) ? 1.f : s;
}

// ---------------------------------------------------------------------------
// f32 -> bf16 convert with zero padding
__global__ __launch_bounds__(256) void convert_pad_kernel(const float* __restrict__ in,
                                                          u16* __restrict__ out,
                                                          int in_rows, int in_cols,
                                                          int out_cols) {
    int idx = blockIdx.x * 256 + threadIdx.x;
    int cpr = out_cols >> 3;
    int r = idx / cpr, c0 = (idx % cpr) << 3;
    u16 res[8] = {0, 0, 0, 0, 0, 0, 0, 0};
    if (r < in_rows && c0 + 8 <= in_cols) {
        float4 v0 = *(const float4*)(in + (size_t)r * in_cols + c0);
        float4 v1 = *(const float4*)(in + (size_t)r * in_cols + c0 + 4);
        res[0] = f2bf(v0.x); res[1] = f2bf(v0.y); res[2] = f2bf(v0.z); res[3] = f2bf(v0.w);
        res[4] = f2bf(v1.x); res[5] = f2bf(v1.y); res[6] = f2bf(v1.z); res[7] = f2bf(v1.w);
    }
    uint4 pack;
    pack.x = (unsigned)res[0] | ((unsigned)res[1] << 16);
    pack.y = (unsigned)res[2] | ((unsigned)res[3] << 16);
    pack.z = (unsigned)res[4] | ((unsigned)res[5] << 16);
    pack.w = (unsigned)res[6] | ((unsigned)res[7] << 16);
    *(uint4*)(out + (size_t)r * out_cols + c0) = pack;
}

// Gt[j][k] = bf16(G[k][j]) padded to [KPAD][KPAD]
__global__ __launch_bounds__(256) void transpose_convert_kernel(const float* __restrict__ G,
                                                                u16* __restrict__ Gt) {
    __shared__ float t[32][33];
    int j0 = blockIdx.x * 32, k0 = blockIdx.y * 32;
    int lx = threadIdx.x & 31, ly = threadIdx.x >> 5;
#pragma unroll
    for (int i = 0; i < 4; ++i) {
        int k = k0 + ly + i * 8, j = j0 + lx;
        t[ly + i * 8][lx] = (k < G_A && j < G_B) ? G[(size_t)k * G_B + j] : 0.f;
    }
    __syncthreads();
#pragma unroll
    for (int i = 0; i < 4; ++i) {
        int j = j0 + ly + i * 8, k = k0 + lx;
        Gt[(size_t)j * KPAD + k] = f2bf(t[lx][ly + i * 8]);
    }
}

// W1 [6000][64] f32 -> W1t [64][KMLP] bf16
__global__ __launch_bounds__(256) void w1t_kernel(const float* __restrict__ W1,
                                                  u16* __restrict__ W1t) {
    int idx = blockIdx.x * 256 + threadIdx.x;
    int n = idx / KMLP, kp = idx % KMLP;
    int seg = kp >= KPAD;
    int k = kp - (seg ? KPAD : 0);
    float v = (k < 3000) ? W1[(size_t)(seg * 3000 + k) * 64 + n] : 0.f;
    W1t[(size_t)n * KMLP + kp] = f2bf(v);
}

// ---------------------------------------------------------------------------
// bf16 MFMA GEMM: out[i][j] = (sum_k A[i][k] * Bt[j][k]) / norm[j]
__global__ __launch_bounds__(256) void mfma_impute_gemm(const u16* __restrict__ A,
                                                        const u16* __restrict__ Bt,
                                                        const float* __restrict__ norm,
                                                        float* __restrict__ out,
                                                        u16* __restrict__ outbf) {
    __shared__ __align__(16) u16 lAs[128 * 64];
    __shared__ __align__(16) u16 lBs[128 * 64];

    const int tid = threadIdx.x;
    const int w = tid >> 6, lane = tid & 63;
    const int row_base = blockIdx.y * 128;
    const int col_base = blockIdx.x * 128;
    const int wr = (w >> 1) * 64, wc = (w & 1) * 64;

    f32x4 acc[4][4] = {};

    int s_r[4], s_off[4];
#pragma unroll
    for (int i = 0; i < 4; ++i) {
        int slin = (w * 4 + i) * 64 + lane;
        int r = slin >> 3, s = slin & 7;
        s_r[i] = r;
        s_off[i] = (s ^ (r & 7)) * 8;
    }

    for (int k0 = 0; k0 < KPAD; k0 += 64) {
#pragma unroll
        for (int i = 0; i < 4; ++i) {
            const u16* ga = A + (size_t)(row_base + s_r[i]) * KPAD + k0 + s_off[i];
            __builtin_amdgcn_global_load_lds((as1_cvp)ga,
                (as3_vp)(lAs + (size_t)(w * 4 + i) * 512), 16, 0, 0);
        }
#pragma unroll
        for (int i = 0; i < 4; ++i) {
            const u16* gb = Bt + (size_t)(col_base + s_r[i]) * KPAD + k0 + s_off[i];
            __builtin_amdgcn_global_load_lds((as1_cvp)gb,
                (as3_vp)(lBs + (size_t)(w * 4 + i) * 512), 16, 0, 0);
        }
        __syncthreads();

#pragma unroll
        for (int kk = 0; kk < 2; ++kk) {
            bf16x8 a[4], b[4];
#pragma unroll
            for (int m = 0; m < 4; ++m) {
                int row = wr + m * 16 + (lane & 15);
                int slot = (kk * 4 + (lane >> 4)) ^ (row & 7);
                a[m] = *(const bf16x8*)(lAs + row * 64 + slot * 8);
            }
#pragma unroll
            for (int n = 0; n < 4; ++n) {
                int row = wc + n * 16 + (lane & 15);
                int slot = (kk * 4 + (lane >> 4)) ^ (row & 7);
                b[n] = *(const bf16x8*)(lBs + row * 64 + slot * 8);
            }
#pragma unroll
            for (int m = 0; m < 4; ++m)
#pragma unroll
                for (int n = 0; n < 4; ++n)
                    acc[m][n] = __builtin_amdgcn_mfma_f32_16x16x32_bf16(a[m], b[n], acc[m][n], 0, 0, 0);
        }
        __syncthreads();
    }

#pragma unroll
    for (int n = 0; n < 4; ++n) {
        int col = col_base + wc + n * 16 + (lane & 15);
        bool valid = col < G_B;
        float rn = valid ? 1.0f / norm[col] : 0.f;
#pragma unroll
        for (int m = 0; m < 4; ++m) {
            int row = row_base + wr + m * 16 + (lane >> 4) * 4;
#pragma unroll
            for (int r = 0; r < 4; ++r) {
                float v = acc[m][n][r] * rn;
                if (valid) out[(size_t)(row + r) * G_B + col] = v;
                outbf[(size_t)(row + r) * KPAD + col] = f2bf(v);
            }
        }
    }
}

// ---------------------------------------------------------------------------
// MLP layer 1 (bf16 MFMA, K-split)
__global__ __launch_bounds__(256) void mlp1_kernel(const u16* __restrict__ xAbf,
                                                   const u16* __restrict__ ximpAbf,
                                                   const u16* __restrict__ ximpBbf,
                                                   const u16* __restrict__ xBbf,
                                                   const u16* __restrict__ W1t,
                                                   float* __restrict__ partial) {
    const int chunk = blockIdx.x;
    const int rb = blockIdx.y;
    const int side = rb >> 6;
    const int r0 = (rb & 63) * 64;
    const int seg = chunk >> 1;
    const u16* src = side ? (seg ? xBbf : ximpBbf) : (seg ? ximpAbf : xAbf);
    const int k0base = (chunk & 1) * 1536;

    __shared__ __align__(16) u16 lAs[64 * 64];
    __shared__ __align__(16) u16 lBs[64 * 64];

    const int tid = threadIdx.x;
    const int w = tid >> 6, lane = tid & 63;

    int s_r[2], s_off[2];
#pragma unroll
    for (int i = 0; i < 2; ++i) {
        int slin = (w * 2 + i) * 64 + lane;
        int r = slin >> 3, s = slin & 7;
        s_r[i] = r;
        s_off[i] = (s ^ (r & 7)) * 8;
    }

    f32x4 acc[4] = {};

    for (int k0 = 0; k0 < 1536; k0 += 64) {
#pragma unroll
        for (int i = 0; i < 2; ++i) {
            const u16* ga = src + (size_t)(r0 + s_r[i]) * KPAD + k0base + k0 + s_off[i];
            __builtin_amdgcn_global_load_lds((as1_cvp)ga,
                (as3_vp)(lAs + (size_t)(w * 2 + i) * 512), 16, 0, 0);
        }
#pragma unroll
        for (int i = 0; i < 2; ++i) {
            const u16* gb = W1t + (size_t)s_r[i] * KMLP + chunk * 1536 + k0 + s_off[i];
            __builtin_amdgcn_global_load_lds((as1_cvp)gb,
                (as3_vp)(lBs + (size_t)(w * 2 + i) * 512), 16, 0, 0);
        }
        __syncthreads();

#pragma unroll
        for (int kk = 0; kk < 2; ++kk) {
            int arow = w * 16 + (lane & 15);
            int aslot = (kk * 4 + (lane >> 4)) ^ (arow & 7);
            bf16x8 a = *(const bf16x8*)(lAs + arow * 64 + aslot * 8);
#pragma unroll
            for (int n = 0; n < 4; ++n) {
                int brow = n * 16 + (lane & 15);
                int bslot = (kk * 4 + (lane >> 4)) ^ (brow & 7);
                bf16x8 b = *(const bf16x8*)(lBs + brow * 64 + bslot * 8);
                acc[n] = __builtin_amdgcn_mfma_f32_16x16x32_bf16(a, b, acc[n], 0, 0, 0);
            }
        }
        __syncthreads();
    }

    const size_t grow0 = (size_t)rb * 64;
#pragma unroll
    for (int n = 0; n < 4; ++n) {
        int col = n * 16 + (lane & 15);
        int rowl = w * 16 + (lane >> 4) * 4;
#pragma unroll
        for (int r = 0; r < 4; ++r)
            partial[((size_t)chunk * 8192 + grow0 + rowl + r) * 64 + col] = acc[n][r];
    }
}

// MLP reduce + layer 2 + fused sqnorm
__global__ __launch_bounds__(256) void mlp2_kernel(const float* __restrict__ partial,
                                                   const float* __restrict__ b1,
                                                   const float* __restrict__ W2,
                                                   const float* __restrict__ b2,
                                                   float* __restrict__ embA,
                                                   float* __restrict__ embB,
                                                   float* __restrict__ sqA,
                                                   float* __restrict__ sqB) {
    const int rb = blockIdx.x;
    const int side = rb >> 6;
    const size_t grow0 = (size_t)rb * 64;
    const int r0 = (rb & 63) * 64;
    float* emb = side ? embB : embA;
    float* sq = side ? sqB : sqA;

    __shared__ float Hs[64][65];
    __shared__ float W2s[64][32];
    const int tid = threadIdx.x;

    {
        const float4* srcw = (const float4*)W2;
        float4* dst = (float4*)&W2s[0][0];
        for (int i = tid; i < 512; i += 256) dst[i] = srcw[i];
    }

    for (int v = tid; v < 1024; v += 256) {
        int row = v >> 4, c4 = v & 15;
        float4 s = {0.f, 0.f, 0.f, 0.f};
#pragma unroll
        for (int c = 0; c < 4; ++c) {
            const float4 p = *(const float4*)(partial + ((size_t)c * 8192 + grow0 + row) * 64 + c4 * 4);
            s.x += p.x; s.y += p.y; s.z += p.z; s.w += p.w;
        }
        const float4 bb = *(const float4*)(b1 + c4 * 4);
        Hs[row][c4 * 4 + 0] = fmaxf(s.x + bb.x, 0.f);
        Hs[row][c4 * 4 + 1] = fmaxf(s.y + bb.y, 0.f);
        Hs[row][c4 * 4 + 2] = fmaxf(s.z + bb.z, 0.f);
        Hs[row][c4 * 4 + 3] = fmaxf(s.w + bb.w, 0.f);
    }
    __syncthreads();

    const int c2 = tid & 31, rg = tid >> 5;
    float acc2[8] = {};
    for (int k = 0; k < 64; ++k) {
        float wv = W2s[k][c2];
#pragma unroll
        for (int i = 0; i < 8; ++i) acc2[i] += Hs[rg * 8 + i][k] * wv;
    }
    float bb = b2[c2];
    float e[8];
#pragma unroll
    for (int i = 0; i < 8; ++i) {
        e[i] = fmaxf(acc2[i] + bb, 0.f);
        emb[(size_t)(r0 + rg * 8 + i) * 32 + c2] = e[i];
    }
#pragma unroll
    for (int i = 0; i < 8; ++i) {
        float v = e[i] * e[i];
#pragma unroll
        for (int off = 16; off > 0; off >>= 1) v += __shfl_xor(v, off, 32);
        if (c2 == 0) sq[r0 + rg * 8 + i] = v;
    }
}

// ---------------------------------------------------------------------------
// Fallback f32 GEMM
template <bool TRANSB>
__global__ __launch_bounds__(256) void impute_gemm(const float* __restrict__ X,
                                                   const float* __restrict__ G,
                                                   const float* __restrict__ norm,
                                                   float* __restrict__ out) {
    __shared__ float As[8][128];
    __shared__ float Bs[8][128];
    const int tid = threadIdx.x;
    const int col_base = blockIdx.x * 128;
    const int row_base = blockIdx.y * 128;
    const int tx = tid & 15;
    const int ty = tid >> 4;
    float acc[8][8] = {};
    const int a_row = tid >> 1;
    const int a_k   = (tid & 1) * 4;
    for (int k0 = 0; k0 < G_B; k0 += 8) {
        {
            float4 av = *(const float4*)(X + (size_t)(row_base + a_row) * G_B + k0 + a_k);
            As[a_k + 0][a_row] = av.x;
            As[a_k + 1][a_row] = av.y;
            As[a_k + 2][a_row] = av.z;
            As[a_k + 3][a_row] = av.w;
        }
        if (!TRANSB) {
            const int bk = tid >> 5;
            const int bc = (tid & 31) * 4;
            float4 bv = {0.f, 0.f, 0.f, 0.f};
            if (col_base + bc < G_B)
                bv = *(const float4*)(G + (size_t)(k0 + bk) * G_B + col_base + bc);
            *(float4*)&Bs[bk][bc] = bv;
        } else {
            const int bj = tid >> 1;
            const int bk = (tid & 1) * 4;
            float4 bv = {0.f, 0.f, 0.f, 0.f};
            if (col_base + bj < G_B)
                bv = *(const float4*)(G + (size_t)(col_base + bj) * G_B + k0 + bk);
            Bs[bk + 0][bj] = bv.x;
            Bs[bk + 1][bj] = bv.y;
            Bs[bk + 2][bj] = bv.z;
            Bs[bk + 3][bj] = bv.w;
        }
        __syncthreads();
#pragma unroll
        for (int kk = 0; kk < 8; ++kk) {
            float4 a0 = *(const float4*)&As[kk][ty * 8];
            float4 a1 = *(const float4*)&As[kk][ty * 8 + 4];
            float4 b0 = *(const float4*)&Bs[kk][tx * 8];
            float4 b1 = *(const float4*)&Bs[kk][tx * 8 + 4];
            float a_[8] = {a0.x, a0.y, a0.z, a0.w, a1.x, a1.y, a1.z, a1.w};
            float b_[8] = {b0.x, b0.y, b0.z, b0.w, b1.x, b1.y, b1.z, b1.w};
#pragma unroll
            for (int i = 0; i < 8; ++i)
#pragma unroll
                for (int j = 0; j < 8; ++j) acc[i][j] += a_[i] * b_[j];
        }
        __syncthreads();
    }
    const int cg = col_base + tx * 8;
    if (cg < G_B) {
        float rn[8];
#pragma unroll
        for (int j = 0; j < 8; ++j) rn[j] = 1.0f / norm[cg + j];
#pragma unroll
        for (int i = 0; i < 8; ++i) {
            float4 o0 = {acc[i][0] * rn[0], acc[i][1] * rn[1], acc[i][2] * rn[2], acc[i][3] * rn[3]};
            float4 o1 = {acc[i][4] * rn[4], acc[i][5] * rn[5], acc[i][6] * rn[6], acc[i][7] * rn[7]};
            size_t o = (size_t)(row_base + ty * 8 + i) * G_B + cg;
            *(float4*)(out + o) = o0;
            *(float4*)(out + o + 4) = o1;
        }
    }
}

// Fallback MLP (f32)
#define MLP_TK 24
__global__ __launch_bounds__(256) void mlp_kernel(const float* __restrict__ xA,
                                                  const float* __restrict__ ximpA,
                                                  const float* __restrict__ ximpB,
                                                  const float* __restrict__ xB,
                                                  const float* __restrict__ W1,
                                                  const float* __restrict__ b1,
                                                  const float* __restrict__ W2,
                                                  const float* __restrict__ b2,
                                                  float* __restrict__ embA,
                                                  float* __restrict__ embB) {
    __shared__ float Xs[MLP_TK][64];
    __shared__ float Ws[MLP_TK][64];
    __shared__ float Hs[64][65];
    __shared__ float W2s[64][32];

    const int side = blockIdx.x >> 6;
    const int row0 = (blockIdx.x & 63) * 64;
    const float* srcL = side ? ximpB : xA;
    const float* srcR = side ? xB : ximpA;
    float* emb = side ? embB : embA;

    const int tid = threadIdx.x;
    {
        const float4* src = (const float4*)W2;
        float4* dst = (float4*)&W2s[0][0];
        for (int i = tid; i < 512; i += 256) dst[i] = src[i];
    }

    const int tx = tid & 15;
    const int ty = tid >> 4;
    float acc[4][4] = {};
    const int lrow = tid >> 2;
    const int lk6  = (tid & 3) * 6;

    for (int k0 = 0; k0 < 6000; k0 += MLP_TK) {
        const float* src = (k0 < 3000) ? srcL : srcR;
        const int kbase = (k0 < 3000) ? k0 : (k0 - 3000);
        {
            const float* p = src + (size_t)(row0 + lrow) * 3000 + kbase + lk6;
#pragma unroll
            for (int e = 0; e < 6; ++e) Xs[lk6 + e][lrow] = p[e];
        }
        {
#pragma unroll
            for (int e = 0; e < 6; ++e) {
                int idx = tid * 6 + e;
                int kk = idx >> 6, cc = idx & 63;
                Ws[kk][cc] = W1[(size_t)(k0 + kk) * 64 + cc];
            }
        }
        __syncthreads();
#pragma unroll
        for (int kk = 0; kk < MLP_TK; ++kk) {
            float4 a = *(const float4*)&Xs[kk][ty * 4];
            float4 wv = *(const float4*)&Ws[kk][tx * 4];
            float a_[4] = {a.x, a.y, a.z, a.w};
            float w_[4] = {wv.x, wv.y, wv.z, wv.w};
#pragma unroll
            for (int i = 0; i < 4; ++i)
#pragma unroll
                for (int j = 0; j < 4; ++j) acc[i][j] += a_[i] * w_[j];
        }
        __syncthreads();
    }

#pragma unroll
    for (int j = 0; j < 4; ++j) {
        float bj = b1[tx * 4 + j];
#pragma unroll
        for (int i = 0; i < 4; ++i) {
            float h = acc[i][j] + bj;
            Hs[ty * 4 + i][tx * 4 + j] = h > 0.f ? h : 0.f;
        }
    }
    __syncthreads();

    const int c2 = tid & 31;
    const int rg = tid >> 5;
    float acc2[8] = {};
    for (int k = 0; k < 64; ++k) {
        float wv = W2s[k][c2];
#pragma unroll
        for (int i = 0; i < 8; ++i) acc2[i] += Hs[rg * 8 + i][k] * wv;
    }
    float bb = b2[c2];
#pragma unroll
    for (int i = 0; i < 8; ++i) {
        float h = acc2[i] + bb;
        emb[(size_t)(row0 + rg * 8 + i) * 32 + c2] = h > 0.f ? h : 0.f;
    }
}

__global__ __launch_bounds__(256) void sqnorm_kernel(const float* __restrict__ emb,
                                                     float* __restrict__ sq) {
    int i = blockIdx.x * 256 + threadIdx.x;
    if (i >= N_A) return;
    const float4* e = (const float4*)(emb + (size_t)i * 32);
    float s = 0.f;
#pragma unroll
    for (int q = 0; q < 8; ++q) {
        float4 v = e[q];
        s += v.x * v.x + v.y * v.y + v.z * v.z + v.w * v.w;
    }
    sq[i] = s;
}

__global__ __launch_bounds__(256) void preds_kernel(const float* __restrict__ emb,
                                                    const float* __restrict__ Wc,
                                                    const float* __restrict__ bc,
                                                    float* __restrict__ out,
                                                    int ncls) {
    int idx = blockIdx.x * 256 + threadIdx.x;
    int row = idx / ncls, c = idx % ncls;
    const float* e = emb + (size_t)row * 32;
    float s = bc[c];
#pragma unroll
    for (int k = 0; k < 32; ++k) s += e[k] * Wc[k * ncls + c];
    out[idx] = s;
}

// ---------------------------------------------------------------------------
// Fused d2 + top-20: block-cooperative key compute (2 queries/block, embQ in
// registers, key = fkey(sqC[j] - 2*dot); the sqQ term is query-constant and
// drops out of the ranking), then PER-WAVE tournament-tree extraction with
// DPP wave-min reduces — no block barriers, no atomics in the 20-round loop.
// Keys in LDS [64][65] (padded): group scan lane-stride 65 (conflict-free),
// group rescan consecutive (conflict-free). Ties -> smallest index, matching
// jax.lax.top_k. grid = 4096 x 128: blocks 0..2047 A-queries, rest B.
__global__ __launch_bounds__(128) void topk_all_kernel(const float* __restrict__ embA,
                                                       const float* __restrict__ sqA,
                                                       const float* __restrict__ embB,
                                                       const float* __restrict__ sqB,
                                                       int* __restrict__ nnA,
                                                       int* __restrict__ nnB) {
    const int side = blockIdx.x >> 11;
    const int q0 = (blockIdx.x & 2047) * 2;
    const float* embQ = side ? embB : embA;
    const float* embC = side ? embA : embB;
    const float* sqCc = side ? sqA : sqB;
    int* nnOut = side ? nnB : nnA;

    __shared__ u32 keys[2][64 * 65];   // 33280 B

    const int tid = threadIdx.x;
    const int lane = tid & 63, w = tid >> 6;

    // both queries' embeddings in registers (wave-uniform broadcast loads)
    float4 q0v[8], q1v[8];
    {
        const float4* e0 = (const float4*)(embQ + (size_t)q0 * 32);
        const float4* e1 = (const float4*)(embQ + (size_t)(q0 + 1) * 32);
#pragma unroll
        for (int c = 0; c < 8; ++c) { q0v[c] = e0[c]; q1v[c] = e1[c]; }
    }

    // phase 1: block-cooperative key compute (embC read once per block)
    for (int i = 0; i < 32; ++i) {
        int j = (i << 7) + tid;
        const float4* ec = (const float4*)(embC + (size_t)j * 32);
        float d0 = 0.f, d1 = 0.f;
#pragma unroll
        for (int c = 0; c < 8; ++c) {
            float4 cv = ec[c];
            d0 += q0v[c].x * cv.x + q0v[c].y * cv.y + q0v[c].z * cv.z + q0v[c].w * cv.w;
            d1 += q1v[c].x * cv.x + q1v[c].y * cv.y + q1v[c].z * cv.z + q1v[c].w * cv.w;
        }
        float sc = sqCc[j];
        int off = (j >> 6) * 65 + (j & 63);
        keys[0][off] = fkey(sc - 2.f * d0);
        keys[1][off] = fkey(sc - 2.f * d1);
    }
    __syncthreads();

    // phase 2: wave w extracts top-20 for query q0+w (wave-synchronous)
    volatile u32* kq = (volatile u32*)&keys[w][0];

    // build L1: lane l holds min of group l (keys j in [64l, 64l+64))
    u32 l1;
    {
        const int base = lane * 65;
        u32 m0 = 0xFFFFFFFFu, m1 = 0xFFFFFFFFu, m2 = 0xFFFFFFFFu, m3 = 0xFFFFFFFFu;
#pragma unroll
        for (int t = 0; t < 64; t += 4) {
            u32 a = kq[base + t + 0];
            u32 b = kq[base + t + 1];
            u32 c = kq[base + t + 2];
            u32 d = kq[base + t + 3];
            m0 = a < m0 ? a : m0;
            m1 = b < m1 ? b : m1;
            m2 = c < m2 ? c : m2;
            m3 = d < m3 ? d : m3;
        }
        m0 = m1 < m0 ? m1 : m0;
        m2 = m3 < m2 ? m3 : m2;
        l1 = m2 < m0 ? m2 : m0;
    }

    int myj = 0;
    for (int r = 0; r < KNBR; ++r) {
        u32 m = wave_min_u32_bcast(l1);              // global current min
        u64 gmask = __ballot(l1 == m);
        int g = __builtin_ctzll(gmask);              // lowest group = lowest j range
        u32 v = kq[g * 65 + lane];                   // rescan group g (coalesced)
        u64 wmask = __ballot(v == m);
        int jl = __builtin_ctzll(wmask);             // lowest index within group
        if (lane == jl) kq[g * 65 + jl] = 0xFFFFFFFFu;
        u32 v2 = (lane == jl) ? 0xFFFFFFFFu : v;
        u32 nm = wave_min_u32_bcast(v2);             // recomputed group min
        if (lane == g) l1 = nm;
        if (lane == r) myj = (g << 6) | jl;
    }
    if (lane < KNBR) nnOut[(size_t)(q0 + w) * KNBR + lane] = myj;
}

// ---------------------------------------------------------------------------
__global__ __launch_bounds__(256) void predloss_kernel(const int* __restrict__ nn,
                                                       const float* __restrict__ ximp,
                                                       const float* __restrict__ xtrue,
                                                       float* __restrict__ partial) {
    int q = blockIdx.x;
    __shared__ int nns[KNBR];
    __shared__ float red[256];
    if (threadIdx.x < KNBR) nns[threadIdx.x] = nn[(size_t)q * KNBR + threadIdx.x];
    __syncthreads();

    int nr[KNBR];
#pragma unroll
    for (int t = 0; t < KNBR; ++t) nr[t] = nns[t];

    const float inv = 1.0f / KNBR;
    float sse = 0.f;
    for (int v = threadIdx.x; v < 750; v += 256) {
        float4 acc = {0.f, 0.f, 0.f, 0.f};
#pragma unroll
        for (int t = 0; t < KNBR; ++t) {
            const float4 w = *(const float4*)(ximp + (size_t)nr[t] * 3000 + v * 4);
            acc.x += w.x; acc.y += w.y; acc.z += w.z; acc.w += w.w;
        }
        const float4 xt = *(const float4*)(xtrue + (size_t)q * 3000 + v * 4);
        float dx = acc.x * inv - xt.x;
        float dy = acc.y * inv - xt.y;
        float dz = acc.z * inv - xt.z;
        float dw = acc.w * inv - xt.w;
        sse += dx * dx + dy * dy + dz * dz + dw * dw;
    }
    red[threadIdx.x] = sse;
    __syncthreads();
    for (int off = 128; off > 0; off >>= 1) {
        if (threadIdx.x < off) red[threadIdx.x] += red[threadIdx.x + off];
        __syncthreads();
    }
    if (threadIdx.x == 0) partial[q] = red[0];
}

__global__ __launch_bounds__(256) void loss_final_kernel(const float* __restrict__ pA,
                                                         const float* __restrict__ pB,
                                                         float* __restrict__ out) {
    __shared__ double red[256];
    double sa = 0.0, sb = 0.0;
    for (int i = threadIdx.x; i < 4096; i += 256) {
        sa += (double)pA[i];
        sb += (double)pB[i];
    }
    red[threadIdx.x] = sa;
    __syncthreads();
    for (int off = 128; off > 0; off >>= 1) {
        if (threadIdx.x < off) red[threadIdx.x] += red[threadIdx.x + off];
        __syncthreads();
    }
    double totA = red[0];
    __syncthreads();
    red[threadIdx.x] = sb;
    __syncthreads();
    for (int off = 128; off > 0; off >>= 1) {
        if (threadIdx.x < off) red[threadIdx.x] += red[threadIdx.x + off];
        __syncthreads();
    }
    if (threadIdx.x == 0) {
        double denom = 4096.0 * 3000.0;
        out[0] = (float)(totA / denom + red[0] / denom);
    }
}

// ---------------------------------------------------------------------------
extern "C" void kernel_launch(void* const* d_in, const int* in_sizes, int n_in,
                              void* d_out, int out_size, void* d_ws, size_t ws_size,
                              hipStream_t stream) {
    const float* x_A = (const float*)d_in[0];
    const float* x_B = (const float*)d_in[1];
    const float* G   = (const float*)d_in[2];
    const float* W1  = (const float*)d_in[3];
    const float* b1  = (const float*)d_in[4];
    const float* W2  = (const float*)d_in[5];
    const float* b2  = (const float*)d_in[6];
    const float* WcA = (const float*)d_in[7];
    const float* bcA = (const float*)d_in[8];
    const float* WcB = (const float*)d_in[9];
    const float* bcB = (const float*)d_in[10];

    float* outp = (float*)d_out;

    size_t off = 0;
    char* base = (char*)d_ws;
    auto carve = [&](size_t bytes) -> void* {
        void* p = base + off;
        off = (off + bytes + 255) & ~(size_t)255;
        return p;
    };
    float* ximpA = (float*)carve((size_t)N_A * G_B * 4);
    float* ximpB = (float*)carve((size_t)N_B * G_A * 4);
    float* normA = (float*)carve(G_A * 4);
    float* normB = (float*)carve(G_B * 4);
    float* colpart = (float*)carve(25 * G_B * 4);
    float* embA = (float*)carve((size_t)N_A * 32 * 4);
    float* embB = (float*)carve((size_t)N_B * 32 * 4);
    float* sqA = (float*)carve(N_A * 4);
    float* sqB = (float*)carve(N_B * 4);
    float* partA = (float*)carve(N_A * 4);
    float* partB = (float*)carve(N_B * 4);
    int* nnA = (int*)carve((size_t)N_A * KNBR * 4);
    int* nnB = (int*)carve((size_t)N_B * KNBR * 4);
    u16* xAbf = (u16*)carve((size_t)N_A * KPAD * 2);
    u16* xBbf = (u16*)carve((size_t)N_B * KPAD * 2);
    u16* Gbf  = (u16*)carve((size_t)KPAD * KPAD * 2);
    u16* Gtbf = (u16*)carve((size_t)KPAD * KPAD * 2);
    size_t r2_needed = off;
    u16* ximpAbf = (u16*)carve((size_t)N_A * KPAD * 2);
    u16* ximpBbf = (u16*)carve((size_t)N_B * KPAD * 2);
    u16* W1tbf   = (u16*)carve((size_t)64 * KMLP * 2);
    float* mlppart = (float*)carve((size_t)4 * 8192 * 64 * 4);
    size_t full_needed = off;

    const bool use_mfma = (ws_size >= r2_needed);
    const bool use_mlp_mfma = (ws_size >= full_needed);

    // 1) normalizers
    row_sum_kernel<<<G_A, 256, 0, stream>>>(G, normA);
    col_partial_kernel<<<dim3(12, 25), 256, 0, stream>>>(G, colpart);
    col_final_kernel<<<12, 256, 0, stream>>>(colpart, normB);

    // 2) imputation GEMMs (+ bf16 copies)
    if (use_mfma && use_mlp_mfma) {
        convert_pad_kernel<<<(N_A * (KPAD / 8)) / 256, 256, 0, stream>>>(x_A, xAbf, N_A, G_A, KPAD);
        convert_pad_kernel<<<(N_B * (KPAD / 8)) / 256, 256, 0, stream>>>(x_B, xBbf, N_B, G_B, KPAD);
        convert_pad_kernel<<<(KPAD * (KPAD / 8)) / 256, 256, 0, stream>>>(G, Gbf, G_A, G_B, KPAD);
        transpose_convert_kernel<<<dim3(96, 96), 256, 0, stream>>>(G, Gtbf);
        w1t_kernel<<<(64 * KMLP) / 256, 256, 0, stream>>>(W1, W1tbf);

        dim3 ggrid(KPAD / 128, N_A / 128);
        mfma_impute_gemm<<<ggrid, 256, 0, stream>>>(xAbf, Gtbf, normB, ximpA, ximpAbf);
        mfma_impute_gemm<<<ggrid, 256, 0, stream>>>(xBbf, Gbf, normA, ximpB, ximpBbf);

        // 3) MLP via MFMA + K-split
        mlp1_kernel<<<dim3(4, 128), 256, 0, stream>>>(xAbf, ximpAbf, ximpBbf, xBbf, W1tbf, mlppart);
        mlp2_kernel<<<128, 256, 0, stream>>>(mlppart, b1, W2, b2, embA, embB, sqA, sqB);
    } else {
        dim3 ggrid(24, 32);
        impute_gemm<false><<<ggrid, 256, 0, stream>>>(x_A, G, normB, ximpA);
        impute_gemm<true><<<ggrid, 256, 0, stream>>>(x_B, G, normA, ximpB);
        mlp_kernel<<<128, 256, 0, stream>>>(x_A, ximpA, ximpB, x_B, W1, b1, W2, b2, embA, embB);
        sqnorm_kernel<<<16, 256, 0, stream>>>(embA, sqA);
        sqnorm_kernel<<<16, 256, 0, stream>>>(embB, sqB);
    }

    // 5) class predictions -> d_out
    preds_kernel<<<(N_A * NCA) / 256, 256, 0, stream>>>(embA, WcA, bcA, outp, NCA);
    preds_kernel<<<(N_B * NCB) / 256, 256, 0, stream>>>(embB, WcB, bcB, outp + (size_t)N_A * NCA, NCB);

    // 6) top-20 neighbors (wave-local tournament tree, DPP reduces)
    topk_all_kernel<<<4096, 128, 0, stream>>>(embA, sqA, embB, sqB, nnA, nnB);

    // 7) fused gather-mean + MSE partials
    predloss_kernel<<<N_A, 256, 0, stream>>>(nnA, ximpB, x_A, partA);
    predloss_kernel<<<N_B, 256, 0, stream>>>(nnB, ximpA, x_B, partB);

    // 8) final loss
    loss_final_kernel<<<1, 256, 0, stream>>>(partA, partB, outp + (size_t)N_A * NCA + (size_t)N_B * NCB);

    (void)in_sizes; (void)n_in; (void)out_size;
}

// Round 7
// 741.296 us; speedup vs baseline: 2.1414x; 1.2323x over previous
//
#include <hip/hip_runtime.h>
#include <cfloat>
#include <cstddef>
#include <climits>

// Problem constants
#define N_A   4096
#define N_B   4096
#define G_A   3000
#define G_B   3000
#define NCA   30
#define NCB   25
#define KNBR  20
#define KPAD  3072   // K/N padding for MFMA tiles (multiple of 128)
#define KMLP  6144   // padded MLP K ( = 2*KPAD )

typedef unsigned short u16;
typedef unsigned int u32;
typedef unsigned long long u64;
typedef __bf16 bf16x8 __attribute__((ext_vector_type(8)));
typedef float f32x4 __attribute__((ext_vector_type(4)));
typedef __attribute__((address_space(1))) const void* as1_cvp;
typedef __attribute__((address_space(3))) void* as3_vp;

static __device__ __forceinline__ u16 f2bf(float f) {
    union { float f; unsigned u; } v; v.f = f;
    unsigned r = v.u + 0x7fffu + ((v.u >> 16) & 1u);   // RTNE
    return (u16)(r >> 16);
}

// monotonic float -> u32 key (ascending float == ascending unsigned)
static __device__ __forceinline__ u32 fkey(float f) {
    union { float f; u32 u; } v; v.f = f;
    return (v.u & 0x80000000u) ? ~v.u : (v.u | 0x80000000u);
}

// 64-lane min-reduce via DPP + broadcast (lane 63 holds global min).
static __device__ __forceinline__ u32 wave_min_u32_bcast(u32 v) {
    u32 t;
    t = (u32)__builtin_amdgcn_update_dpp((int)v, (int)v, 0x111, 0xf, 0xf, false); v = t < v ? t : v;
    t = (u32)__builtin_amdgcn_update_dpp((int)v, (int)v, 0x112, 0xf, 0xf, false); v = t < v ? t : v;
    t = (u32)__builtin_amdgcn_update_dpp((int)v, (int)v, 0x114, 0xf, 0xf, false); v = t < v ? t : v;
    t = (u32)__builtin_amdgcn_update_dpp((int)v, (int)v, 0x118, 0xf, 0xf, false); v = t < v ? t : v;
    t = (u32)__builtin_amdgcn_update_dpp((int)v, (int)v, 0x142, 0xf, 0xf, false); v = t < v ? t : v;
    t = (u32)__builtin_amdgcn_update_dpp((int)v, (int)v, 0x143, 0xf, 0xf, false); v = t < v ? t : v;
    return (u32)__builtin_amdgcn_readlane((int)v, 63);
}

// ---------------------------------------------------------------------------
// normalizers
__global__ __launch_bounds__(256) void row_sum_kernel(const float* __restrict__ G,
                                                      float* __restrict__ normA) {
    int row = blockIdx.x;
    __shared__ float red[256];
    float s = 0.f;
    for (int j = threadIdx.x; j < G_B; j += 256) s += G[(size_t)row * G_B + j];
    red[threadIdx.x] = s;
    __syncthreads();
    for (int off = 128; off > 0; off >>= 1) {
        if (threadIdx.x < off) red[threadIdx.x] += red[threadIdx.x + off];
        __syncthreads();
    }
    if (threadIdx.x == 0) {
        float v = red[0];
        normA[row] = (v == 0.f) ? 1.f : v;
    }
}

__global__ __launch_bounds__(256) void col_partial_kernel(const float* __restrict__ G,
                                                          float* __restrict__ part) {
    int j = blockIdx.x * 256 + threadIdx.x;
    if (j >= G_B) return;
    int r0 = blockIdx.y * 120;
    float s = 0.f;
    for (int i = r0; i < r0 + 120; ++i) s += G[(size_t)i * G_B + j];
    part[(size_t)blockIdx.y * G_B + j] = s;
}

__global__ __launch_bounds__(256) void col_final_kernel(const float* __restrict__ part,
                                                        float* __restrict__ normB) {
    int j = blockIdx.x * 256 + threadIdx.x;
    if (j >= G_B) return;
    float s = 0.f;
    for (int c = 0; c < 25; ++c) s += part[(size_t)c * G_B + j];
    normB[j] = (s == 0.f) ? 1.f : s;
}

// ---------------------------------------------------------------------------
// f32 -> bf16 convert with zero padding
__global__ __launch_bounds__(256) void convert_pad_kernel(const float* __restrict__ in,
                                                          u16* __restrict__ out,
                                                          int in_rows, int in_cols,
                                                          int out_cols) {
    int idx = blockIdx.x * 256 + threadIdx.x;
    int cpr = out_cols >> 3;
    int r = idx / cpr, c0 = (idx % cpr) << 3;
    u16 res[8] = {0, 0, 0, 0, 0, 0, 0, 0};
    if (r < in_rows && c0 + 8 <= in_cols) {
        float4 v0 = *(const float4*)(in + (size_t)r * in_cols + c0);
        float4 v1 = *(const float4*)(in + (size_t)r * in_cols + c0 + 4);
        res[0] = f2bf(v0.x); res[1] = f2bf(v0.y); res[2] = f2bf(v0.z); res[3] = f2bf(v0.w);
        res[4] = f2bf(v1.x); res[5] = f2bf(v1.y); res[6] = f2bf(v1.z); res[7] = f2bf(v1.w);
    }
    uint4 pack;
    pack.x = (unsigned)res[0] | ((unsigned)res[1] << 16);
    pack.y = (unsigned)res[2] | ((unsigned)res[3] << 16);
    pack.z = (unsigned)res[4] | ((unsigned)res[5] << 16);
    pack.w = (unsigned)res[6] | ((unsigned)res[7] << 16);
    *(uint4*)(out + (size_t)r * out_cols + c0) = pack;
}

// Gt[j][k] = bf16(G[k][j]) padded to [KPAD][KPAD]
__global__ __launch_bounds__(256) void transpose_convert_kernel(const float* __restrict__ G,
                                                                u16* __restrict__ Gt) {
    __shared__ float t[32][33];
    int j0 = blockIdx.x * 32, k0 = blockIdx.y * 32;
    int lx = threadIdx.x & 31, ly = threadIdx.x >> 5;
#pragma unroll
    for (int i = 0; i < 4; ++i) {
        int k = k0 + ly + i * 8, j = j0 + lx;
        t[ly + i * 8][lx] = (k < G_A && j < G_B) ? G[(size_t)k * G_B + j] : 0.f;
    }
    __syncthreads();
#pragma unroll
    for (int i = 0; i < 4; ++i) {
        int j = j0 + ly + i * 8, k = k0 + lx;
        Gt[(size_t)j * KPAD + k] = f2bf(t[lx][ly + i * 8]);
    }
}

// W1 [6000][64] f32 -> W1t [64][KMLP] bf16
__global__ __launch_bounds__(256) void w1t_kernel(const float* __restrict__ W1,
                                                  u16* __restrict__ W1t) {
    int idx = blockIdx.x * 256 + threadIdx.x;
    int n = idx / KMLP, kp = idx % KMLP;
    int seg = kp >= KPAD;
    int k = kp - (seg ? KPAD : 0);
    float v = (k < 3000) ? W1[(size_t)(seg * 3000 + k) * 64 + n] : 0.f;
    W1t[(size_t)n * KMLP + kp] = f2bf(v);
}

// ---------------------------------------------------------------------------
// bf16 MFMA GEMM: out[i][j] = (sum_k A[i][k] * Bt[j][k]) / norm[j]
__global__ __launch_bounds__(256) void mfma_impute_gemm(const u16* __restrict__ A,
                                                        const u16* __restrict__ Bt,
                                                        const float* __restrict__ norm,
                                                        float* __restrict__ out,
                                                        u16* __restrict__ outbf) {
    __shared__ __align__(16) u16 lAs[128 * 64];
    __shared__ __align__(16) u16 lBs[128 * 64];

    const int tid = threadIdx.x;
    const int w = tid >> 6, lane = tid & 63;
    const int row_base = blockIdx.y * 128;
    const int col_base = blockIdx.x * 128;
    const int wr = (w >> 1) * 64, wc = (w & 1) * 64;

    f32x4 acc[4][4] = {};

    int s_r[4], s_off[4];
#pragma unroll
    for (int i = 0; i < 4; ++i) {
        int slin = (w * 4 + i) * 64 + lane;
        int r = slin >> 3, s = slin & 7;
        s_r[i] = r;
        s_off[i] = (s ^ (r & 7)) * 8;
    }

    for (int k0 = 0; k0 < KPAD; k0 += 64) {
#pragma unroll
        for (int i = 0; i < 4; ++i) {
            const u16* ga = A + (size_t)(row_base + s_r[i]) * KPAD + k0 + s_off[i];
            __builtin_amdgcn_global_load_lds((as1_cvp)ga,
                (as3_vp)(lAs + (size_t)(w * 4 + i) * 512), 16, 0, 0);
        }
#pragma unroll
        for (int i = 0; i < 4; ++i) {
            const u16* gb = Bt + (size_t)(col_base + s_r[i]) * KPAD + k0 + s_off[i];
            __builtin_amdgcn_global_load_lds((as1_cvp)gb,
                (as3_vp)(lBs + (size_t)(w * 4 + i) * 512), 16, 0, 0);
        }
        __syncthreads();

#pragma unroll
        for (int kk = 0; kk < 2; ++kk) {
            bf16x8 a[4], b[4];
#pragma unroll
            for (int m = 0; m < 4; ++m) {
                int row = wr + m * 16 + (lane & 15);
                int slot = (kk * 4 + (lane >> 4)) ^ (row & 7);
                a[m] = *(const bf16x8*)(lAs + row * 64 + slot * 8);
            }
#pragma unroll
            for (int n = 0; n < 4; ++n) {
                int row = wc + n * 16 + (lane & 15);
                int slot = (kk * 4 + (lane >> 4)) ^ (row & 7);
                b[n] = *(const bf16x8*)(lBs + row * 64 + slot * 8);
            }
#pragma unroll
            for (int m = 0; m < 4; ++m)
#pragma unroll
                for (int n = 0; n < 4; ++n)
                    acc[m][n] = __builtin_amdgcn_mfma_f32_16x16x32_bf16(a[m], b[n], acc[m][n], 0, 0, 0);
        }
        __syncthreads();
    }

#pragma unroll
    for (int n = 0; n < 4; ++n) {
        int col = col_base + wc + n * 16 + (lane & 15);
        bool valid = col < G_B;
        float rn = valid ? 1.0f / norm[col] : 0.f;
#pragma unroll
        for (int m = 0; m < 4; ++m) {
            int row = row_base + wr + m * 16 + (lane >> 4) * 4;
#pragma unroll
            for (int r = 0; r < 4; ++r) {
                float v = acc[m][n][r] * rn;
                if (valid) out[(size_t)(row + r) * G_B + col] = v;
                outbf[(size_t)(row + r) * KPAD + col] = f2bf(v);
            }
        }
    }
}

// ---------------------------------------------------------------------------
// MLP layer 1 (bf16 MFMA, K-split)
__global__ __launch_bounds__(256) void mlp1_kernel(const u16* __restrict__ xAbf,
                                                   const u16* __restrict__ ximpAbf,
                                                   const u16* __restrict__ ximpBbf,
                                                   const u16* __restrict__ xBbf,
                                                   const u16* __restrict__ W1t,
                                                   float* __restrict__ partial) {
    const int chunk = blockIdx.x;
    const int rb = blockIdx.y;
    const int side = rb >> 6;
    const int r0 = (rb & 63) * 64;
    const int seg = chunk >> 1;
    const u16* src = side ? (seg ? xBbf : ximpBbf) : (seg ? ximpAbf : xAbf);
    const int k0base = (chunk & 1) * 1536;

    __shared__ __align__(16) u16 lAs[64 * 64];
    __shared__ __align__(16) u16 lBs[64 * 64];

    const int tid = threadIdx.x;
    const int w = tid >> 6, lane = tid & 63;

    int s_r[2], s_off[2];
#pragma unroll
    for (int i = 0; i < 2; ++i) {
        int slin = (w * 2 + i) * 64 + lane;
        int r = slin >> 3, s = slin & 7;
        s_r[i] = r;
        s_off[i] = (s ^ (r & 7)) * 8;
    }

    f32x4 acc[4] = {};

    for (int k0 = 0; k0 < 1536; k0 += 64) {
#pragma unroll
        for (int i = 0; i < 2; ++i) {
            const u16* ga = src + (size_t)(r0 + s_r[i]) * KPAD + k0base + k0 + s_off[i];
            __builtin_amdgcn_global_load_lds((as1_cvp)ga,
                (as3_vp)(lAs + (size_t)(w * 2 + i) * 512), 16, 0, 0);
        }
#pragma unroll
        for (int i = 0; i < 2; ++i) {
            const u16* gb = W1t + (size_t)s_r[i] * KMLP + chunk * 1536 + k0 + s_off[i];
            __builtin_amdgcn_global_load_lds((as1_cvp)gb,
                (as3_vp)(lBs + (size_t)(w * 2 + i) * 512), 16, 0, 0);
        }
        __syncthreads();

#pragma unroll
        for (int kk = 0; kk < 2; ++kk) {
            int arow = w * 16 + (lane & 15);
            int aslot = (kk * 4 + (lane >> 4)) ^ (arow & 7);
            bf16x8 a = *(const bf16x8*)(lAs + arow * 64 + aslot * 8);
#pragma unroll
            for (int n = 0; n < 4; ++n) {
                int brow = n * 16 + (lane & 15);
                int bslot = (kk * 4 + (lane >> 4)) ^ (brow & 7);
                bf16x8 b = *(const bf16x8*)(lBs + brow * 64 + bslot * 8);
                acc[n] = __builtin_amdgcn_mfma_f32_16x16x32_bf16(a, b, acc[n], 0, 0, 0);
            }
        }
        __syncthreads();
    }

    const size_t grow0 = (size_t)rb * 64;
#pragma unroll
    for (int n = 0; n < 4; ++n) {
        int col = n * 16 + (lane & 15);
        int rowl = w * 16 + (lane >> 4) * 4;
#pragma unroll
        for (int r = 0; r < 4; ++r)
            partial[((size_t)chunk * 8192 + grow0 + rowl + r) * 64 + col] = acc[n][r];
    }
}

// MLP reduce + layer 2 + fused sqnorm
__global__ __launch_bounds__(256) void mlp2_kernel(const float* __restrict__ partial,
                                                   const float* __restrict__ b1,
                                                   const float* __restrict__ W2,
                                                   const float* __restrict__ b2,
                                                   float* __restrict__ embA,
                                                   float* __restrict__ embB,
                                                   float* __restrict__ sqA,
                                                   float* __restrict__ sqB) {
    const int rb = blockIdx.x;
    const int side = rb >> 6;
    const size_t grow0 = (size_t)rb * 64;
    const int r0 = (rb & 63) * 64;
    float* emb = side ? embB : embA;
    float* sq = side ? sqB : sqA;

    __shared__ float Hs[64][65];
    __shared__ float W2s[64][32];
    const int tid = threadIdx.x;

    {
        const float4* srcw = (const float4*)W2;
        float4* dst = (float4*)&W2s[0][0];
        for (int i = tid; i < 512; i += 256) dst[i] = srcw[i];
    }

    for (int v = tid; v < 1024; v += 256) {
        int row = v >> 4, c4 = v & 15;
        float4 s = {0.f, 0.f, 0.f, 0.f};
#pragma unroll
        for (int c = 0; c < 4; ++c) {
            const float4 p = *(const float4*)(partial + ((size_t)c * 8192 + grow0 + row) * 64 + c4 * 4);
            s.x += p.x; s.y += p.y; s.z += p.z; s.w += p.w;
        }
        const float4 bb = *(const float4*)(b1 + c4 * 4);
        Hs[row][c4 * 4 + 0] = fmaxf(s.x + bb.x, 0.f);
        Hs[row][c4 * 4 + 1] = fmaxf(s.y + bb.y, 0.f);
        Hs[row][c4 * 4 + 2] = fmaxf(s.z + bb.z, 0.f);
        Hs[row][c4 * 4 + 3] = fmaxf(s.w + bb.w, 0.f);
    }
    __syncthreads();

    const int c2 = tid & 31, rg = tid >> 5;
    float acc2[8] = {};
    for (int k = 0; k < 64; ++k) {
        float wv = W2s[k][c2];
#pragma unroll
        for (int i = 0; i < 8; ++i) acc2[i] += Hs[rg * 8 + i][k] * wv;
    }
    float bb = b2[c2];
    float e[8];
#pragma unroll
    for (int i = 0; i < 8; ++i) {
        e[i] = fmaxf(acc2[i] + bb, 0.f);
        emb[(size_t)(r0 + rg * 8 + i) * 32 + c2] = e[i];
    }
#pragma unroll
    for (int i = 0; i < 8; ++i) {
        float v = e[i] * e[i];
#pragma unroll
        for (int off = 16; off > 0; off >>= 1) v += __shfl_xor(v, off, 32);
        if (c2 == 0) sq[r0 + rg * 8 + i] = v;
    }
}

// ---------------------------------------------------------------------------
// Fallback f32 GEMM
template <bool TRANSB>
__global__ __launch_bounds__(256) void impute_gemm(const float* __restrict__ X,
                                                   const float* __restrict__ G,
                                                   const float* __restrict__ norm,
                                                   float* __restrict__ out) {
    __shared__ float As[8][128];
    __shared__ float Bs[8][128];
    const int tid = threadIdx.x;
    const int col_base = blockIdx.x * 128;
    const int row_base = blockIdx.y * 128;
    const int tx = tid & 15;
    const int ty = tid >> 4;
    float acc[8][8] = {};
    const int a_row = tid >> 1;
    const int a_k   = (tid & 1) * 4;
    for (int k0 = 0; k0 < G_B; k0 += 8) {
        {
            float4 av = *(const float4*)(X + (size_t)(row_base + a_row) * G_B + k0 + a_k);
            As[a_k + 0][a_row] = av.x;
            As[a_k + 1][a_row] = av.y;
            As[a_k + 2][a_row] = av.z;
            As[a_k + 3][a_row] = av.w;
        }
        if (!TRANSB) {
            const int bk = tid >> 5;
            const int bc = (tid & 31) * 4;
            float4 bv = {0.f, 0.f, 0.f, 0.f};
            if (col_base + bc < G_B)
                bv = *(const float4*)(G + (size_t)(k0 + bk) * G_B + col_base + bc);
            *(float4*)&Bs[bk][bc] = bv;
        } else {
            const int bj = tid >> 1;
            const int bk = (tid & 1) * 4;
            float4 bv = {0.f, 0.f, 0.f, 0.f};
            if (col_base + bj < G_B)
                bv = *(const float4*)(G + (size_t)(col_base + bj) * G_B + k0 + bk);
            Bs[bk + 0][bj] = bv.x;
            Bs[bk + 1][bj] = bv.y;
            Bs[bk + 2][bj] = bv.z;
            Bs[bk + 3][bj] = bv.w;
        }
        __syncthreads();
#pragma unroll
        for (int kk = 0; kk < 8; ++kk) {
            float4 a0 = *(const float4*)&As[kk][ty * 8];
            float4 a1 = *(const float4*)&As[kk][ty * 8 + 4];
            float4 b0 = *(const float4*)&Bs[kk][tx * 8];
            float4 b1 = *(const float4*)&Bs[kk][tx * 8 + 4];
            float a_[8] = {a0.x, a0.y, a0.z, a0.w, a1.x, a1.y, a1.z, a1.w};
            float b_[8] = {b0.x, b0.y, b0.z, b0.w, b1.x, b1.y, b1.z, b1.w};
#pragma unroll
            for (int i = 0; i < 8; ++i)
#pragma unroll
                for (int j = 0; j < 8; ++j) acc[i][j] += a_[i] * b_[j];
        }
        __syncthreads();
    }
    const int cg = col_base + tx * 8;
    if (cg < G_B) {
        float rn[8];
#pragma unroll
        for (int j = 0; j < 8; ++j) rn[j] = 1.0f / norm[cg + j];
#pragma unroll
        for (int i = 0; i < 8; ++i) {
            float4 o0 = {acc[i][0] * rn[0], acc[i][1] * rn[1], acc[i][2] * rn[2], acc[i][3] * rn[3]};
            float4 o1 = {acc[i][4] * rn[4], acc[i][5] * rn[5], acc[i][6] * rn[6], acc[i][7] * rn[7]};
            size_t o = (size_t)(row_base + ty * 8 + i) * G_B + cg;
            *(float4*)(out + o) = o0;
            *(float4*)(out + o + 4) = o1;
        }
    }
}

// Fallback MLP (f32)
#define MLP_TK 24
__global__ __launch_bounds__(256) void mlp_kernel(const float* __restrict__ xA,
                                                  const float* __restrict__ ximpA,
                                                  const float* __restrict__ ximpB,
                                                  const float* __restrict__ xB,
                                                  const float* __restrict__ W1,
                                                  const float* __restrict__ b1,
                                                  const float* __restrict__ W2,
                                                  const float* __restrict__ b2,
                                                  float* __restrict__ embA,
                                                  float* __restrict__ embB) {
    __shared__ float Xs[MLP_TK][64];
    __shared__ float Ws[MLP_TK][64];
    __shared__ float Hs[64][65];
    __shared__ float W2s[64][32];

    const int side = blockIdx.x >> 6;
    const int row0 = (blockIdx.x & 63) * 64;
    const float* srcL = side ? ximpB : xA;
    const float* srcR = side ? xB : ximpA;
    float* emb = side ? embB : embA;

    const int tid = threadIdx.x;
    {
        const float4* src = (const float4*)W2;
        float4* dst = (float4*)&W2s[0][0];
        for (int i = tid; i < 512; i += 256) dst[i] = src[i];
    }

    const int tx = tid & 15;
    const int ty = tid >> 4;
    float acc[4][4] = {};
    const int lrow = tid >> 2;
    const int lk6  = (tid & 3) * 6;

    for (int k0 = 0; k0 < 6000; k0 += MLP_TK) {
        const float* src = (k0 < 3000) ? srcL : srcR;
        const int kbase = (k0 < 3000) ? k0 : (k0 - 3000);
        {
            const float* p = src + (size_t)(row0 + lrow) * 3000 + kbase + lk6;
#pragma unroll
            for (int e = 0; e < 6; ++e) Xs[lk6 + e][lrow] = p[e];
        }
        {
#pragma unroll
            for (int e = 0; e < 6; ++e) {
                int idx = tid * 6 + e;
                int kk = idx >> 6, cc = idx & 63;
                Ws[kk][cc] = W1[(size_t)(k0 + kk) * 64 + cc];
            }
        }
        __syncthreads();
#pragma unroll
        for (int kk = 0; kk < MLP_TK; ++kk) {
            float4 a = *(const float4*)&Xs[kk][ty * 4];
            float4 wv = *(const float4*)&Ws[kk][tx * 4];
            float a_[4] = {a.x, a.y, a.z, a.w};
            float w_[4] = {wv.x, wv.y, wv.z, wv.w};
#pragma unroll
            for (int i = 0; i < 4; ++i)
#pragma unroll
                for (int j = 0; j < 4; ++j) acc[i][j] += a_[i] * w_[j];
        }
        __syncthreads();
    }

#pragma unroll
    for (int j = 0; j < 4; ++j) {
        float bj = b1[tx * 4 + j];
#pragma unroll
        for (int i = 0; i < 4; ++i) {
            float h = acc[i][j] + bj;
            Hs[ty * 4 + i][tx * 4 + j] = h > 0.f ? h : 0.f;
        }
    }
    __syncthreads();

    const int c2 = tid & 31;
    const int rg = tid >> 5;
    float acc2[8] = {};
    for (int k = 0; k < 64; ++k) {
        float wv = W2s[k][c2];
#pragma unroll
        for (int i = 0; i < 8; ++i) acc2[i] += Hs[rg * 8 + i][k] * wv;
    }
    float bb = b2[c2];
#pragma unroll
    for (int i = 0; i < 8; ++i) {
        float h = acc2[i] + bb;
        emb[(size_t)(row0 + rg * 8 + i) * 32 + c2] = h > 0.f ? h : 0.f;
    }
}

__global__ __launch_bounds__(256) void sqnorm_kernel(const float* __restrict__ emb,
                                                     float* __restrict__ sq) {
    int i = blockIdx.x * 256 + threadIdx.x;
    if (i >= N_A) return;
    const float4* e = (const float4*)(emb + (size_t)i * 32);
    float s = 0.f;
#pragma unroll
    for (int q = 0; q < 8; ++q) {
        float4 v = e[q];
        s += v.x * v.x + v.y * v.y + v.z * v.z + v.w * v.w;
    }
    sq[i] = s;
}

__global__ __launch_bounds__(256) void preds_kernel(const float* __restrict__ emb,
                                                    const float* __restrict__ Wc,
                                                    const float* __restrict__ bc,
                                                    float* __restrict__ out,
                                                    int ncls) {
    int idx = blockIdx.x * 256 + threadIdx.x;
    int row = idx / ncls, c = idx % ncls;
    const float* e = emb + (size_t)row * 32;
    float s = bc[c];
#pragma unroll
    for (int k = 0; k < 32; ++k) s += e[k] * Wc[k * ncls + c];
    out[idx] = s;
}

// ---------------------------------------------------------------------------
// Distance-key GEMM: keys[q][j] = fkey(sqC[j] - 2 * dot(embQ[q], embC[j]))
// f32, K=32, 128x128 tile, 256 threads, 8x8 micro-tile. grid (32,32).
// (sqQ is a per-query constant -> dropped from the ranking key.)
__global__ __launch_bounds__(256) void distkey_gemm(const float* __restrict__ embQ,
                                                    const float* __restrict__ embC,
                                                    const float* __restrict__ sqC,
                                                    u32* __restrict__ keys) {
    __shared__ float As[32][132];
    __shared__ float Bs[32][132];

    const int tid = threadIdx.x;
    const int row_base = blockIdx.y * 128;
    const int col_base = blockIdx.x * 128;

    // stage: 128 rows x 32 k, transposed into [k][row]
#pragma unroll
    for (int i = 0; i < 4; ++i) {
        int idx = i * 256 + tid;          // 0..1023
        int row = idx >> 3, k4 = (idx & 7) * 4;
        float4 a = *(const float4*)(embQ + (size_t)(row_base + row) * 32 + k4);
        As[k4 + 0][row] = a.x;
        As[k4 + 1][row] = a.y;
        As[k4 + 2][row] = a.z;
        As[k4 + 3][row] = a.w;
        float4 b = *(const float4*)(embC + (size_t)(col_base + row) * 32 + k4);
        Bs[k4 + 0][row] = b.x;
        Bs[k4 + 1][row] = b.y;
        Bs[k4 + 2][row] = b.z;
        Bs[k4 + 3][row] = b.w;
    }
    __syncthreads();

    const int tx = tid & 15, ty = tid >> 4;
    float acc[8][8] = {};
#pragma unroll
    for (int k = 0; k < 32; ++k) {
        float4 a0 = *(const float4*)&As[k][ty * 8];
        float4 a1 = *(const float4*)&As[k][ty * 8 + 4];
        float4 b0 = *(const float4*)&Bs[k][tx * 8];
        float4 b1 = *(const float4*)&Bs[k][tx * 8 + 4];
        float a_[8] = {a0.x, a0.y, a0.z, a0.w, a1.x, a1.y, a1.z, a1.w};
        float b_[8] = {b0.x, b0.y, b0.z, b0.w, b1.x, b1.y, b1.z, b1.w};
#pragma unroll
        for (int i = 0; i < 8; ++i)
#pragma unroll
            for (int j = 0; j < 8; ++j) acc[i][j] += a_[i] * b_[j];
    }

    const int cg = col_base + tx * 8;
    float sc[8];
#pragma unroll
    for (int j = 0; j < 8; ++j) sc[j] = sqC[cg + j];
#pragma unroll
    for (int i = 0; i < 8; ++i) {
        uint4 o0, o1;
        o0.x = fkey(sc[0] - 2.f * acc[i][0]);
        o0.y = fkey(sc[1] - 2.f * acc[i][1]);
        o0.z = fkey(sc[2] - 2.f * acc[i][2]);
        o0.w = fkey(sc[3] - 2.f * acc[i][3]);
        o1.x = fkey(sc[4] - 2.f * acc[i][4]);
        o1.y = fkey(sc[5] - 2.f * acc[i][5]);
        o1.z = fkey(sc[6] - 2.f * acc[i][6]);
        o1.w = fkey(sc[7] - 2.f * acc[i][7]);
        size_t o = (size_t)(row_base + ty * 8 + i) * 4096 + cg;
        *(uint4*)(keys + o) = o0;
        *(uint4*)(keys + o + 4) = o1;
    }
}

// Per-query top-20 extraction from a precomputed key row. One wave per block.
// Load 4096 keys coalesced -> LDS [64][65]; DPP tournament (no barriers).
// Ties -> smallest index (ascending (key, j)), matching jax.lax.top_k.
__global__ __launch_bounds__(64) void topk_select(const u32* __restrict__ keyA,
                                                  const u32* __restrict__ keyB,
                                                  int* __restrict__ nnA,
                                                  int* __restrict__ nnB) {
    const int side = blockIdx.x >> 12;
    const int q = blockIdx.x & 4095;
    const u32* krow = (side ? keyB : keyA) + (size_t)q * 4096;
    int* nnOut = (side ? nnB : nnA) + (size_t)q * KNBR;

    __shared__ u32 kbuf[64 * 65];
    const int lane = threadIdx.x;

    // stage keys: j = t*64+lane -> lds[(j>>6)*65 + (j&63)] = lds[t*65+lane]
#pragma unroll 8
    for (int t = 0; t < 64; ++t) kbuf[t * 65 + lane] = krow[t * 64 + lane];

    volatile u32* kq = (volatile u32*)kbuf;

    // L1: lane l = min of group l (keys j in [64l, 64l+64))
    u32 l1;
    {
        const int base = lane * 65;
        u32 m0 = 0xFFFFFFFFu, m1 = 0xFFFFFFFFu, m2 = 0xFFFFFFFFu, m3 = 0xFFFFFFFFu;
#pragma unroll
        for (int t = 0; t < 64; t += 4) {
            u32 a = kq[base + t + 0];
            u32 b = kq[base + t + 1];
            u32 c = kq[base + t + 2];
            u32 d = kq[base + t + 3];
            m0 = a < m0 ? a : m0;
            m1 = b < m1 ? b : m1;
            m2 = c < m2 ? c : m2;
            m3 = d < m3 ? d : m3;
        }
        m0 = m1 < m0 ? m1 : m0;
        m2 = m3 < m2 ? m3 : m2;
        l1 = m2 < m0 ? m2 : m0;
    }

    int myj = 0;
    for (int r = 0; r < KNBR; ++r) {
        u32 m = wave_min_u32_bcast(l1);              // current global min
        u64 gmask = __ballot(l1 == m);
        int g = __builtin_ctzll(gmask);              // lowest group
        u32 v = kq[g * 65 + lane];                   // rescan group g
        u64 wmask = __ballot(v == m);
        int jl = __builtin_ctzll(wmask);             // lowest index in group
        if (lane == jl) kq[g * 65 + jl] = 0xFFFFFFFFu;
        u32 v2 = (lane == jl) ? 0xFFFFFFFFu : v;
        u32 nm = wave_min_u32_bcast(v2);             // recomputed group min
        if (lane == g) l1 = nm;
        if (lane == r) myj = (g << 6) | jl;
    }
    if (lane < KNBR) nnOut[lane] = myj;
}

// Fallback (round-6) fused topk for the non-MFMA path.
__global__ __launch_bounds__(128) void topk_all_kernel(const float* __restrict__ embA,
                                                       const float* __restrict__ sqA,
                                                       const float* __restrict__ embB,
                                                       const float* __restrict__ sqB,
                                                       int* __restrict__ nnA,
                                                       int* __restrict__ nnB) {
    const int side = blockIdx.x >> 11;
    const int q0 = (blockIdx.x & 2047) * 2;
    const float* embQ = side ? embB : embA;
    const float* embC = side ? embA : embB;
    const float* sqCc = side ? sqA : sqB;
    int* nnOut = side ? nnB : nnA;

    __shared__ u32 keys[2][64 * 65];

    const int tid = threadIdx.x;
    const int lane = tid & 63, w = tid >> 6;

    float4 q0v[8], q1v[8];
    {
        const float4* e0 = (const float4*)(embQ + (size_t)q0 * 32);
        const float4* e1 = (const float4*)(embQ + (size_t)(q0 + 1) * 32);
#pragma unroll
        for (int c = 0; c < 8; ++c) { q0v[c] = e0[c]; q1v[c] = e1[c]; }
    }

    for (int i = 0; i < 32; ++i) {
        int j = (i << 7) + tid;
        const float4* ec = (const float4*)(embC + (size_t)j * 32);
        float d0 = 0.f, d1 = 0.f;
#pragma unroll
        for (int c = 0; c < 8; ++c) {
            float4 cv = ec[c];
            d0 += q0v[c].x * cv.x + q0v[c].y * cv.y + q0v[c].z * cv.z + q0v[c].w * cv.w;
            d1 += q1v[c].x * cv.x + q1v[c].y * cv.y + q1v[c].z * cv.z + q1v[c].w * cv.w;
        }
        float sc = sqCc[j];
        int off = (j >> 6) * 65 + (j & 63);
        keys[0][off] = fkey(sc - 2.f * d0);
        keys[1][off] = fkey(sc - 2.f * d1);
    }
    __syncthreads();

    volatile u32* kq = (volatile u32*)&keys[w][0];

    u32 l1;
    {
        const int base = lane * 65;
        u32 m0 = 0xFFFFFFFFu, m1 = 0xFFFFFFFFu, m2 = 0xFFFFFFFFu, m3 = 0xFFFFFFFFu;
#pragma unroll
        for (int t = 0; t < 64; t += 4) {
            u32 a = kq[base + t + 0];
            u32 b = kq[base + t + 1];
            u32 c = kq[base + t + 2];
            u32 d = kq[base + t + 3];
            m0 = a < m0 ? a : m0;
            m1 = b < m1 ? b : m1;
            m2 = c < m2 ? c : m2;
            m3 = d < m3 ? d : m3;
        }
        m0 = m1 < m0 ? m1 : m0;
        m2 = m3 < m2 ? m3 : m2;
        l1 = m2 < m0 ? m2 : m0;
    }

    int myj = 0;
    for (int r = 0; r < KNBR; ++r) {
        u32 m = wave_min_u32_bcast(l1);
        u64 gmask = __ballot(l1 == m);
        int g = __builtin_ctzll(gmask);
        u32 v = kq[g * 65 + lane];
        u64 wmask = __ballot(v == m);
        int jl = __builtin_ctzll(wmask);
        if (lane == jl) kq[g * 65 + jl] = 0xFFFFFFFFu;
        u32 v2 = (lane == jl) ? 0xFFFFFFFFu : v;
        u32 nm = wave_min_u32_bcast(v2);
        if (lane == g) l1 = nm;
        if (lane == r) myj = (g << 6) | jl;
    }
    if (lane < KNBR) nnOut[(size_t)(q0 + w) * KNBR + lane] = myj;
}

// ---------------------------------------------------------------------------
__global__ __launch_bounds__(256) void predloss_kernel(const int* __restrict__ nn,
                                                       const float* __restrict__ ximp,
                                                       const float* __restrict__ xtrue,
                                                       float* __restrict__ partial) {
    int q = blockIdx.x;
    __shared__ int nns[KNBR];
    __shared__ float red[256];
    if (threadIdx.x < KNBR) nns[threadIdx.x] = nn[(size_t)q * KNBR + threadIdx.x];
    __syncthreads();

    int nr[KNBR];
#pragma unroll
    for (int t = 0; t < KNBR; ++t) nr[t] = nns[t];

    const float inv = 1.0f / KNBR;
    float sse = 0.f;
    for (int v = threadIdx.x; v < 750; v += 256) {
        float4 acc = {0.f, 0.f, 0.f, 0.f};
#pragma unroll
        for (int t = 0; t < KNBR; ++t) {
            const float4 w = *(const float4*)(ximp + (size_t)nr[t] * 3000 + v * 4);
            acc.x += w.x; acc.y += w.y; acc.z += w.z; acc.w += w.w;
        }
        const float4 xt = *(const float4*)(xtrue + (size_t)q * 3000 + v * 4);
        float dx = acc.x * inv - xt.x;
        float dy = acc.y * inv - xt.y;
        float dz = acc.z * inv - xt.z;
        float dw = acc.w * inv - xt.w;
        sse += dx * dx + dy * dy + dz * dz + dw * dw;
    }
    red[threadIdx.x] = sse;
    __syncthreads();
    for (int off = 128; off > 0; off >>= 1) {
        if (threadIdx.x < off) red[threadIdx.x] += red[threadIdx.x + off];
        __syncthreads();
    }
    if (threadIdx.x == 0) partial[q] = red[0];
}

__global__ __launch_bounds__(256) void loss_final_kernel(const float* __restrict__ pA,
                                                         const float* __restrict__ pB,
                                                         float* __restrict__ out) {
    __shared__ double red[256];
    double sa = 0.0, sb = 0.0;
    for (int i = threadIdx.x; i < 4096; i += 256) {
        sa += (double)pA[i];
        sb += (double)pB[i];
    }
    red[threadIdx.x] = sa;
    __syncthreads();
    for (int off = 128; off > 0; off >>= 1) {
        if (threadIdx.x < off) red[threadIdx.x] += red[threadIdx.x + off];
        __syncthreads();
    }
    double totA = red[0];
    __syncthreads();
    red[threadIdx.x] = sb;
    __syncthreads();
    for (int off = 128; off > 0; off >>= 1) {
        if (threadIdx.x < off) red[threadIdx.x] += red[threadIdx.x + off];
        __syncthreads();
    }
    if (threadIdx.x == 0) {
        double denom = 4096.0 * 3000.0;
        out[0] = (float)(totA / denom + red[0] / denom);
    }
}

// ---------------------------------------------------------------------------
extern "C" void kernel_launch(void* const* d_in, const int* in_sizes, int n_in,
                              void* d_out, int out_size, void* d_ws, size_t ws_size,
                              hipStream_t stream) {
    const float* x_A = (const float*)d_in[0];
    const float* x_B = (const float*)d_in[1];
    const float* G   = (const float*)d_in[2];
    const float* W1  = (const float*)d_in[3];
    const float* b1  = (const float*)d_in[4];
    const float* W2  = (const float*)d_in[5];
    const float* b2  = (const float*)d_in[6];
    const float* WcA = (const float*)d_in[7];
    const float* bcA = (const float*)d_in[8];
    const float* WcB = (const float*)d_in[9];
    const float* bcB = (const float*)d_in[10];

    float* outp = (float*)d_out;

    size_t off = 0;
    char* base = (char*)d_ws;
    auto carve = [&](size_t bytes) -> void* {
        void* p = base + off;
        off = (off + bytes + 255) & ~(size_t)255;
        return p;
    };
    float* ximpA = (float*)carve((size_t)N_A * G_B * 4);
    float* ximpB = (float*)carve((size_t)N_B * G_A * 4);
    float* normA = (float*)carve(G_A * 4);
    float* normB = (float*)carve(G_B * 4);
    float* colpart = (float*)carve(25 * G_B * 4);
    float* embA = (float*)carve((size_t)N_A * 32 * 4);
    float* embB = (float*)carve((size_t)N_B * 32 * 4);
    float* sqA = (float*)carve(N_A * 4);
    float* sqB = (float*)carve(N_B * 4);
    float* partA = (float*)carve(N_A * 4);
    float* partB = (float*)carve(N_B * 4);
    int* nnA = (int*)carve((size_t)N_A * KNBR * 4);
    int* nnB = (int*)carve((size_t)N_B * KNBR * 4);
    u16* xAbf = (u16*)carve((size_t)N_A * KPAD * 2);
    u16* xBbf = (u16*)carve((size_t)N_B * KPAD * 2);
    u16* Gbf  = (u16*)carve((size_t)KPAD * KPAD * 2);
    u16* Gtbf = (u16*)carve((size_t)KPAD * KPAD * 2);
    size_t r2_needed = off;
    u16* ximpAbf = (u16*)carve((size_t)N_A * KPAD * 2);
    u16* ximpBbf = (u16*)carve((size_t)N_B * KPAD * 2);
    u16* W1tbf   = (u16*)carve((size_t)64 * KMLP * 2);
    float* mlppart = (float*)carve((size_t)4 * 8192 * 64 * 4);
    size_t full_needed = off;

    // Key matrices (134 MB) alias the bf16 staging region (dead after mlp1):
    // region [xAbf, full_needed) is ~147 MB.
    u32* keyAm = (u32*)xAbf;
    u32* keyBm = keyAm + (size_t)4096 * 4096;

    const bool use_mfma = (ws_size >= r2_needed);
    const bool use_mlp_mfma = (ws_size >= full_needed);

    // 1) normalizers
    row_sum_kernel<<<G_A, 256, 0, stream>>>(G, normA);
    col_partial_kernel<<<dim3(12, 25), 256, 0, stream>>>(G, colpart);
    col_final_kernel<<<12, 256, 0, stream>>>(colpart, normB);

    // 2) imputation GEMMs (+ bf16 copies)
    if (use_mfma && use_mlp_mfma) {
        convert_pad_kernel<<<(N_A * (KPAD / 8)) / 256, 256, 0, stream>>>(x_A, xAbf, N_A, G_A, KPAD);
        convert_pad_kernel<<<(N_B * (KPAD / 8)) / 256, 256, 0, stream>>>(x_B, xBbf, N_B, G_B, KPAD);
        convert_pad_kernel<<<(KPAD * (KPAD / 8)) / 256, 256, 0, stream>>>(G, Gbf, G_A, G_B, KPAD);
        transpose_convert_kernel<<<dim3(96, 96), 256, 0, stream>>>(G, Gtbf);
        w1t_kernel<<<(64 * KMLP) / 256, 256, 0, stream>>>(W1, W1tbf);

        dim3 ggrid(KPAD / 128, N_A / 128);
        mfma_impute_gemm<<<ggrid, 256, 0, stream>>>(xAbf, Gtbf, normB, ximpA, ximpAbf);
        mfma_impute_gemm<<<ggrid, 256, 0, stream>>>(xBbf, Gbf, normA, ximpB, ximpBbf);

        // 3) MLP via MFMA + K-split
        mlp1_kernel<<<dim3(4, 128), 256, 0, stream>>>(xAbf, ximpAbf, ximpBbf, xBbf, W1tbf, mlppart);
        mlp2_kernel<<<128, 256, 0, stream>>>(mlppart, b1, W2, b2, embA, embB, sqA, sqB);

        // 5) class predictions -> d_out
        preds_kernel<<<(N_A * NCA) / 256, 256, 0, stream>>>(embA, WcA, bcA, outp, NCA);
        preds_kernel<<<(N_B * NCB) / 256, 256, 0, stream>>>(embB, WcB, bcB, outp + (size_t)N_A * NCA, NCB);

        // 6) top-20: distance-key GEMMs (overwrite dead bf16 buffers) + select
        distkey_gemm<<<dim3(32, 32), 256, 0, stream>>>(embA, embB, sqB, keyAm);
        distkey_gemm<<<dim3(32, 32), 256, 0, stream>>>(embB, embA, sqA, keyBm);
        topk_select<<<8192, 64, 0, stream>>>(keyAm, keyBm, nnA, nnB);
    } else {
        dim3 ggrid(24, 32);
        impute_gemm<false><<<ggrid, 256, 0, stream>>>(x_A, G, normB, ximpA);
        impute_gemm<true><<<ggrid, 256, 0, stream>>>(x_B, G, normA, ximpB);
        mlp_kernel<<<128, 256, 0, stream>>>(x_A, ximpA, ximpB, x_B, W1, b1, W2, b2, embA, embB);
        sqnorm_kernel<<<16, 256, 0, stream>>>(embA, sqA);
        sqnorm_kernel<<<16, 256, 0, stream>>>(embB, sqB);
        preds_kernel<<<(N_A * NCA) / 256, 256, 0, stream>>>(embA, WcA, bcA, outp, NCA);
        preds_kernel<<<(N_B * NCB) / 256, 256, 0, stream>>>(embB, WcB, bcB, outp + (size_t)N_A * NCA, NCB);
        topk_all_kernel<<<4096, 128, 0, stream>>>(embA, sqA, embB, sqB, nnA, nnB);
    }

    // 7) fused gather-mean + MSE partials
    predloss_kernel<<<N_A, 256, 0, stream>>>(nnA, ximpB, x_A, partA);
    predloss_kernel<<<N_B, 256, 0, stream>>>(nnB, ximpA, x_B, partB);

    // 8) final loss
    loss_final_kernel<<<1, 256, 0, stream>>>(partA, partB, outp + (size_t)N_A * NCA + (size_t)N_B * NCB);

    (void)in_sizes; (void)n_in; (void)out_size;
}

// Round 8
// 521.542 us; speedup vs baseline: 3.0436x; 1.4214x over previous
//
#include <hip/hip_runtime.h>
#include <cfloat>
#include <cstddef>
#include <climits>

// Problem constants
#define N_A   4096
#define N_B   4096
#define G_A   3000
#define G_B   3000
#define NCA   30
#define NCB   25
#define KNBR  20
#define KPAD  3072   // K/N padding for MFMA tiles (multiple of 128)
#define KMLP  6144   // padded MLP K ( = 2*KPAD )

typedef unsigned short u16;
typedef unsigned int u32;
typedef unsigned long long u64;
typedef __bf16 bf16x8 __attribute__((ext_vector_type(8)));
typedef float f32x4 __attribute__((ext_vector_type(4)));
typedef __attribute__((address_space(1))) const void* as1_cvp;
typedef __attribute__((address_space(3))) void* as3_vp;

static __device__ __forceinline__ u16 f2bf(float f) {
    union { float f; unsigned u; } v; v.f = f;
    unsigned r = v.u + 0x7fffu + ((v.u >> 16) & 1u);   // RTNE
    return (u16)(r >> 16);
}

static __device__ __forceinline__ float bf2f(u16 h) {
    union { unsigned u; float f; } v; v.u = ((unsigned)h) << 16;
    return v.f;
}

// monotonic float -> u32 key (ascending float == ascending unsigned)
static __device__ __forceinline__ u32 fkey(float f) {
    union { float f; u32 u; } v; v.f = f;
    return (v.u & 0x80000000u) ? ~v.u : (v.u | 0x80000000u);
}

// 64-lane min-reduce via DPP + broadcast (lane 63 holds global min).
static __device__ __forceinline__ u32 wave_min_u32_bcast(u32 v) {
    u32 t;
    t = (u32)__builtin_amdgcn_update_dpp((int)v, (int)v, 0x111, 0xf, 0xf, false); v = t < v ? t : v;
    t = (u32)__builtin_amdgcn_update_dpp((int)v, (int)v, 0x112, 0xf, 0xf, false); v = t < v ? t : v;
    t = (u32)__builtin_amdgcn_update_dpp((int)v, (int)v, 0x114, 0xf, 0xf, false); v = t < v ? t : v;
    t = (u32)__builtin_amdgcn_update_dpp((int)v, (int)v, 0x118, 0xf, 0xf, false); v = t < v ? t : v;
    t = (u32)__builtin_amdgcn_update_dpp((int)v, (int)v, 0x142, 0xf, 0xf, false); v = t < v ? t : v;
    t = (u32)__builtin_amdgcn_update_dpp((int)v, (int)v, 0x143, 0xf, 0xf, false); v = t < v ? t : v;
    return (u32)__builtin_amdgcn_readlane((int)v, 63);
}

// ---------------------------------------------------------------------------
// normalizers
__global__ __launch_bounds__(256) void row_sum_kernel(const float* __restrict__ G,
                                                      float* __restrict__ normA) {
    int row = blockIdx.x;
    __shared__ float red[256];
    float s = 0.f;
    for (int j = threadIdx.x; j < G_B; j += 256) s += G[(size_t)row * G_B + j];
    red[threadIdx.x] = s;
    __syncthreads();
    for (int off = 128; off > 0; off >>= 1) {
        if (threadIdx.x < off) red[threadIdx.x] += red[threadIdx.x + off];
        __syncthreads();
    }
    if (threadIdx.x == 0) {
        float v = red[0];
        normA[row] = (v == 0.f) ? 1.f : v;
    }
}

__global__ __launch_bounds__(256) void col_partial_kernel(const float* __restrict__ G,
                                                          float* __restrict__ part) {
    int j = blockIdx.x * 256 + threadIdx.x;
    if (j >= G_B) return;
    int r0 = blockIdx.y * 120;
    float s = 0.f;
    for (int i = r0; i < r0 + 120; ++i) s += G[(size_t)i * G_B + j];
    part[(size_t)blockIdx.y * G_B + j] = s;
}

__global__ __launch_bounds__(256) void col_final_kernel(const float* __restrict__ part,
                                                        float* __restrict__ normB) {
    int j = blockIdx.x * 256 + threadIdx.x;
    if (j >= G_B) return;
    float s = 0.f;
    for (int c = 0; c < 25; ++c) s += part[(size_t)c * G_B + j];
    normB[j] = (s == 0.f) ? 1.f : s;
}

// ---------------------------------------------------------------------------
// f32 -> bf16 convert with zero padding
__global__ __launch_bounds__(256) void convert_pad_kernel(const float* __restrict__ in,
                                                          u16* __restrict__ out,
                                                          int in_rows, int in_cols,
                                                          int out_cols) {
    int idx = blockIdx.x * 256 + threadIdx.x;
    int cpr = out_cols >> 3;
    int r = idx / cpr, c0 = (idx % cpr) << 3;
    u16 res[8] = {0, 0, 0, 0, 0, 0, 0, 0};
    if (r < in_rows && c0 + 8 <= in_cols) {
        float4 v0 = *(const float4*)(in + (size_t)r * in_cols + c0);
        float4 v1 = *(const float4*)(in + (size_t)r * in_cols + c0 + 4);
        res[0] = f2bf(v0.x); res[1] = f2bf(v0.y); res[2] = f2bf(v0.z); res[3] = f2bf(v0.w);
        res[4] = f2bf(v1.x); res[5] = f2bf(v1.y); res[6] = f2bf(v1.z); res[7] = f2bf(v1.w);
    }
    uint4 pack;
    pack.x = (unsigned)res[0] | ((unsigned)res[1] << 16);
    pack.y = (unsigned)res[2] | ((unsigned)res[3] << 16);
    pack.z = (unsigned)res[4] | ((unsigned)res[5] << 16);
    pack.w = (unsigned)res[6] | ((unsigned)res[7] << 16);
    *(uint4*)(out + (size_t)r * out_cols + c0) = pack;
}

// G -> Gbf (straight) + Gt (transposed), both bf16 padded to [KPAD][KPAD].
// Reads G once through 32x32 LDS tiles. grid (96,96), 256 thr.
__global__ __launch_bounds__(256) void g_convert_dual_kernel(const float* __restrict__ G,
                                                             u16* __restrict__ Gbf,
                                                             u16* __restrict__ Gt) {
    __shared__ float t[32][33];
    int j0 = blockIdx.x * 32, k0 = blockIdx.y * 32;
    int lx = threadIdx.x & 31, ly = threadIdx.x >> 5;
#pragma unroll
    for (int i = 0; i < 4; ++i) {
        int k = k0 + ly + i * 8, j = j0 + lx;
        float v = (k < G_A && j < G_B) ? G[(size_t)k * G_B + j] : 0.f;
        t[ly + i * 8][lx] = v;
        Gbf[(size_t)k * KPAD + j] = f2bf(v);
    }
    __syncthreads();
#pragma unroll
    for (int i = 0; i < 4; ++i) {
        int j = j0 + ly + i * 8, k = k0 + lx;
        Gt[(size_t)j * KPAD + k] = f2bf(t[lx][ly + i * 8]);
    }
}

// W1 [6000][64] f32 -> W1t [64][KMLP] bf16
__global__ __launch_bounds__(256) void w1t_kernel(const float* __restrict__ W1,
                                                  u16* __restrict__ W1t) {
    int idx = blockIdx.x * 256 + threadIdx.x;
    int n = idx / KMLP, kp = idx % KMLP;
    int seg = kp >= KPAD;
    int k = kp - (seg ? KPAD : 0);
    float v = (k < 3000) ? W1[(size_t)(seg * 3000 + k) * 64 + n] : 0.f;
    W1t[(size_t)n * KMLP + kp] = f2bf(v);
}

// ---------------------------------------------------------------------------
// Merged bf16 MFMA imputation GEMM, both directions in one launch:
// z=0: ximpAbf[i][j] = bf16((sum_k xA[i][k] Gt[j][k]) / normB[j])
// z=1: ximpBbf[i][j] = bf16((sum_k xB[i][k] G [j][k]) / normA[j])
// Output bf16 only (predloss + MLP both consume bf16). grid (24,32,2).
__global__ __launch_bounds__(256) void mfma_impute2_gemm(const u16* __restrict__ xAbf,
                                                         const u16* __restrict__ xBbf,
                                                         const u16* __restrict__ Gtbf,
                                                         const u16* __restrict__ Gbf,
                                                         const float* __restrict__ normB,
                                                         const float* __restrict__ normA,
                                                         u16* __restrict__ ximpAbf,
                                                         u16* __restrict__ ximpBbf) {
    const int side = blockIdx.z;
    const u16* A  = side ? xBbf : xAbf;
    const u16* Bt = side ? Gbf : Gtbf;
    const float* norm = side ? normA : normB;
    u16* outbf = side ? ximpBbf : ximpAbf;

    __shared__ __align__(16) u16 lAs[128 * 64];
    __shared__ __align__(16) u16 lBs[128 * 64];

    const int tid = threadIdx.x;
    const int w = tid >> 6, lane = tid & 63;
    const int row_base = blockIdx.y * 128;
    const int col_base = blockIdx.x * 128;
    const int wr = (w >> 1) * 64, wc = (w & 1) * 64;

    f32x4 acc[4][4] = {};

    int s_r[4], s_off[4];
#pragma unroll
    for (int i = 0; i < 4; ++i) {
        int slin = (w * 4 + i) * 64 + lane;
        int r = slin >> 3, s = slin & 7;
        s_r[i] = r;
        s_off[i] = (s ^ (r & 7)) * 8;
    }

    for (int k0 = 0; k0 < KPAD; k0 += 64) {
#pragma unroll
        for (int i = 0; i < 4; ++i) {
            const u16* ga = A + (size_t)(row_base + s_r[i]) * KPAD + k0 + s_off[i];
            __builtin_amdgcn_global_load_lds((as1_cvp)ga,
                (as3_vp)(lAs + (size_t)(w * 4 + i) * 512), 16, 0, 0);
        }
#pragma unroll
        for (int i = 0; i < 4; ++i) {
            const u16* gb = Bt + (size_t)(col_base + s_r[i]) * KPAD + k0 + s_off[i];
            __builtin_amdgcn_global_load_lds((as1_cvp)gb,
                (as3_vp)(lBs + (size_t)(w * 4 + i) * 512), 16, 0, 0);
        }
        __syncthreads();

#pragma unroll
        for (int kk = 0; kk < 2; ++kk) {
            bf16x8 a[4], b[4];
#pragma unroll
            for (int m = 0; m < 4; ++m) {
                int row = wr + m * 16 + (lane & 15);
                int slot = (kk * 4 + (lane >> 4)) ^ (row & 7);
                a[m] = *(const bf16x8*)(lAs + row * 64 + slot * 8);
            }
#pragma unroll
            for (int n = 0; n < 4; ++n) {
                int row = wc + n * 16 + (lane & 15);
                int slot = (kk * 4 + (lane >> 4)) ^ (row & 7);
                b[n] = *(const bf16x8*)(lBs + row * 64 + slot * 8);
            }
#pragma unroll
            for (int m = 0; m < 4; ++m)
#pragma unroll
                for (int n = 0; n < 4; ++n)
                    acc[m][n] = __builtin_amdgcn_mfma_f32_16x16x32_bf16(a[m], b[n], acc[m][n], 0, 0, 0);
        }
        __syncthreads();
    }

#pragma unroll
    for (int n = 0; n < 4; ++n) {
        int col = col_base + wc + n * 16 + (lane & 15);
        bool valid = col < G_B;
        float rn = valid ? 1.0f / norm[col] : 0.f;
#pragma unroll
        for (int m = 0; m < 4; ++m) {
            int row = row_base + wr + m * 16 + (lane >> 4) * 4;
#pragma unroll
            for (int r = 0; r < 4; ++r)
                outbf[(size_t)(row + r) * KPAD + col] = f2bf(acc[m][n][r] * rn);
        }
    }
}

// ---------------------------------------------------------------------------
// MLP layer 1 (bf16 MFMA, K-split)
__global__ __launch_bounds__(256) void mlp1_kernel(const u16* __restrict__ xAbf,
                                                   const u16* __restrict__ ximpAbf,
                                                   const u16* __restrict__ ximpBbf,
                                                   const u16* __restrict__ xBbf,
                                                   const u16* __restrict__ W1t,
                                                   float* __restrict__ partial) {
    const int chunk = blockIdx.x;
    const int rb = blockIdx.y;
    const int side = rb >> 6;
    const int r0 = (rb & 63) * 64;
    const int seg = chunk >> 1;
    const u16* src = side ? (seg ? xBbf : ximpBbf) : (seg ? ximpAbf : xAbf);
    const int k0base = (chunk & 1) * 1536;

    __shared__ __align__(16) u16 lAs[64 * 64];
    __shared__ __align__(16) u16 lBs[64 * 64];

    const int tid = threadIdx.x;
    const int w = tid >> 6, lane = tid & 63;

    int s_r[2], s_off[2];
#pragma unroll
    for (int i = 0; i < 2; ++i) {
        int slin = (w * 2 + i) * 64 + lane;
        int r = slin >> 3, s = slin & 7;
        s_r[i] = r;
        s_off[i] = (s ^ (r & 7)) * 8;
    }

    f32x4 acc[4] = {};

    for (int k0 = 0; k0 < 1536; k0 += 64) {
#pragma unroll
        for (int i = 0; i < 2; ++i) {
            const u16* ga = src + (size_t)(r0 + s_r[i]) * KPAD + k0base + k0 + s_off[i];
            __builtin_amdgcn_global_load_lds((as1_cvp)ga,
                (as3_vp)(lAs + (size_t)(w * 2 + i) * 512), 16, 0, 0);
        }
#pragma unroll
        for (int i = 0; i < 2; ++i) {
            const u16* gb = W1t + (size_t)s_r[i] * KMLP + chunk * 1536 + k0 + s_off[i];
            __builtin_amdgcn_global_load_lds((as1_cvp)gb,
                (as3_vp)(lBs + (size_t)(w * 2 + i) * 512), 16, 0, 0);
        }
        __syncthreads();

#pragma unroll
        for (int kk = 0; kk < 2; ++kk) {
            int arow = w * 16 + (lane & 15);
            int aslot = (kk * 4 + (lane >> 4)) ^ (arow & 7);
            bf16x8 a = *(const bf16x8*)(lAs + arow * 64 + aslot * 8);
#pragma unroll
            for (int n = 0; n < 4; ++n) {
                int brow = n * 16 + (lane & 15);
                int bslot = (kk * 4 + (lane >> 4)) ^ (brow & 7);
                bf16x8 b = *(const bf16x8*)(lBs + brow * 64 + bslot * 8);
                acc[n] = __builtin_amdgcn_mfma_f32_16x16x32_bf16(a, b, acc[n], 0, 0, 0);
            }
        }
        __syncthreads();
    }

    const size_t grow0 = (size_t)rb * 64;
#pragma unroll
    for (int n = 0; n < 4; ++n) {
        int col = n * 16 + (lane & 15);
        int rowl = w * 16 + (lane >> 4) * 4;
#pragma unroll
        for (int r = 0; r < 4; ++r)
            partial[((size_t)chunk * 8192 + grow0 + rowl + r) * 64 + col] = acc[n][r];
    }
}

// MLP reduce + layer 2 + fused sqnorm
__global__ __launch_bounds__(256) void mlp2_kernel(const float* __restrict__ partial,
                                                   const float* __restrict__ b1,
                                                   const float* __restrict__ W2,
                                                   const float* __restrict__ b2,
                                                   float* __restrict__ embA,
                                                   float* __restrict__ embB,
                                                   float* __restrict__ sqA,
                                                   float* __restrict__ sqB) {
    const int rb = blockIdx.x;
    const int side = rb >> 6;
    const size_t grow0 = (size_t)rb * 64;
    const int r0 = (rb & 63) * 64;
    float* emb = side ? embB : embA;
    float* sq = side ? sqB : sqA;

    __shared__ float Hs[64][65];
    __shared__ float W2s[64][32];
    const int tid = threadIdx.x;

    {
        const float4* srcw = (const float4*)W2;
        float4* dst = (float4*)&W2s[0][0];
        for (int i = tid; i < 512; i += 256) dst[i] = srcw[i];
    }

    for (int v = tid; v < 1024; v += 256) {
        int row = v >> 4, c4 = v & 15;
        float4 s = {0.f, 0.f, 0.f, 0.f};
#pragma unroll
        for (int c = 0; c < 4; ++c) {
            const float4 p = *(const float4*)(partial + ((size_t)c * 8192 + grow0 + row) * 64 + c4 * 4);
            s.x += p.x; s.y += p.y; s.z += p.z; s.w += p.w;
        }
        const float4 bb = *(const float4*)(b1 + c4 * 4);
        Hs[row][c4 * 4 + 0] = fmaxf(s.x + bb.x, 0.f);
        Hs[row][c4 * 4 + 1] = fmaxf(s.y + bb.y, 0.f);
        Hs[row][c4 * 4 + 2] = fmaxf(s.z + bb.z, 0.f);
        Hs[row][c4 * 4 + 3] = fmaxf(s.w + bb.w, 0.f);
    }
    __syncthreads();

    const int c2 = tid & 31, rg = tid >> 5;
    float acc2[8] = {};
    for (int k = 0; k < 64; ++k) {
        float wv = W2s[k][c2];
#pragma unroll
        for (int i = 0; i < 8; ++i) acc2[i] += Hs[rg * 8 + i][k] * wv;
    }
    float bb = b2[c2];
    float e[8];
#pragma unroll
    for (int i = 0; i < 8; ++i) {
        e[i] = fmaxf(acc2[i] + bb, 0.f);
        emb[(size_t)(r0 + rg * 8 + i) * 32 + c2] = e[i];
    }
#pragma unroll
    for (int i = 0; i < 8; ++i) {
        float v = e[i] * e[i];
#pragma unroll
        for (int off = 16; off > 0; off >>= 1) v += __shfl_xor(v, off, 32);
        if (c2 == 0) sq[r0 + rg * 8 + i] = v;
    }
}

// ---------------------------------------------------------------------------
// Fallback f32 GEMM
template <bool TRANSB>
__global__ __launch_bounds__(256) void impute_gemm(const float* __restrict__ X,
                                                   const float* __restrict__ G,
                                                   const float* __restrict__ norm,
                                                   float* __restrict__ out) {
    __shared__ float As[8][128];
    __shared__ float Bs[8][128];
    const int tid = threadIdx.x;
    const int col_base = blockIdx.x * 128;
    const int row_base = blockIdx.y * 128;
    const int tx = tid & 15;
    const int ty = tid >> 4;
    float acc[8][8] = {};
    const int a_row = tid >> 1;
    const int a_k   = (tid & 1) * 4;
    for (int k0 = 0; k0 < G_B; k0 += 8) {
        {
            float4 av = *(const float4*)(X + (size_t)(row_base + a_row) * G_B + k0 + a_k);
            As[a_k + 0][a_row] = av.x;
            As[a_k + 1][a_row] = av.y;
            As[a_k + 2][a_row] = av.z;
            As[a_k + 3][a_row] = av.w;
        }
        if (!TRANSB) {
            const int bk = tid >> 5;
            const int bc = (tid & 31) * 4;
            float4 bv = {0.f, 0.f, 0.f, 0.f};
            if (col_base + bc < G_B)
                bv = *(const float4*)(G + (size_t)(k0 + bk) * G_B + col_base + bc);
            *(float4*)&Bs[bk][bc] = bv;
        } else {
            const int bj = tid >> 1;
            const int bk = (tid & 1) * 4;
            float4 bv = {0.f, 0.f, 0.f, 0.f};
            if (col_base + bj < G_B)
                bv = *(const float4*)(G + (size_t)(col_base + bj) * G_B + k0 + bk);
            Bs[bk + 0][bj] = bv.x;
            Bs[bk + 1][bj] = bv.y;
            Bs[bk + 2][bj] = bv.z;
            Bs[bk + 3][bj] = bv.w;
        }
        __syncthreads();
#pragma unroll
        for (int kk = 0; kk < 8; ++kk) {
            float4 a0 = *(const float4*)&As[kk][ty * 8];
            float4 a1 = *(const float4*)&As[kk][ty * 8 + 4];
            float4 b0 = *(const float4*)&Bs[kk][tx * 8];
            float4 b1 = *(const float4*)&Bs[kk][tx * 8 + 4];
            float a_[8] = {a0.x, a0.y, a0.z, a0.w, a1.x, a1.y, a1.z, a1.w};
            float b_[8] = {b0.x, b0.y, b0.z, b0.w, b1.x, b1.y, b1.z, b1.w};
#pragma unroll
            for (int i = 0; i < 8; ++i)
#pragma unroll
                for (int j = 0; j < 8; ++j) acc[i][j] += a_[i] * b_[j];
        }
        __syncthreads();
    }
    const int cg = col_base + tx * 8;
    if (cg < G_B) {
        float rn[8];
#pragma unroll
        for (int j = 0; j < 8; ++j) rn[j] = 1.0f / norm[cg + j];
#pragma unroll
        for (int i = 0; i < 8; ++i) {
            float4 o0 = {acc[i][0] * rn[0], acc[i][1] * rn[1], acc[i][2] * rn[2], acc[i][3] * rn[3]};
            float4 o1 = {acc[i][4] * rn[4], acc[i][5] * rn[5], acc[i][6] * rn[6], acc[i][7] * rn[7]};
            size_t o = (size_t)(row_base + ty * 8 + i) * G_B + cg;
            *(float4*)(out + o) = o0;
            *(float4*)(out + o + 4) = o1;
        }
    }
}

// Fallback MLP (f32)
#define MLP_TK 24
__global__ __launch_bounds__(256) void mlp_kernel(const float* __restrict__ xA,
                                                  const float* __restrict__ ximpA,
                                                  const float* __restrict__ ximpB,
                                                  const float* __restrict__ xB,
                                                  const float* __restrict__ W1,
                                                  const float* __restrict__ b1,
                                                  const float* __restrict__ W2,
                                                  const float* __restrict__ b2,
                                                  float* __restrict__ embA,
                                                  float* __restrict__ embB) {
    __shared__ float Xs[MLP_TK][64];
    __shared__ float Ws[MLP_TK][64];
    __shared__ float Hs[64][65];
    __shared__ float W2s[64][32];

    const int side = blockIdx.x >> 6;
    const int row0 = (blockIdx.x & 63) * 64;
    const float* srcL = side ? ximpB : xA;
    const float* srcR = side ? xB : ximpA;
    float* emb = side ? embB : embA;

    const int tid = threadIdx.x;
    {
        const float4* src = (const float4*)W2;
        float4* dst = (float4*)&W2s[0][0];
        for (int i = tid; i < 512; i += 256) dst[i] = src[i];
    }

    const int tx = tid & 15;
    const int ty = tid >> 4;
    float acc[4][4] = {};
    const int lrow = tid >> 2;
    const int lk6  = (tid & 3) * 6;

    for (int k0 = 0; k0 < 6000; k0 += MLP_TK) {
        const float* src = (k0 < 3000) ? srcL : srcR;
        const int kbase = (k0 < 3000) ? k0 : (k0 - 3000);
        {
            const float* p = src + (size_t)(row0 + lrow) * 3000 + kbase + lk6;
#pragma unroll
            for (int e = 0; e < 6; ++e) Xs[lk6 + e][lrow] = p[e];
        }
        {
#pragma unroll
            for (int e = 0; e < 6; ++e) {
                int idx = tid * 6 + e;
                int kk = idx >> 6, cc = idx & 63;
                Ws[kk][cc] = W1[(size_t)(k0 + kk) * 64 + cc];
            }
        }
        __syncthreads();
#pragma unroll
        for (int kk = 0; kk < MLP_TK; ++kk) {
            float4 a = *(const float4*)&Xs[kk][ty * 4];
            float4 wv = *(const float4*)&Ws[kk][tx * 4];
            float a_[4] = {a.x, a.y, a.z, a.w};
            float w_[4] = {wv.x, wv.y, wv.z, wv.w};
#pragma unroll
            for (int i = 0; i < 4; ++i)
#pragma unroll
                for (int j = 0; j < 4; ++j) acc[i][j] += a_[i] * w_[j];
        }
        __syncthreads();
    }

#pragma unroll
    for (int j = 0; j < 4; ++j) {
        float bj = b1[tx * 4 + j];
#pragma unroll
        for (int i = 0; i < 4; ++i) {
            float h = acc[i][j] + bj;
            Hs[ty * 4 + i][tx * 4 + j] = h > 0.f ? h : 0.f;
        }
    }
    __syncthreads();

    const int c2 = tid & 31;
    const int rg = tid >> 5;
    float acc2[8] = {};
    for (int k = 0; k < 64; ++k) {
        float wv = W2s[k][c2];
#pragma unroll
        for (int i = 0; i < 8; ++i) acc2[i] += Hs[rg * 8 + i][k] * wv;
    }
    float bb = b2[c2];
#pragma unroll
    for (int i = 0; i < 8; ++i) {
        float h = acc2[i] + bb;
        emb[(size_t)(row0 + rg * 8 + i) * 32 + c2] = h > 0.f ? h : 0.f;
    }
}

__global__ __launch_bounds__(256) void sqnorm_kernel(const float* __restrict__ emb,
                                                     float* __restrict__ sq) {
    int i = blockIdx.x * 256 + threadIdx.x;
    if (i >= N_A) return;
    const float4* e = (const float4*)(emb + (size_t)i * 32);
    float s = 0.f;
#pragma unroll
    for (int q = 0; q < 8; ++q) {
        float4 v = e[q];
        s += v.x * v.x + v.y * v.y + v.z * v.z + v.w * v.w;
    }
    sq[i] = s;
}

__global__ __launch_bounds__(256) void preds_kernel(const float* __restrict__ emb,
                                                    const float* __restrict__ Wc,
                                                    const float* __restrict__ bc,
                                                    float* __restrict__ out,
                                                    int ncls) {
    int idx = blockIdx.x * 256 + threadIdx.x;
    int row = idx / ncls, c = idx % ncls;
    const float* e = emb + (size_t)row * 32;
    float s = bc[c];
#pragma unroll
    for (int k = 0; k < 32; ++k) s += e[k] * Wc[k * ncls + c];
    out[idx] = s;
}

// ---------------------------------------------------------------------------
// Distance-key GEMM: keys[q][j] = fkey(sqC[j] - 2 * dot(embQ[q], embC[j]))
__global__ __launch_bounds__(256) void distkey_gemm(const float* __restrict__ embQ,
                                                    const float* __restrict__ embC,
                                                    const float* __restrict__ sqC,
                                                    u32* __restrict__ keys) {
    __shared__ float As[32][132];
    __shared__ float Bs[32][132];

    const int tid = threadIdx.x;
    const int row_base = blockIdx.y * 128;
    const int col_base = blockIdx.x * 128;

#pragma unroll
    for (int i = 0; i < 4; ++i) {
        int idx = i * 256 + tid;
        int row = idx >> 3, k4 = (idx & 7) * 4;
        float4 a = *(const float4*)(embQ + (size_t)(row_base + row) * 32 + k4);
        As[k4 + 0][row] = a.x;
        As[k4 + 1][row] = a.y;
        As[k4 + 2][row] = a.z;
        As[k4 + 3][row] = a.w;
        float4 b = *(const float4*)(embC + (size_t)(col_base + row) * 32 + k4);
        Bs[k4 + 0][row] = b.x;
        Bs[k4 + 1][row] = b.y;
        Bs[k4 + 2][row] = b.z;
        Bs[k4 + 3][row] = b.w;
    }
    __syncthreads();

    const int tx = tid & 15, ty = tid >> 4;
    float acc[8][8] = {};
#pragma unroll
    for (int k = 0; k < 32; ++k) {
        float4 a0 = *(const float4*)&As[k][ty * 8];
        float4 a1 = *(const float4*)&As[k][ty * 8 + 4];
        float4 b0 = *(const float4*)&Bs[k][tx * 8];
        float4 b1 = *(const float4*)&Bs[k][tx * 8 + 4];
        float a_[8] = {a0.x, a0.y, a0.z, a0.w, a1.x, a1.y, a1.z, a1.w};
        float b_[8] = {b0.x, b0.y, b0.z, b0.w, b1.x, b1.y, b1.z, b1.w};
#pragma unroll
        for (int i = 0; i < 8; ++i)
#pragma unroll
            for (int j = 0; j < 8; ++j) acc[i][j] += a_[i] * b_[j];
    }

    const int cg = col_base + tx * 8;
    float sc[8];
#pragma unroll
    for (int j = 0; j < 8; ++j) sc[j] = sqC[cg + j];
#pragma unroll
    for (int i = 0; i < 8; ++i) {
        uint4 o0, o1;
        o0.x = fkey(sc[0] - 2.f * acc[i][0]);
        o0.y = fkey(sc[1] - 2.f * acc[i][1]);
        o0.z = fkey(sc[2] - 2.f * acc[i][2]);
        o0.w = fkey(sc[3] - 2.f * acc[i][3]);
        o1.x = fkey(sc[4] - 2.f * acc[i][4]);
        o1.y = fkey(sc[5] - 2.f * acc[i][5]);
        o1.z = fkey(sc[6] - 2.f * acc[i][6]);
        o1.w = fkey(sc[7] - 2.f * acc[i][7]);
        size_t o = (size_t)(row_base + ty * 8 + i) * 4096 + cg;
        *(uint4*)(keys + o) = o0;
        *(uint4*)(keys + o + 4) = o1;
    }
}

// Per-query top-20 extraction from a precomputed key row. One wave per block.
__global__ __launch_bounds__(64) void topk_select(const u32* __restrict__ keys,
                                                  int* __restrict__ nnOut) {
    const int q = blockIdx.x;
    const u32* krow = keys + (size_t)q * 4096;
    int* nn = nnOut + (size_t)q * KNBR;

    __shared__ u32 kbuf[64 * 65];
    const int lane = threadIdx.x;

#pragma unroll 8
    for (int t = 0; t < 64; ++t) kbuf[t * 65 + lane] = krow[t * 64 + lane];

    volatile u32* kq = (volatile u32*)kbuf;

    u32 l1;
    {
        const int base = lane * 65;
        u32 m0 = 0xFFFFFFFFu, m1 = 0xFFFFFFFFu, m2 = 0xFFFFFFFFu, m3 = 0xFFFFFFFFu;
#pragma unroll
        for (int t = 0; t < 64; t += 4) {
            u32 a = kq[base + t + 0];
            u32 b = kq[base + t + 1];
            u32 c = kq[base + t + 2];
            u32 d = kq[base + t + 3];
            m0 = a < m0 ? a : m0;
            m1 = b < m1 ? b : m1;
            m2 = c < m2 ? c : m2;
            m3 = d < m3 ? d : m3;
        }
        m0 = m1 < m0 ? m1 : m0;
        m2 = m3 < m2 ? m3 : m2;
        l1 = m2 < m0 ? m2 : m0;
    }

    int myj = 0;
    for (int r = 0; r < KNBR; ++r) {
        u32 m = wave_min_u32_bcast(l1);
        u64 gmask = __ballot(l1 == m);
        int g = __builtin_ctzll(gmask);
        u32 v = kq[g * 65 + lane];
        u64 wmask = __ballot(v == m);
        int jl = __builtin_ctzll(wmask);
        if (lane == jl) kq[g * 65 + jl] = 0xFFFFFFFFu;
        u32 v2 = (lane == jl) ? 0xFFFFFFFFu : v;
        u32 nm = wave_min_u32_bcast(v2);
        if (lane == g) l1 = nm;
        if (lane == r) myj = (g << 6) | jl;
    }
    if (lane < KNBR) nn[lane] = myj;
}

// Fallback (round-6) fused topk for the non-MFMA path.
__global__ __launch_bounds__(128) void topk_all_kernel(const float* __restrict__ embA,
                                                       const float* __restrict__ sqA,
                                                       const float* __restrict__ embB,
                                                       const float* __restrict__ sqB,
                                                       int* __restrict__ nnA,
                                                       int* __restrict__ nnB) {
    const int side = blockIdx.x >> 11;
    const int q0 = (blockIdx.x & 2047) * 2;
    const float* embQ = side ? embB : embA;
    const float* embC = side ? embA : embB;
    const float* sqCc = side ? sqA : sqB;
    int* nnOut = side ? nnB : nnA;

    __shared__ u32 keys[2][64 * 65];

    const int tid = threadIdx.x;
    const int lane = tid & 63, w = tid >> 6;

    float4 q0v[8], q1v[8];
    {
        const float4* e0 = (const float4*)(embQ + (size_t)q0 * 32);
        const float4* e1 = (const float4*)(embQ + (size_t)(q0 + 1) * 32);
#pragma unroll
        for (int c = 0; c < 8; ++c) { q0v[c] = e0[c]; q1v[c] = e1[c]; }
    }

    for (int i = 0; i < 32; ++i) {
        int j = (i << 7) + tid;
        const float4* ec = (const float4*)(embC + (size_t)j * 32);
        float d0 = 0.f, d1 = 0.f;
#pragma unroll
        for (int c = 0; c < 8; ++c) {
            float4 cv = ec[c];
            d0 += q0v[c].x * cv.x + q0v[c].y * cv.y + q0v[c].z * cv.z + q0v[c].w * cv.w;
            d1 += q1v[c].x * cv.x + q1v[c].y * cv.y + q1v[c].z * cv.z + q1v[c].w * cv.w;
        }
        float sc = sqCc[j];
        int off = (j >> 6) * 65 + (j & 63);
        keys[0][off] = fkey(sc - 2.f * d0);
        keys[1][off] = fkey(sc - 2.f * d1);
    }
    __syncthreads();

    volatile u32* kq = (volatile u32*)&keys[w][0];

    u32 l1;
    {
        const int base = lane * 65;
        u32 m0 = 0xFFFFFFFFu, m1 = 0xFFFFFFFFu, m2 = 0xFFFFFFFFu, m3 = 0xFFFFFFFFu;
#pragma unroll
        for (int t = 0; t < 64; t += 4) {
            u32 a = kq[base + t + 0];
            u32 b = kq[base + t + 1];
            u32 c = kq[base + t + 2];
            u32 d = kq[base + t + 3];
            m0 = a < m0 ? a : m0;
            m1 = b < m1 ? b : m1;
            m2 = c < m2 ? c : m2;
            m3 = d < m3 ? d : m3;
        }
        m0 = m1 < m0 ? m1 : m0;
        m2 = m3 < m2 ? m3 : m2;
        l1 = m2 < m0 ? m2 : m0;
    }

    int myj = 0;
    for (int r = 0; r < KNBR; ++r) {
        u32 m = wave_min_u32_bcast(l1);
        u64 gmask = __ballot(l1 == m);
        int g = __builtin_ctzll(gmask);
        u32 v = kq[g * 65 + lane];
        u64 wmask = __ballot(v == m);
        int jl = __builtin_ctzll(wmask);
        if (lane == jl) kq[g * 65 + jl] = 0xFFFFFFFFu;
        u32 v2 = (lane == jl) ? 0xFFFFFFFFu : v;
        u32 nm = wave_min_u32_bcast(v2);
        if (lane == g) l1 = nm;
        if (lane == r) myj = (g << 6) | jl;
    }
    if (lane < KNBR) nnOut[(size_t)(q0 + w) * KNBR + lane] = myj;
}

// ---------------------------------------------------------------------------
// Fused gather-mean + MSE partials, bf16 ximp, both sides in one launch.
// blocks 0..4095: pred_A (nnA gathers ximpBbf, vs x_A) -> partA
// blocks 4096..8191: pred_B (nnB gathers ximpAbf, vs x_B) -> partB
__global__ __launch_bounds__(256) void predloss_bf16_kernel(const int* __restrict__ nnA,
                                                            const int* __restrict__ nnB,
                                                            const u16* __restrict__ ximpBbf,
                                                            const u16* __restrict__ ximpAbf,
                                                            const float* __restrict__ xA,
                                                            const float* __restrict__ xB,
                                                            float* __restrict__ partA,
                                                            float* __restrict__ partB) {
    const int side = blockIdx.x >> 12;
    const int q = blockIdx.x & 4095;
    const int* nn = (side ? nnB : nnA) + (size_t)q * KNBR;
    const u16* ximp = side ? ximpAbf : ximpBbf;
    const float* xtrue = (side ? xB : xA) + (size_t)q * 3000;
    float* partial = side ? partB : partA;

    __shared__ int nns[KNBR];
    __shared__ float red[256];
    if (threadIdx.x < KNBR) nns[threadIdx.x] = nn[threadIdx.x];
    __syncthreads();

    int nr[KNBR];
#pragma unroll
    for (int t = 0; t < KNBR; ++t) nr[t] = nns[t];

    const float inv = 1.0f / KNBR;
    float sse = 0.f;
    for (int v = threadIdx.x; v < 375; v += 256) {   // 375 chunks of 8 bf16 = 3000 cols
        float acc[8] = {};
#pragma unroll
        for (int t = 0; t < KNBR; ++t) {
            uint4 pk = *(const uint4*)(ximp + (size_t)nr[t] * KPAD + v * 8);
            acc[0] += bf2f((u16)(pk.x & 0xFFFF));
            acc[1] += bf2f((u16)(pk.x >> 16));
            acc[2] += bf2f((u16)(pk.y & 0xFFFF));
            acc[3] += bf2f((u16)(pk.y >> 16));
            acc[4] += bf2f((u16)(pk.z & 0xFFFF));
            acc[5] += bf2f((u16)(pk.z >> 16));
            acc[6] += bf2f((u16)(pk.w & 0xFFFF));
            acc[7] += bf2f((u16)(pk.w >> 16));
        }
        const float4 x0 = *(const float4*)(xtrue + v * 8);
        const float4 x1 = *(const float4*)(xtrue + v * 8 + 4);
        float d0 = acc[0] * inv - x0.x;
        float d1 = acc[1] * inv - x0.y;
        float d2 = acc[2] * inv - x0.z;
        float d3 = acc[3] * inv - x0.w;
        float d4 = acc[4] * inv - x1.x;
        float d5 = acc[5] * inv - x1.y;
        float d6 = acc[6] * inv - x1.z;
        float d7 = acc[7] * inv - x1.w;
        sse += d0 * d0 + d1 * d1 + d2 * d2 + d3 * d3
             + d4 * d4 + d5 * d5 + d6 * d6 + d7 * d7;
    }
    red[threadIdx.x] = sse;
    __syncthreads();
    for (int off = 128; off > 0; off >>= 1) {
        if (threadIdx.x < off) red[threadIdx.x] += red[threadIdx.x + off];
        __syncthreads();
    }
    if (threadIdx.x == 0) partial[q] = red[0];
}

// Fallback f32 predloss
__global__ __launch_bounds__(256) void predloss_kernel(const int* __restrict__ nn,
                                                       const float* __restrict__ ximp,
                                                       const float* __restrict__ xtrue,
                                                       float* __restrict__ partial) {
    int q = blockIdx.x;
    __shared__ int nns[KNBR];
    __shared__ float red[256];
    if (threadIdx.x < KNBR) nns[threadIdx.x] = nn[(size_t)q * KNBR + threadIdx.x];
    __syncthreads();

    int nr[KNBR];
#pragma unroll
    for (int t = 0; t < KNBR; ++t) nr[t] = nns[t];

    const float inv = 1.0f / KNBR;
    float sse = 0.f;
    for (int v = threadIdx.x; v < 750; v += 256) {
        float4 acc = {0.f, 0.f, 0.f, 0.f};
#pragma unroll
        for (int t = 0; t < KNBR; ++t) {
            const float4 w = *(const float4*)(ximp + (size_t)nr[t] * 3000 + v * 4);
            acc.x += w.x; acc.y += w.y; acc.z += w.z; acc.w += w.w;
        }
        const float4 xt = *(const float4*)(xtrue + (size_t)q * 3000 + v * 4);
        float dx = acc.x * inv - xt.x;
        float dy = acc.y * inv - xt.y;
        float dz = acc.z * inv - xt.z;
        float dw = acc.w * inv - xt.w;
        sse += dx * dx + dy * dy + dz * dz + dw * dw;
    }
    red[threadIdx.x] = sse;
    __syncthreads();
    for (int off = 128; off > 0; off >>= 1) {
        if (threadIdx.x < off) red[threadIdx.x] += red[threadIdx.x + off];
        __syncthreads();
    }
    if (threadIdx.x == 0) partial[q] = red[0];
}

__global__ __launch_bounds__(256) void loss_final_kernel(const float* __restrict__ pA,
                                                         const float* __restrict__ pB,
                                                         float* __restrict__ out) {
    __shared__ double red[256];
    double sa = 0.0, sb = 0.0;
    for (int i = threadIdx.x; i < 4096; i += 256) {
        sa += (double)pA[i];
        sb += (double)pB[i];
    }
    red[threadIdx.x] = sa;
    __syncthreads();
    for (int off = 128; off > 0; off >>= 1) {
        if (threadIdx.x < off) red[threadIdx.x] += red[threadIdx.x + off];
        __syncthreads();
    }
    double totA = red[0];
    __syncthreads();
    red[threadIdx.x] = sb;
    __syncthreads();
    for (int off = 128; off > 0; off >>= 1) {
        if (threadIdx.x < off) red[threadIdx.x] += red[threadIdx.x + off];
        __syncthreads();
    }
    if (threadIdx.x == 0) {
        double denom = 4096.0 * 3000.0;
        out[0] = (float)(totA / denom + red[0] / denom);
    }
}

// ---------------------------------------------------------------------------
extern "C" void kernel_launch(void* const* d_in, const int* in_sizes, int n_in,
                              void* d_out, int out_size, void* d_ws, size_t ws_size,
                              hipStream_t stream) {
    const float* x_A = (const float*)d_in[0];
    const float* x_B = (const float*)d_in[1];
    const float* G   = (const float*)d_in[2];
    const float* W1  = (const float*)d_in[3];
    const float* b1  = (const float*)d_in[4];
    const float* W2  = (const float*)d_in[5];
    const float* b2  = (const float*)d_in[6];
    const float* WcA = (const float*)d_in[7];
    const float* bcA = (const float*)d_in[8];
    const float* WcB = (const float*)d_in[9];
    const float* bcB = (const float*)d_in[10];

    float* outp = (float*)d_out;

    size_t off = 0;
    char* base = (char*)d_ws;
    auto carve = [&](size_t bytes) -> void* {
        void* p = base + off;
        off = (off + bytes + 255) & ~(size_t)255;
        return p;
    };
    // f32 ximp buffers: used by the FALLBACK path only; on the bf16 path this
    // 98.4 MB region is dead and hosts the 67 MB distance-key matrix.
    float* ximpA = (float*)carve((size_t)N_A * G_B * 4);
    float* ximpB = (float*)carve((size_t)N_B * G_A * 4);
    float* normA = (float*)carve(G_A * 4);
    float* normB = (float*)carve(G_B * 4);
    float* colpart = (float*)carve(25 * G_B * 4);
    float* embA = (float*)carve((size_t)N_A * 32 * 4);
    float* embB = (float*)carve((size_t)N_B * 32 * 4);
    float* sqA = (float*)carve(N_A * 4);
    float* sqB = (float*)carve(N_B * 4);
    float* partA = (float*)carve(N_A * 4);
    float* partB = (float*)carve(N_B * 4);
    int* nnA = (int*)carve((size_t)N_A * KNBR * 4);
    int* nnB = (int*)carve((size_t)N_B * KNBR * 4);
    u16* xAbf = (u16*)carve((size_t)N_A * KPAD * 2);
    u16* xBbf = (u16*)carve((size_t)N_B * KPAD * 2);
    u16* Gbf  = (u16*)carve((size_t)KPAD * KPAD * 2);
    u16* Gtbf = (u16*)carve((size_t)KPAD * KPAD * 2);
    size_t r2_needed = off;
    u16* ximpAbf = (u16*)carve((size_t)N_A * KPAD * 2);   // live until predloss
    u16* ximpBbf = (u16*)carve((size_t)N_B * KPAD * 2);   // live until predloss
    u16* W1tbf   = (u16*)carve((size_t)64 * KMLP * 2);
    float* mlppart = (float*)carve((size_t)4 * 8192 * 64 * 4);
    size_t full_needed = off;

    // Single key matrix (67 MB) aliases the f32 ximp region (dead on bf16 path).
    u32* keybuf = (u32*)ximpA;

    const bool use_mfma = (ws_size >= full_needed);

    // 1) normalizers
    row_sum_kernel<<<G_A, 256, 0, stream>>>(G, normA);
    col_partial_kernel<<<dim3(12, 25), 256, 0, stream>>>(G, colpart);
    col_final_kernel<<<12, 256, 0, stream>>>(colpart, normB);

    if (use_mfma) {
        // 2) bf16 conversions (G read once for both layouts)
        convert_pad_kernel<<<(N_A * (KPAD / 8)) / 256, 256, 0, stream>>>(x_A, xAbf, N_A, G_A, KPAD);
        convert_pad_kernel<<<(N_B * (KPAD / 8)) / 256, 256, 0, stream>>>(x_B, xBbf, N_B, G_B, KPAD);
        g_convert_dual_kernel<<<dim3(96, 96), 256, 0, stream>>>(G, Gbf, Gtbf);
        w1t_kernel<<<(64 * KMLP) / 256, 256, 0, stream>>>(W1, W1tbf);

        // 3) both imputation GEMMs in ONE launch (bf16 output only)
        mfma_impute2_gemm<<<dim3(KPAD / 128, N_A / 128, 2), 256, 0, stream>>>(
            xAbf, xBbf, Gtbf, Gbf, normB, normA, ximpAbf, ximpBbf);

        // 4) MLP via MFMA + K-split
        mlp1_kernel<<<dim3(4, 128), 256, 0, stream>>>(xAbf, ximpAbf, ximpBbf, xBbf, W1tbf, mlppart);
        mlp2_kernel<<<128, 256, 0, stream>>>(mlppart, b1, W2, b2, embA, embB, sqA, sqB);

        // 5) class predictions -> d_out
        preds_kernel<<<(N_A * NCA) / 256, 256, 0, stream>>>(embA, WcA, bcA, outp, NCA);
        preds_kernel<<<(N_B * NCB) / 256, 256, 0, stream>>>(embB, WcB, bcB, outp + (size_t)N_A * NCA, NCB);

        // 6) top-20 per direction through one key buffer (aliases dead f32 ximp)
        distkey_gemm<<<dim3(32, 32), 256, 0, stream>>>(embA, embB, sqB, keybuf);
        topk_select<<<4096, 64, 0, stream>>>(keybuf, nnA);
        distkey_gemm<<<dim3(32, 32), 256, 0, stream>>>(embB, embA, sqA, keybuf);
        topk_select<<<4096, 64, 0, stream>>>(keybuf, nnB);

        // 7) fused gather-mean + MSE partials (bf16 ximp, both sides)
        predloss_bf16_kernel<<<8192, 256, 0, stream>>>(nnA, nnB, ximpBbf, ximpAbf,
                                                       x_A, x_B, partA, partB);
    } else {
        dim3 ggrid(24, 32);
        impute_gemm<false><<<ggrid, 256, 0, stream>>>(x_A, G, normB, ximpA);
        impute_gemm<true><<<ggrid, 256, 0, stream>>>(x_B, G, normA, ximpB);
        mlp_kernel<<<128, 256, 0, stream>>>(x_A, ximpA, ximpB, x_B, W1, b1, W2, b2, embA, embB);
        sqnorm_kernel<<<16, 256, 0, stream>>>(embA, sqA);
        sqnorm_kernel<<<16, 256, 0, stream>>>(embB, sqB);
        preds_kernel<<<(N_A * NCA) / 256, 256, 0, stream>>>(embA, WcA, bcA, outp, NCA);
        preds_kernel<<<(N_B * NCB) / 256, 256, 0, stream>>>(embB, WcB, bcB, outp + (size_t)N_A * NCA, NCB);
        topk_all_kernel<<<4096, 128, 0, stream>>>(embA, sqA, embB, sqB, nnA, nnB);
        predloss_kernel<<<N_A, 256, 0, stream>>>(nnA, ximpB, x_A, partA);
        predloss_kernel<<<N_B, 256, 0, stream>>>(nnB, ximpA, x_B, partB);
    }

    // 8) final loss
    loss_final_kernel<<<1, 256, 0, stream>>>(partA, partB, outp + (size_t)N_A * NCA + (size_t)N_B * NCB);

    (void)in_sizes; (void)n_in; (void)out_size;
}

// Round 9
// 489.754 us; speedup vs baseline: 3.2412x; 1.0649x over previous
//
#include <hip/hip_runtime.h>
#include <cfloat>
#include <cstddef>
#include <climits>

// Problem constants
#define N_A   4096
#define N_B   4096
#define G_A   3000
#define G_B   3000
#define NCA   30
#define NCB   25
#define KNBR  20
#define KPAD  3072   // K/N padding for MFMA tiles (multiple of 128)
#define KMLP  6144   // padded MLP K ( = 2*KPAD )

typedef unsigned short u16;
typedef unsigned int u32;
typedef unsigned long long u64;
typedef __bf16 bf16x8 __attribute__((ext_vector_type(8)));
typedef float f32x4 __attribute__((ext_vector_type(4)));
typedef __attribute__((address_space(1))) const void* as1_cvp;
typedef __attribute__((address_space(3))) void* as3_vp;

static __device__ __forceinline__ u16 f2bf(float f) {
    union { float f; unsigned u; } v; v.f = f;
    unsigned r = v.u + 0x7fffu + ((v.u >> 16) & 1u);   // RTNE
    return (u16)(r >> 16);
}

static __device__ __forceinline__ float bf2f(u16 h) {
    union { unsigned u; float f; } v; v.u = ((unsigned)h) << 16;
    return v.f;
}

// monotonic float -> u32 key (ascending float == ascending unsigned)
static __device__ __forceinline__ u32 fkey(float f) {
    union { float f; u32 u; } v; v.f = f;
    return (v.u & 0x80000000u) ? ~v.u : (v.u | 0x80000000u);
}

// 64-lane min-reduce via DPP + broadcast (lane 63 holds global min).
static __device__ __forceinline__ u32 wave_min_u32_bcast(u32 v) {
    u32 t;
    t = (u32)__builtin_amdgcn_update_dpp((int)v, (int)v, 0x111, 0xf, 0xf, false); v = t < v ? t : v;
    t = (u32)__builtin_amdgcn_update_dpp((int)v, (int)v, 0x112, 0xf, 0xf, false); v = t < v ? t : v;
    t = (u32)__builtin_amdgcn_update_dpp((int)v, (int)v, 0x114, 0xf, 0xf, false); v = t < v ? t : v;
    t = (u32)__builtin_amdgcn_update_dpp((int)v, (int)v, 0x118, 0xf, 0xf, false); v = t < v ? t : v;
    t = (u32)__builtin_amdgcn_update_dpp((int)v, (int)v, 0x142, 0xf, 0xf, false); v = t < v ? t : v;
    t = (u32)__builtin_amdgcn_update_dpp((int)v, (int)v, 0x143, 0xf, 0xf, false); v = t < v ? t : v;
    return (u32)__builtin_amdgcn_readlane((int)v, 63);
}

// ---------------------------------------------------------------------------
// normalizers (FALLBACK path only; bf16 path fuses these into g_convert)
__global__ __launch_bounds__(256) void row_sum_kernel(const float* __restrict__ G,
                                                      float* __restrict__ normA) {
    int row = blockIdx.x;
    __shared__ float red[256];
    float s = 0.f;
    for (int j = threadIdx.x; j < G_B; j += 256) s += G[(size_t)row * G_B + j];
    red[threadIdx.x] = s;
    __syncthreads();
    for (int off = 128; off > 0; off >>= 1) {
        if (threadIdx.x < off) red[threadIdx.x] += red[threadIdx.x + off];
        __syncthreads();
    }
    if (threadIdx.x == 0) {
        float v = red[0];
        normA[row] = (v == 0.f) ? 1.f : v;
    }
}

__global__ __launch_bounds__(256) void col_partial_kernel(const float* __restrict__ G,
                                                          float* __restrict__ part) {
    int j = blockIdx.x * 256 + threadIdx.x;
    if (j >= G_B) return;
    int r0 = blockIdx.y * 120;
    float s = 0.f;
    for (int i = r0; i < r0 + 120; ++i) s += G[(size_t)i * G_B + j];
    part[(size_t)blockIdx.y * G_B + j] = s;
}

__global__ __launch_bounds__(256) void col_final_kernel(const float* __restrict__ part,
                                                        float* __restrict__ normB) {
    int j = blockIdx.x * 256 + threadIdx.x;
    if (j >= G_B) return;
    float s = 0.f;
    for (int c = 0; c < 25; ++c) s += part[(size_t)c * G_B + j];
    normB[j] = (s == 0.f) ? 1.f : s;
}

// ---------------------------------------------------------------------------
// Merged x_A + x_B f32 -> bf16 convert with zero padding. grid 12288.
__global__ __launch_bounds__(256) void convert_pad2_kernel(const float* __restrict__ xA,
                                                           const float* __restrict__ xB,
                                                           u16* __restrict__ xAbf,
                                                           u16* __restrict__ xBbf) {
    const int half = (N_A * (KPAD / 8)) / 256;   // 6144 blocks per side
    const int side = blockIdx.x >= half;
    const float* in = side ? xB : xA;
    u16* out = side ? xBbf : xAbf;
    int idx = (blockIdx.x - (side ? half : 0)) * 256 + threadIdx.x;
    int cpr = KPAD >> 3;
    int r = idx / cpr, c0 = (idx % cpr) << 3;
    u16 res[8] = {0, 0, 0, 0, 0, 0, 0, 0};
    if (c0 + 8 <= G_A) {
        float4 v0 = *(const float4*)(in + (size_t)r * G_A + c0);
        float4 v1 = *(const float4*)(in + (size_t)r * G_A + c0 + 4);
        res[0] = f2bf(v0.x); res[1] = f2bf(v0.y); res[2] = f2bf(v0.z); res[3] = f2bf(v0.w);
        res[4] = f2bf(v1.x); res[5] = f2bf(v1.y); res[6] = f2bf(v1.z); res[7] = f2bf(v1.w);
    }
    uint4 pack;
    pack.x = (unsigned)res[0] | ((unsigned)res[1] << 16);
    pack.y = (unsigned)res[2] | ((unsigned)res[3] << 16);
    pack.z = (unsigned)res[4] | ((unsigned)res[5] << 16);
    pack.w = (unsigned)res[6] | ((unsigned)res[7] << 16);
    *(uint4*)(out + (size_t)r * KPAD + c0) = pack;
}

// G -> Gbf (straight) + Gt (transposed) bf16, padded; ALSO per-tile partial
// row sums (over j, for normA) and col sums (over k, for normB). G read once.
// grid (96,96), 256 thr. Deterministic (no atomics).
__global__ __launch_bounds__(256) void g_convert_dual_norm_kernel(const float* __restrict__ G,
                                                                  u16* __restrict__ Gbf,
                                                                  u16* __restrict__ Gt,
                                                                  float* __restrict__ rowpart,
                                                                  float* __restrict__ colpart2) {
    __shared__ float t[32][33];
    int j0 = blockIdx.x * 32, k0 = blockIdx.y * 32;
    int lx = threadIdx.x & 31, ly = threadIdx.x >> 5;
#pragma unroll
    for (int i = 0; i < 4; ++i) {
        int k = k0 + ly + i * 8, j = j0 + lx;
        float v = (k < G_A && j < G_B) ? G[(size_t)k * G_B + j] : 0.f;
        t[ly + i * 8][lx] = v;
        Gbf[(size_t)k * KPAD + j] = f2bf(v);
    }
    __syncthreads();
#pragma unroll
    for (int i = 0; i < 4; ++i) {
        int j = j0 + ly + i * 8, k = k0 + lx;
        Gt[(size_t)j * KPAD + k] = f2bf(t[lx][ly + i * 8]);
    }
    // partial sums (conflict-free: addr = r*33+c -> bank (r+c)%32)
    if (threadIdx.x < 32) {
        int kl = threadIdx.x;
        float s = 0.f;
#pragma unroll
        for (int j2 = 0; j2 < 32; ++j2) s += t[kl][j2];
        rowpart[(size_t)blockIdx.x * KPAD + k0 + kl] = s;
    } else if (threadIdx.x < 64) {
        int jl = threadIdx.x - 32;
        float s = 0.f;
#pragma unroll
        for (int k2 = 0; k2 < 32; ++k2) s += t[k2][jl];
        colpart2[(size_t)blockIdx.y * KPAD + j0 + jl] = s;
    }
}

__global__ __launch_bounds__(256) void normA_final_kernel(const float* __restrict__ rowpart,
                                                          float* __restrict__ normA) {
    int k = blockIdx.x * 256 + threadIdx.x;
    if (k >= G_A) return;
    float s = 0.f;
    for (int jt = 0; jt < 96; ++jt) s += rowpart[(size_t)jt * KPAD + k];
    normA[k] = (s == 0.f) ? 1.f : s;
}

__global__ __launch_bounds__(256) void normB_final_kernel(const float* __restrict__ colpart2,
                                                          float* __restrict__ normB) {
    int j = blockIdx.x * 256 + threadIdx.x;
    if (j >= G_B) return;
    float s = 0.f;
    for (int kt = 0; kt < 96; ++kt) s += colpart2[(size_t)kt * KPAD + j];
    normB[j] = (s == 0.f) ? 1.f : s;
}

// W1 [6000][64] f32 -> W1t [64][KMLP] bf16
__global__ __launch_bounds__(256) void w1t_kernel(const float* __restrict__ W1,
                                                  u16* __restrict__ W1t) {
    int idx = blockIdx.x * 256 + threadIdx.x;
    int n = idx / KMLP, kp = idx % KMLP;
    int seg = kp >= KPAD;
    int k = kp - (seg ? KPAD : 0);
    float v = (k < 3000) ? W1[(size_t)(seg * 3000 + k) * 64 + n] : 0.f;
    W1t[(size_t)n * KMLP + kp] = f2bf(v);
}

// ---------------------------------------------------------------------------
// Merged bf16 MFMA imputation GEMM, both directions, XCD-swizzled tiles.
__global__ __launch_bounds__(256) void mfma_impute2_gemm(const u16* __restrict__ xAbf,
                                                         const u16* __restrict__ xBbf,
                                                         const u16* __restrict__ Gtbf,
                                                         const u16* __restrict__ Gbf,
                                                         const float* __restrict__ normB,
                                                         const float* __restrict__ normA,
                                                         u16* __restrict__ ximpAbf,
                                                         u16* __restrict__ ximpBbf) {
    const int side = blockIdx.z;
    const u16* A  = side ? xBbf : xAbf;
    const u16* Bt = side ? Gbf : Gtbf;
    const float* norm = side ? normA : normB;
    u16* outbf = side ? ximpBbf : ximpAbf;

    // XCD-aware bijective swizzle: 768 tiles, 8 XCDs -> each XCD gets a
    // contiguous 96-tile chunk (4 tile-rows of 24).
    const int flat = blockIdx.y * 24 + blockIdx.x;
    const int tile = (flat & 7) * 96 + (flat >> 3);
    const int col_base = (tile % 24) * 128;
    const int row_base = (tile / 24) * 128;

    __shared__ __align__(16) u16 lAs[128 * 64];
    __shared__ __align__(16) u16 lBs[128 * 64];

    const int tid = threadIdx.x;
    const int w = tid >> 6, lane = tid & 63;
    const int wr = (w >> 1) * 64, wc = (w & 1) * 64;

    f32x4 acc[4][4] = {};

    int s_r[4], s_off[4];
#pragma unroll
    for (int i = 0; i < 4; ++i) {
        int slin = (w * 4 + i) * 64 + lane;
        int r = slin >> 3, s = slin & 7;
        s_r[i] = r;
        s_off[i] = (s ^ (r & 7)) * 8;
    }

    for (int k0 = 0; k0 < KPAD; k0 += 64) {
#pragma unroll
        for (int i = 0; i < 4; ++i) {
            const u16* ga = A + (size_t)(row_base + s_r[i]) * KPAD + k0 + s_off[i];
            __builtin_amdgcn_global_load_lds((as1_cvp)ga,
                (as3_vp)(lAs + (size_t)(w * 4 + i) * 512), 16, 0, 0);
        }
#pragma unroll
        for (int i = 0; i < 4; ++i) {
            const u16* gb = Bt + (size_t)(col_base + s_r[i]) * KPAD + k0 + s_off[i];
            __builtin_amdgcn_global_load_lds((as1_cvp)gb,
                (as3_vp)(lBs + (size_t)(w * 4 + i) * 512), 16, 0, 0);
        }
        __syncthreads();

#pragma unroll
        for (int kk = 0; kk < 2; ++kk) {
            bf16x8 a[4], b[4];
#pragma unroll
            for (int m = 0; m < 4; ++m) {
                int row = wr + m * 16 + (lane & 15);
                int slot = (kk * 4 + (lane >> 4)) ^ (row & 7);
                a[m] = *(const bf16x8*)(lAs + row * 64 + slot * 8);
            }
#pragma unroll
            for (int n = 0; n < 4; ++n) {
                int row = wc + n * 16 + (lane & 15);
                int slot = (kk * 4 + (lane >> 4)) ^ (row & 7);
                b[n] = *(const bf16x8*)(lBs + row * 64 + slot * 8);
            }
#pragma unroll
            for (int m = 0; m < 4; ++m)
#pragma unroll
                for (int n = 0; n < 4; ++n)
                    acc[m][n] = __builtin_amdgcn_mfma_f32_16x16x32_bf16(a[m], b[n], acc[m][n], 0, 0, 0);
        }
        __syncthreads();
    }

#pragma unroll
    for (int n = 0; n < 4; ++n) {
        int col = col_base + wc + n * 16 + (lane & 15);
        bool valid = col < G_B;
        float rn = valid ? 1.0f / norm[col] : 0.f;
#pragma unroll
        for (int m = 0; m < 4; ++m) {
            int row = row_base + wr + m * 16 + (lane >> 4) * 4;
#pragma unroll
            for (int r = 0; r < 4; ++r)
                outbf[(size_t)(row + r) * KPAD + col] = f2bf(acc[m][n][r] * rn);
        }
    }
}

// ---------------------------------------------------------------------------
// MLP layer 1 (bf16 MFMA, K-split)
__global__ __launch_bounds__(256) void mlp1_kernel(const u16* __restrict__ xAbf,
                                                   const u16* __restrict__ ximpAbf,
                                                   const u16* __restrict__ ximpBbf,
                                                   const u16* __restrict__ xBbf,
                                                   const u16* __restrict__ W1t,
                                                   float* __restrict__ partial) {
    const int chunk = blockIdx.x;
    const int rb = blockIdx.y;
    const int side = rb >> 6;
    const int r0 = (rb & 63) * 64;
    const int seg = chunk >> 1;
    const u16* src = side ? (seg ? xBbf : ximpBbf) : (seg ? ximpAbf : xAbf);
    const int k0base = (chunk & 1) * 1536;

    __shared__ __align__(16) u16 lAs[64 * 64];
    __shared__ __align__(16) u16 lBs[64 * 64];

    const int tid = threadIdx.x;
    const int w = tid >> 6, lane = tid & 63;

    int s_r[2], s_off[2];
#pragma unroll
    for (int i = 0; i < 2; ++i) {
        int slin = (w * 2 + i) * 64 + lane;
        int r = slin >> 3, s = slin & 7;
        s_r[i] = r;
        s_off[i] = (s ^ (r & 7)) * 8;
    }

    f32x4 acc[4] = {};

    for (int k0 = 0; k0 < 1536; k0 += 64) {
#pragma unroll
        for (int i = 0; i < 2; ++i) {
            const u16* ga = src + (size_t)(r0 + s_r[i]) * KPAD + k0base + k0 + s_off[i];
            __builtin_amdgcn_global_load_lds((as1_cvp)ga,
                (as3_vp)(lAs + (size_t)(w * 2 + i) * 512), 16, 0, 0);
        }
#pragma unroll
        for (int i = 0; i < 2; ++i) {
            const u16* gb = W1t + (size_t)s_r[i] * KMLP + chunk * 1536 + k0 + s_off[i];
            __builtin_amdgcn_global_load_lds((as1_cvp)gb,
                (as3_vp)(lBs + (size_t)(w * 2 + i) * 512), 16, 0, 0);
        }
        __syncthreads();

#pragma unroll
        for (int kk = 0; kk < 2; ++kk) {
            int arow = w * 16 + (lane & 15);
            int aslot = (kk * 4 + (lane >> 4)) ^ (arow & 7);
            bf16x8 a = *(const bf16x8*)(lAs + arow * 64 + aslot * 8);
#pragma unroll
            for (int n = 0; n < 4; ++n) {
                int brow = n * 16 + (lane & 15);
                int bslot = (kk * 4 + (lane >> 4)) ^ (brow & 7);
                bf16x8 b = *(const bf16x8*)(lBs + brow * 64 + bslot * 8);
                acc[n] = __builtin_amdgcn_mfma_f32_16x16x32_bf16(a, b, acc[n], 0, 0, 0);
            }
        }
        __syncthreads();
    }

    const size_t grow0 = (size_t)rb * 64;
#pragma unroll
    for (int n = 0; n < 4; ++n) {
        int col = n * 16 + (lane & 15);
        int rowl = w * 16 + (lane >> 4) * 4;
#pragma unroll
        for (int r = 0; r < 4; ++r)
            partial[((size_t)chunk * 8192 + grow0 + rowl + r) * 64 + col] = acc[n][r];
    }
}

// MLP reduce + layer 2 + fused sqnorm
__global__ __launch_bounds__(256) void mlp2_kernel(const float* __restrict__ partial,
                                                   const float* __restrict__ b1,
                                                   const float* __restrict__ W2,
                                                   const float* __restrict__ b2,
                                                   float* __restrict__ embA,
                                                   float* __restrict__ embB,
                                                   float* __restrict__ sqA,
                                                   float* __restrict__ sqB) {
    const int rb = blockIdx.x;
    const int side = rb >> 6;
    const size_t grow0 = (size_t)rb * 64;
    const int r0 = (rb & 63) * 64;
    float* emb = side ? embB : embA;
    float* sq = side ? sqB : sqA;

    __shared__ float Hs[64][65];
    __shared__ float W2s[64][32];
    const int tid = threadIdx.x;

    {
        const float4* srcw = (const float4*)W2;
        float4* dst = (float4*)&W2s[0][0];
        for (int i = tid; i < 512; i += 256) dst[i] = srcw[i];
    }

    for (int v = tid; v < 1024; v += 256) {
        int row = v >> 4, c4 = v & 15;
        float4 s = {0.f, 0.f, 0.f, 0.f};
#pragma unroll
        for (int c = 0; c < 4; ++c) {
            const float4 p = *(const float4*)(partial + ((size_t)c * 8192 + grow0 + row) * 64 + c4 * 4);
            s.x += p.x; s.y += p.y; s.z += p.z; s.w += p.w;
        }
        const float4 bb = *(const float4*)(b1 + c4 * 4);
        Hs[row][c4 * 4 + 0] = fmaxf(s.x + bb.x, 0.f);
        Hs[row][c4 * 4 + 1] = fmaxf(s.y + bb.y, 0.f);
        Hs[row][c4 * 4 + 2] = fmaxf(s.z + bb.z, 0.f);
        Hs[row][c4 * 4 + 3] = fmaxf(s.w + bb.w, 0.f);
    }
    __syncthreads();

    const int c2 = tid & 31, rg = tid >> 5;
    float acc2[8] = {};
    for (int k = 0; k < 64; ++k) {
        float wv = W2s[k][c2];
#pragma unroll
        for (int i = 0; i < 8; ++i) acc2[i] += Hs[rg * 8 + i][k] * wv;
    }
    float bb = b2[c2];
    float e[8];
#pragma unroll
    for (int i = 0; i < 8; ++i) {
        e[i] = fmaxf(acc2[i] + bb, 0.f);
        emb[(size_t)(r0 + rg * 8 + i) * 32 + c2] = e[i];
    }
#pragma unroll
    for (int i = 0; i < 8; ++i) {
        float v = e[i] * e[i];
#pragma unroll
        for (int off = 16; off > 0; off >>= 1) v += __shfl_xor(v, off, 32);
        if (c2 == 0) sq[r0 + rg * 8 + i] = v;
    }
}

// ---------------------------------------------------------------------------
// Fallback f32 GEMM
template <bool TRANSB>
__global__ __launch_bounds__(256) void impute_gemm(const float* __restrict__ X,
                                                   const float* __restrict__ G,
                                                   const float* __restrict__ norm,
                                                   float* __restrict__ out) {
    __shared__ float As[8][128];
    __shared__ float Bs[8][128];
    const int tid = threadIdx.x;
    const int col_base = blockIdx.x * 128;
    const int row_base = blockIdx.y * 128;
    const int tx = tid & 15;
    const int ty = tid >> 4;
    float acc[8][8] = {};
    const int a_row = tid >> 1;
    const int a_k   = (tid & 1) * 4;
    for (int k0 = 0; k0 < G_B; k0 += 8) {
        {
            float4 av = *(const float4*)(X + (size_t)(row_base + a_row) * G_B + k0 + a_k);
            As[a_k + 0][a_row] = av.x;
            As[a_k + 1][a_row] = av.y;
            As[a_k + 2][a_row] = av.z;
            As[a_k + 3][a_row] = av.w;
        }
        if (!TRANSB) {
            const int bk = tid >> 5;
            const int bc = (tid & 31) * 4;
            float4 bv = {0.f, 0.f, 0.f, 0.f};
            if (col_base + bc < G_B)
                bv = *(const float4*)(G + (size_t)(k0 + bk) * G_B + col_base + bc);
            *(float4*)&Bs[bk][bc] = bv;
        } else {
            const int bj = tid >> 1;
            const int bk = (tid & 1) * 4;
            float4 bv = {0.f, 0.f, 0.f, 0.f};
            if (col_base + bj < G_B)
                bv = *(const float4*)(G + (size_t)(col_base + bj) * G_B + k0 + bk);
            Bs[bk + 0][bj] = bv.x;
            Bs[bk + 1][bj] = bv.y;
            Bs[bk + 2][bj] = bv.z;
            Bs[bk + 3][bj] = bv.w;
        }
        __syncthreads();
#pragma unroll
        for (int kk = 0; kk < 8; ++kk) {
            float4 a0 = *(const float4*)&As[kk][ty * 8];
            float4 a1 = *(const float4*)&As[kk][ty * 8 + 4];
            float4 b0 = *(const float4*)&Bs[kk][tx * 8];
            float4 b1 = *(const float4*)&Bs[kk][tx * 8 + 4];
            float a_[8] = {a0.x, a0.y, a0.z, a0.w, a1.x, a1.y, a1.z, a1.w};
            float b_[8] = {b0.x, b0.y, b0.z, b0.w, b1.x, b1.y, b1.z, b1.w};
#pragma unroll
            for (int i = 0; i < 8; ++i)
#pragma unroll
                for (int j = 0; j < 8; ++j) acc[i][j] += a_[i] * b_[j];
        }
        __syncthreads();
    }
    const int cg = col_base + tx * 8;
    if (cg < G_B) {
        float rn[8];
#pragma unroll
        for (int j = 0; j < 8; ++j) rn[j] = 1.0f / norm[cg + j];
#pragma unroll
        for (int i = 0; i < 8; ++i) {
            float4 o0 = {acc[i][0] * rn[0], acc[i][1] * rn[1], acc[i][2] * rn[2], acc[i][3] * rn[3]};
            float4 o1 = {acc[i][4] * rn[4], acc[i][5] * rn[5], acc[i][6] * rn[6], acc[i][7] * rn[7]};
            size_t o = (size_t)(row_base + ty * 8 + i) * G_B + cg;
            *(float4*)(out + o) = o0;
            *(float4*)(out + o + 4) = o1;
        }
    }
}

// Fallback MLP (f32)
#define MLP_TK 24
__global__ __launch_bounds__(256) void mlp_kernel(const float* __restrict__ xA,
                                                  const float* __restrict__ ximpA,
                                                  const float* __restrict__ ximpB,
                                                  const float* __restrict__ xB,
                                                  const float* __restrict__ W1,
                                                  const float* __restrict__ b1,
                                                  const float* __restrict__ W2,
                                                  const float* __restrict__ b2,
                                                  float* __restrict__ embA,
                                                  float* __restrict__ embB) {
    __shared__ float Xs[MLP_TK][64];
    __shared__ float Ws[MLP_TK][64];
    __shared__ float Hs[64][65];
    __shared__ float W2s[64][32];

    const int side = blockIdx.x >> 6;
    const int row0 = (blockIdx.x & 63) * 64;
    const float* srcL = side ? ximpB : xA;
    const float* srcR = side ? xB : ximpA;
    float* emb = side ? embB : embA;

    const int tid = threadIdx.x;
    {
        const float4* src = (const float4*)W2;
        float4* dst = (float4*)&W2s[0][0];
        for (int i = tid; i < 512; i += 256) dst[i] = src[i];
    }

    const int tx = tid & 15;
    const int ty = tid >> 4;
    float acc[4][4] = {};
    const int lrow = tid >> 2;
    const int lk6  = (tid & 3) * 6;

    for (int k0 = 0; k0 < 6000; k0 += MLP_TK) {
        const float* src = (k0 < 3000) ? srcL : srcR;
        const int kbase = (k0 < 3000) ? k0 : (k0 - 3000);
        {
            const float* p = src + (size_t)(row0 + lrow) * 3000 + kbase + lk6;
#pragma unroll
            for (int e = 0; e < 6; ++e) Xs[lk6 + e][lrow] = p[e];
        }
        {
#pragma unroll
            for (int e = 0; e < 6; ++e) {
                int idx = tid * 6 + e;
                int kk = idx >> 6, cc = idx & 63;
                Ws[kk][cc] = W1[(size_t)(k0 + kk) * 64 + cc];
            }
        }
        __syncthreads();
#pragma unroll
        for (int kk = 0; kk < MLP_TK; ++kk) {
            float4 a = *(const float4*)&Xs[kk][ty * 4];
            float4 wv = *(const float4*)&Ws[kk][tx * 4];
            float a_[4] = {a.x, a.y, a.z, a.w};
            float w_[4] = {wv.x, wv.y, wv.z, wv.w};
#pragma unroll
            for (int i = 0; i < 4; ++i)
#pragma unroll
                for (int j = 0; j < 4; ++j) acc[i][j] += a_[i] * w_[j];
        }
        __syncthreads();
    }

#pragma unroll
    for (int j = 0; j < 4; ++j) {
        float bj = b1[tx * 4 + j];
#pragma unroll
        for (int i = 0; i < 4; ++i) {
            float h = acc[i][j] + bj;
            Hs[ty * 4 + i][tx * 4 + j] = h > 0.f ? h : 0.f;
        }
    }
    __syncthreads();

    const int c2 = tid & 31;
    const int rg = tid >> 5;
    float acc2[8] = {};
    for (int k = 0; k < 64; ++k) {
        float wv = W2s[k][c2];
#pragma unroll
        for (int i = 0; i < 8; ++i) acc2[i] += Hs[rg * 8 + i][k] * wv;
    }
    float bb = b2[c2];
#pragma unroll
    for (int i = 0; i < 8; ++i) {
        float h = acc2[i] + bb;
        emb[(size_t)(row0 + rg * 8 + i) * 32 + c2] = h > 0.f ? h : 0.f;
    }
}

__global__ __launch_bounds__(256) void sqnorm_kernel(const float* __restrict__ emb,
                                                     float* __restrict__ sq) {
    int i = blockIdx.x * 256 + threadIdx.x;
    if (i >= N_A) return;
    const float4* e = (const float4*)(emb + (size_t)i * 32);
    float s = 0.f;
#pragma unroll
    for (int q = 0; q < 8; ++q) {
        float4 v = e[q];
        s += v.x * v.x + v.y * v.y + v.z * v.z + v.w * v.w;
    }
    sq[i] = s;
}

__global__ __launch_bounds__(256) void preds_kernel(const float* __restrict__ emb,
                                                    const float* __restrict__ Wc,
                                                    const float* __restrict__ bc,
                                                    float* __restrict__ out,
                                                    int ncls) {
    int idx = blockIdx.x * 256 + threadIdx.x;
    int row = idx / ncls, c = idx % ncls;
    const float* e = emb + (size_t)row * 32;
    float s = bc[c];
#pragma unroll
    for (int k = 0; k < 32; ++k) s += e[k] * Wc[k * ncls + c];
    out[idx] = s;
}

// ---------------------------------------------------------------------------
// Distance-key GEMM, both directions in one launch (z=0: A->B keys, z=1: B->A).
// keys[q][j] = fkey(sqC[j] - 2 * dot(embQ[q], embC[j]))
__global__ __launch_bounds__(256) void distkey2_gemm(const float* __restrict__ embA,
                                                     const float* __restrict__ embB,
                                                     const float* __restrict__ sqA,
                                                     const float* __restrict__ sqB,
                                                     u32* __restrict__ keyA,
                                                     u32* __restrict__ keyB) {
    const int side = blockIdx.z;
    const float* embQ = side ? embB : embA;
    const float* embC = side ? embA : embB;
    const float* sqC = side ? sqA : sqB;
    u32* keys = side ? keyB : keyA;

    __shared__ float As[32][132];
    __shared__ float Bs[32][132];

    const int tid = threadIdx.x;
    const int row_base = blockIdx.y * 128;
    const int col_base = blockIdx.x * 128;

#pragma unroll
    for (int i = 0; i < 4; ++i) {
        int idx = i * 256 + tid;
        int row = idx >> 3, k4 = (idx & 7) * 4;
        float4 a = *(const float4*)(embQ + (size_t)(row_base + row) * 32 + k4);
        As[k4 + 0][row] = a.x;
        As[k4 + 1][row] = a.y;
        As[k4 + 2][row] = a.z;
        As[k4 + 3][row] = a.w;
        float4 b = *(const float4*)(embC + (size_t)(col_base + row) * 32 + k4);
        Bs[k4 + 0][row] = b.x;
        Bs[k4 + 1][row] = b.y;
        Bs[k4 + 2][row] = b.z;
        Bs[k4 + 3][row] = b.w;
    }
    __syncthreads();

    const int tx = tid & 15, ty = tid >> 4;
    float acc[8][8] = {};
#pragma unroll
    for (int k = 0; k < 32; ++k) {
        float4 a0 = *(const float4*)&As[k][ty * 8];
        float4 a1 = *(const float4*)&As[k][ty * 8 + 4];
        float4 b0 = *(const float4*)&Bs[k][tx * 8];
        float4 b1 = *(const float4*)&Bs[k][tx * 8 + 4];
        float a_[8] = {a0.x, a0.y, a0.z, a0.w, a1.x, a1.y, a1.z, a1.w};
        float b_[8] = {b0.x, b0.y, b0.z, b0.w, b1.x, b1.y, b1.z, b1.w};
#pragma unroll
        for (int i = 0; i < 8; ++i)
#pragma unroll
            for (int j = 0; j < 8; ++j) acc[i][j] += a_[i] * b_[j];
    }

    const int cg = col_base + tx * 8;
    float sc[8];
#pragma unroll
    for (int j = 0; j < 8; ++j) sc[j] = sqC[cg + j];
#pragma unroll
    for (int i = 0; i < 8; ++i) {
        uint4 o0, o1;
        o0.x = fkey(sc[0] - 2.f * acc[i][0]);
        o0.y = fkey(sc[1] - 2.f * acc[i][1]);
        o0.z = fkey(sc[2] - 2.f * acc[i][2]);
        o0.w = fkey(sc[3] - 2.f * acc[i][3]);
        o1.x = fkey(sc[4] - 2.f * acc[i][4]);
        o1.y = fkey(sc[5] - 2.f * acc[i][5]);
        o1.z = fkey(sc[6] - 2.f * acc[i][6]);
        o1.w = fkey(sc[7] - 2.f * acc[i][7]);
        size_t o = (size_t)(row_base + ty * 8 + i) * 4096 + cg;
        *(uint4*)(keys + o) = o0;
        *(uint4*)(keys + o + 4) = o1;
    }
}

// Per-query top-20 extraction, both sides in one launch. One wave per block.
__global__ __launch_bounds__(64) void topk_select2(const u32* __restrict__ keyA,
                                                   const u32* __restrict__ keyB,
                                                   int* __restrict__ nnA,
                                                   int* __restrict__ nnB) {
    const int side = blockIdx.x >> 12;
    const int q = blockIdx.x & 4095;
    const u32* krow = (side ? keyB : keyA) + (size_t)q * 4096;
    int* nn = (side ? nnB : nnA) + (size_t)q * KNBR;

    __shared__ u32 kbuf[64 * 65];
    const int lane = threadIdx.x;

#pragma unroll 8
    for (int t = 0; t < 64; ++t) kbuf[t * 65 + lane] = krow[t * 64 + lane];

    volatile u32* kq = (volatile u32*)kbuf;

    u32 l1;
    {
        const int base = lane * 65;
        u32 m0 = 0xFFFFFFFFu, m1 = 0xFFFFFFFFu, m2 = 0xFFFFFFFFu, m3 = 0xFFFFFFFFu;
#pragma unroll
        for (int t = 0; t < 64; t += 4) {
            u32 a = kq[base + t + 0];
            u32 b = kq[base + t + 1];
            u32 c = kq[base + t + 2];
            u32 d = kq[base + t + 3];
            m0 = a < m0 ? a : m0;
            m1 = b < m1 ? b : m1;
            m2 = c < m2 ? c : m2;
            m3 = d < m3 ? d : m3;
        }
        m0 = m1 < m0 ? m1 : m0;
        m2 = m3 < m2 ? m3 : m2;
        l1 = m2 < m0 ? m2 : m0;
    }

    int myj = 0;
    for (int r = 0; r < KNBR; ++r) {
        u32 m = wave_min_u32_bcast(l1);
        u64 gmask = __ballot(l1 == m);
        int g = __builtin_ctzll(gmask);
        u32 v = kq[g * 65 + lane];
        u64 wmask = __ballot(v == m);
        int jl = __builtin_ctzll(wmask);
        if (lane == jl) kq[g * 65 + jl] = 0xFFFFFFFFu;
        u32 v2 = (lane == jl) ? 0xFFFFFFFFu : v;
        u32 nm = wave_min_u32_bcast(v2);
        if (lane == g) l1 = nm;
        if (lane == r) myj = (g << 6) | jl;
    }
    if (lane < KNBR) nn[lane] = myj;
}

// Fallback (round-6) fused topk for the non-MFMA path.
__global__ __launch_bounds__(128) void topk_all_kernel(const float* __restrict__ embA,
                                                       const float* __restrict__ sqA,
                                                       const float* __restrict__ embB,
                                                       const float* __restrict__ sqB,
                                                       int* __restrict__ nnA,
                                                       int* __restrict__ nnB) {
    const int side = blockIdx.x >> 11;
    const int q0 = (blockIdx.x & 2047) * 2;
    const float* embQ = side ? embB : embA;
    const float* embC = side ? embA : embB;
    const float* sqCc = side ? sqA : sqB;
    int* nnOut = side ? nnB : nnA;

    __shared__ u32 keys[2][64 * 65];

    const int tid = threadIdx.x;
    const int lane = tid & 63, w = tid >> 6;

    float4 q0v[8], q1v[8];
    {
        const float4* e0 = (const float4*)(embQ + (size_t)q0 * 32);
        const float4* e1 = (const float4*)(embQ + (size_t)(q0 + 1) * 32);
#pragma unroll
        for (int c = 0; c < 8; ++c) { q0v[c] = e0[c]; q1v[c] = e1[c]; }
    }

    for (int i = 0; i < 32; ++i) {
        int j = (i << 7) + tid;
        const float4* ec = (const float4*)(embC + (size_t)j * 32);
        float d0 = 0.f, d1 = 0.f;
#pragma unroll
        for (int c = 0; c < 8; ++c) {
            float4 cv = ec[c];
            d0 += q0v[c].x * cv.x + q0v[c].y * cv.y + q0v[c].z * cv.z + q0v[c].w * cv.w;
            d1 += q1v[c].x * cv.x + q1v[c].y * cv.y + q1v[c].z * cv.z + q1v[c].w * cv.w;
        }
        float sc = sqCc[j];
        int off = (j >> 6) * 65 + (j & 63);
        keys[0][off] = fkey(sc - 2.f * d0);
        keys[1][off] = fkey(sc - 2.f * d1);
    }
    __syncthreads();

    volatile u32* kq = (volatile u32*)&keys[w][0];

    u32 l1;
    {
        const int base = lane * 65;
        u32 m0 = 0xFFFFFFFFu, m1 = 0xFFFFFFFFu, m2 = 0xFFFFFFFFu, m3 = 0xFFFFFFFFu;
#pragma unroll
        for (int t = 0; t < 64; t += 4) {
            u32 a = kq[base + t + 0];
            u32 b = kq[base + t + 1];
            u32 c = kq[base + t + 2];
            u32 d = kq[base + t + 3];
            m0 = a < m0 ? a : m0;
            m1 = b < m1 ? b : m1;
            m2 = c < m2 ? c : m2;
            m3 = d < m3 ? d : m3;
        }
        m0 = m1 < m0 ? m1 : m0;
        m2 = m3 < m2 ? m3 : m2;
        l1 = m2 < m0 ? m2 : m0;
    }

    int myj = 0;
    for (int r = 0; r < KNBR; ++r) {
        u32 m = wave_min_u32_bcast(l1);
        u64 gmask = __ballot(l1 == m);
        int g = __builtin_ctzll(gmask);
        u32 v = kq[g * 65 + lane];
        u64 wmask = __ballot(v == m);
        int jl = __builtin_ctzll(wmask);
        if (lane == jl) kq[g * 65 + jl] = 0xFFFFFFFFu;
        u32 v2 = (lane == jl) ? 0xFFFFFFFFu : v;
        u32 nm = wave_min_u32_bcast(v2);
        if (lane == g) l1 = nm;
        if (lane == r) myj = (g << 6) | jl;
    }
    if (lane < KNBR) nnOut[(size_t)(q0 + w) * KNBR + lane] = myj;
}

// ---------------------------------------------------------------------------
// Fused gather-mean + MSE partials, bf16 ximp, both sides in one launch.
__global__ __launch_bounds__(256) void predloss_bf16_kernel(const int* __restrict__ nnA,
                                                            const int* __restrict__ nnB,
                                                            const u16* __restrict__ ximpBbf,
                                                            const u16* __restrict__ ximpAbf,
                                                            const float* __restrict__ xA,
                                                            const float* __restrict__ xB,
                                                            float* __restrict__ partA,
                                                            float* __restrict__ partB) {
    const int side = blockIdx.x >> 12;
    const int q = blockIdx.x & 4095;
    const int* nn = (side ? nnB : nnA) + (size_t)q * KNBR;
    const u16* ximp = side ? ximpAbf : ximpBbf;
    const float* xtrue = (side ? xB : xA) + (size_t)q * 3000;
    float* partial = side ? partB : partA;

    __shared__ int nns[KNBR];
    __shared__ float red[256];
    if (threadIdx.x < KNBR) nns[threadIdx.x] = nn[threadIdx.x];
    __syncthreads();

    int nr[KNBR];
#pragma unroll
    for (int t = 0; t < KNBR; ++t) nr[t] = nns[t];

    const float inv = 1.0f / KNBR;
    float sse = 0.f;
    for (int v = threadIdx.x; v < 375; v += 256) {
        float acc[8] = {};
#pragma unroll
        for (int t = 0; t < KNBR; ++t) {
            uint4 pk = *(const uint4*)(ximp + (size_t)nr[t] * KPAD + v * 8);
            acc[0] += bf2f((u16)(pk.x & 0xFFFF));
            acc[1] += bf2f((u16)(pk.x >> 16));
            acc[2] += bf2f((u16)(pk.y & 0xFFFF));
            acc[3] += bf2f((u16)(pk.y >> 16));
            acc[4] += bf2f((u16)(pk.z & 0xFFFF));
            acc[5] += bf2f((u16)(pk.z >> 16));
            acc[6] += bf2f((u16)(pk.w & 0xFFFF));
            acc[7] += bf2f((u16)(pk.w >> 16));
        }
        const float4 x0 = *(const float4*)(xtrue + v * 8);
        const float4 x1 = *(const float4*)(xtrue + v * 8 + 4);
        float d0 = acc[0] * inv - x0.x;
        float d1 = acc[1] * inv - x0.y;
        float d2 = acc[2] * inv - x0.z;
        float d3 = acc[3] * inv - x0.w;
        float d4 = acc[4] * inv - x1.x;
        float d5 = acc[5] * inv - x1.y;
        float d6 = acc[6] * inv - x1.z;
        float d7 = acc[7] * inv - x1.w;
        sse += d0 * d0 + d1 * d1 + d2 * d2 + d3 * d3
             + d4 * d4 + d5 * d5 + d6 * d6 + d7 * d7;
    }
    red[threadIdx.x] = sse;
    __syncthreads();
    for (int off = 128; off > 0; off >>= 1) {
        if (threadIdx.x < off) red[threadIdx.x] += red[threadIdx.x + off];
        __syncthreads();
    }
    if (threadIdx.x == 0) partial[q] = red[0];
}

// Fallback f32 predloss
__global__ __launch_bounds__(256) void predloss_kernel(const int* __restrict__ nn,
                                                       const float* __restrict__ ximp,
                                                       const float* __restrict__ xtrue,
                                                       float* __restrict__ partial) {
    int q = blockIdx.x;
    __shared__ int nns[KNBR];
    __shared__ float red[256];
    if (threadIdx.x < KNBR) nns[threadIdx.x] = nn[(size_t)q * KNBR + threadIdx.x];
    __syncthreads();

    int nr[KNBR];
#pragma unroll
    for (int t = 0; t < KNBR; ++t) nr[t] = nns[t];

    const float inv = 1.0f / KNBR;
    float sse = 0.f;
    for (int v = threadIdx.x; v < 750; v += 256) {
        float4 acc = {0.f, 0.f, 0.f, 0.f};
#pragma unroll
        for (int t = 0; t < KNBR; ++t) {
            const float4 w = *(const float4*)(ximp + (size_t)nr[t] * 3000 + v * 4);
            acc.x += w.x; acc.y += w.y; acc.z += w.z; acc.w += w.w;
        }
        const float4 xt = *(const float4*)(xtrue + (size_t)q * 3000 + v * 4);
        float dx = acc.x * inv - xt.x;
        float dy = acc.y * inv - xt.y;
        float dz = acc.z * inv - xt.z;
        float dw = acc.w * inv - xt.w;
        sse += dx * dx + dy * dy + dz * dz + dw * dw;
    }
    red[threadIdx.x] = sse;
    __syncthreads();
    for (int off = 128; off > 0; off >>= 1) {
        if (threadIdx.x < off) red[threadIdx.x] += red[threadIdx.x + off];
        __syncthreads();
    }
    if (threadIdx.x == 0) partial[q] = red[0];
}

__global__ __launch_bounds__(256) void loss_final_kernel(const float* __restrict__ pA,
                                                         const float* __restrict__ pB,
                                                         float* __restrict__ out) {
    __shared__ double red[256];
    double sa = 0.0, sb = 0.0;
    for (int i = threadIdx.x; i < 4096; i += 256) {
        sa += (double)pA[i];
        sb += (double)pB[i];
    }
    red[threadIdx.x] = sa;
    __syncthreads();
    for (int off = 128; off > 0; off >>= 1) {
        if (threadIdx.x < off) red[threadIdx.x] += red[threadIdx.x + off];
        __syncthreads();
    }
    double totA = red[0];
    __syncthreads();
    red[threadIdx.x] = sb;
    __syncthreads();
    for (int off = 128; off > 0; off >>= 1) {
        if (threadIdx.x < off) red[threadIdx.x] += red[threadIdx.x + off];
        __syncthreads();
    }
    if (threadIdx.x == 0) {
        double denom = 4096.0 * 3000.0;
        out[0] = (float)(totA / denom + red[0] / denom);
    }
}

// ---------------------------------------------------------------------------
extern "C" void kernel_launch(void* const* d_in, const int* in_sizes, int n_in,
                              void* d_out, int out_size, void* d_ws, size_t ws_size,
                              hipStream_t stream) {
    const float* x_A = (const float*)d_in[0];
    const float* x_B = (const float*)d_in[1];
    const float* G   = (const float*)d_in[2];
    const float* W1  = (const float*)d_in[3];
    const float* b1  = (const float*)d_in[4];
    const float* W2  = (const float*)d_in[5];
    const float* b2  = (const float*)d_in[6];
    const float* WcA = (const float*)d_in[7];
    const float* bcA = (const float*)d_in[8];
    const float* WcB = (const float*)d_in[9];
    const float* bcB = (const float*)d_in[10];

    float* outp = (float*)d_out;

    size_t off = 0;
    char* base = (char*)d_ws;
    auto carve = [&](size_t bytes) -> void* {
        void* p = base + off;
        off = (off + bytes + 255) & ~(size_t)255;
        return p;
    };
    // f32 ximp: FALLBACK path only; on bf16 path this 98.4 MB region hosts keyA.
    float* ximpA = (float*)carve((size_t)N_A * G_B * 4);
    float* ximpB = (float*)carve((size_t)N_B * G_A * 4);
    float* normA = (float*)carve(G_A * 4);
    float* normB = (float*)carve(G_B * 4);
    float* colpart = (float*)carve(25 * G_B * 4);
    float* embA = (float*)carve((size_t)N_A * 32 * 4);
    float* embB = (float*)carve((size_t)N_B * 32 * 4);
    float* sqA = (float*)carve(N_A * 4);
    float* sqB = (float*)carve(N_B * 4);
    float* partA = (float*)carve(N_A * 4);
    float* partB = (float*)carve(N_B * 4);
    int* nnA = (int*)carve((size_t)N_A * KNBR * 4);
    int* nnB = (int*)carve((size_t)N_B * KNBR * 4);
    u16* xAbf = (u16*)carve((size_t)N_A * KPAD * 2);   // region start for keyB alias
    u16* xBbf = (u16*)carve((size_t)N_B * KPAD * 2);
    u16* Gbf  = (u16*)carve((size_t)KPAD * KPAD * 2);
    u16* Gtbf = (u16*)carve((size_t)KPAD * KPAD * 2);
    u16* ximpAbf = (u16*)carve((size_t)N_A * KPAD * 2);   // live until predloss
    u16* ximpBbf = (u16*)carve((size_t)N_B * KPAD * 2);   // live until predloss
    u16* W1tbf   = (u16*)carve((size_t)64 * KMLP * 2);
    float* mlppart = (float*)carve((size_t)4 * 8192 * 64 * 4);
    size_t full_needed = off;

    // Aliases (bf16 path only):
    // keyA (67 MB) over dead f32 ximpA/ximpB (98.4 MB contiguous).
    // keyB (67 MB) over dead xAbf..Gtbf (88.1 MB contiguous, dead after mlp1).
    // norm partials (2 x 1.2 MB) over mlppart (written only later by mlp1).
    u32* keyA = (u32*)ximpA;
    u32* keyB = (u32*)xAbf;
    float* rowpart  = mlppart;                    // [96][KPAD]
    float* colpart2 = mlppart + 96 * KPAD;        // [96][KPAD]

    const bool use_mfma = (ws_size >= full_needed);

    if (use_mfma) {
        // 1) bf16 conversions; G read ONCE (dual layout + fused norm partials)
        convert_pad2_kernel<<<2 * (N_A * (KPAD / 8)) / 256, 256, 0, stream>>>(x_A, x_B, xAbf, xBbf);
        g_convert_dual_norm_kernel<<<dim3(96, 96), 256, 0, stream>>>(G, Gbf, Gtbf, rowpart, colpart2);
        normA_final_kernel<<<12, 256, 0, stream>>>(rowpart, normA);
        normB_final_kernel<<<12, 256, 0, stream>>>(colpart2, normB);
        w1t_kernel<<<(64 * KMLP) / 256, 256, 0, stream>>>(W1, W1tbf);

        // 2) both imputation GEMMs in ONE launch (bf16 out, XCD-swizzled)
        mfma_impute2_gemm<<<dim3(KPAD / 128, N_A / 128, 2), 256, 0, stream>>>(
            xAbf, xBbf, Gtbf, Gbf, normB, normA, ximpAbf, ximpBbf);

        // 3) MLP via MFMA + K-split (clobbers rowpart/colpart2 -> fine, consumed)
        mlp1_kernel<<<dim3(4, 128), 256, 0, stream>>>(xAbf, ximpAbf, ximpBbf, xBbf, W1tbf, mlppart);
        mlp2_kernel<<<128, 256, 0, stream>>>(mlppart, b1, W2, b2, embA, embB, sqA, sqB);

        // 4) class predictions -> d_out
        preds_kernel<<<(N_A * NCA) / 256, 256, 0, stream>>>(embA, WcA, bcA, outp, NCA);
        preds_kernel<<<(N_B * NCB) / 256, 256, 0, stream>>>(embB, WcB, bcB, outp + (size_t)N_A * NCA, NCB);

        // 5) top-20: both key GEMMs in one launch, both selects in one launch
        distkey2_gemm<<<dim3(32, 32, 2), 256, 0, stream>>>(embA, embB, sqA, sqB, keyA, keyB);
        topk_select2<<<8192, 64, 0, stream>>>(keyA, keyB, nnA, nnB);

        // 6) fused gather-mean + MSE partials (bf16 ximp, both sides)
        predloss_bf16_kernel<<<8192, 256, 0, stream>>>(nnA, nnB, ximpBbf, ximpAbf,
                                                       x_A, x_B, partA, partB);
    } else {
        row_sum_kernel<<<G_A, 256, 0, stream>>>(G, normA);
        col_partial_kernel<<<dim3(12, 25), 256, 0, stream>>>(G, colpart);
        col_final_kernel<<<12, 256, 0, stream>>>(colpart, normB);
        dim3 ggrid(24, 32);
        impute_gemm<false><<<ggrid, 256, 0, stream>>>(x_A, G, normB, ximpA);
        impute_gemm<true><<<ggrid, 256, 0, stream>>>(x_B, G, normA, ximpB);
        mlp_kernel<<<128, 256, 0, stream>>>(x_A, ximpA, ximpB, x_B, W1, b1, W2, b2, embA, embB);
        sqnorm_kernel<<<16, 256, 0, stream>>>(embA, sqA);
        sqnorm_kernel<<<16, 256, 0, stream>>>(embB, sqB);
        preds_kernel<<<(N_A * NCA) / 256, 256, 0, stream>>>(embA, WcA, bcA, outp, NCA);
        preds_kernel<<<(N_B * NCB) / 256, 256, 0, stream>>>(embB, WcB, bcB, outp + (size_t)N_A * NCA, NCB);
        topk_all_kernel<<<4096, 128, 0, stream>>>(embA, sqA, embB, sqB, nnA, nnB);
        predloss_kernel<<<N_A, 256, 0, stream>>>(nnA, ximpB, x_A, partA);
        predloss_kernel<<<N_B, 256, 0, stream>>>(nnB, ximpA, x_B, partB);
    }

    // 7) final loss
    loss_final_kernel<<<1, 256, 0, stream>>>(partA, partB, outp + (size_t)N_A * NCA + (size_t)N_B * NCB);

    (void)in_sizes; (void)n_in; (void)out_size;
}

// Round 10
// 470.848 us; speedup vs baseline: 3.3713x; 1.0402x over previous
//
#include <hip/hip_runtime.h>
#include <cfloat>
#include <cstddef>
#include <climits>

// Problem constants
#define N_A   4096
#define N_B   4096
#define G_A   3000
#define G_B   3000
#define NCA   30
#define NCB   25
#define KNBR  20
#define KPAD  3072   // K/N padding for MFMA tiles (multiple of 128)
#define KMLP  6144   // padded MLP K ( = 2*KPAD )

typedef unsigned short u16;
typedef unsigned int u32;
typedef unsigned long long u64;
typedef __bf16 bf16x8 __attribute__((ext_vector_type(8)));
typedef float f32x4 __attribute__((ext_vector_type(4)));
typedef __attribute__((address_space(1))) const void* as1_cvp;
typedef __attribute__((address_space(3))) void* as3_vp;

static __device__ __forceinline__ u16 f2bf(float f) {
    union { float f; unsigned u; } v; v.f = f;
    unsigned r = v.u + 0x7fffu + ((v.u >> 16) & 1u);   // RTNE
    return (u16)(r >> 16);
}

static __device__ __forceinline__ float bf2f(u16 h) {
    union { unsigned u; float f; } v; v.u = ((unsigned)h) << 16;
    return v.f;
}

// monotonic float -> u32 key (ascending float == ascending unsigned)
static __device__ __forceinline__ u32 fkey(float f) {
    union { float f; u32 u; } v; v.f = f;
    return (v.u & 0x80000000u) ? ~v.u : (v.u | 0x80000000u);
}

// 64-lane min-reduce via DPP + broadcast (lane 63 holds global min).
static __device__ __forceinline__ u32 wave_min_u32_bcast(u32 v) {
    u32 t;
    t = (u32)__builtin_amdgcn_update_dpp((int)v, (int)v, 0x111, 0xf, 0xf, false); v = t < v ? t : v;
    t = (u32)__builtin_amdgcn_update_dpp((int)v, (int)v, 0x112, 0xf, 0xf, false); v = t < v ? t : v;
    t = (u32)__builtin_amdgcn_update_dpp((int)v, (int)v, 0x114, 0xf, 0xf, false); v = t < v ? t : v;
    t = (u32)__builtin_amdgcn_update_dpp((int)v, (int)v, 0x118, 0xf, 0xf, false); v = t < v ? t : v;
    t = (u32)__builtin_amdgcn_update_dpp((int)v, (int)v, 0x142, 0xf, 0xf, false); v = t < v ? t : v;
    t = (u32)__builtin_amdgcn_update_dpp((int)v, (int)v, 0x143, 0xf, 0xf, false); v = t < v ? t : v;
    return (u32)__builtin_amdgcn_readlane((int)v, 63);
}

// ---------------------------------------------------------------------------
// normalizers (FALLBACK path only)
__global__ __launch_bounds__(256) void row_sum_kernel(const float* __restrict__ G,
                                                      float* __restrict__ normA) {
    int row = blockIdx.x;
    __shared__ float red[256];
    float s = 0.f;
    for (int j = threadIdx.x; j < G_B; j += 256) s += G[(size_t)row * G_B + j];
    red[threadIdx.x] = s;
    __syncthreads();
    for (int off = 128; off > 0; off >>= 1) {
        if (threadIdx.x < off) red[threadIdx.x] += red[threadIdx.x + off];
        __syncthreads();
    }
    if (threadIdx.x == 0) {
        float v = red[0];
        normA[row] = (v == 0.f) ? 1.f : v;
    }
}

__global__ __launch_bounds__(256) void col_partial_kernel(const float* __restrict__ G,
                                                          float* __restrict__ part) {
    int j = blockIdx.x * 256 + threadIdx.x;
    if (j >= G_B) return;
    int r0 = blockIdx.y * 120;
    float s = 0.f;
    for (int i = r0; i < r0 + 120; ++i) s += G[(size_t)i * G_B + j];
    part[(size_t)blockIdx.y * G_B + j] = s;
}

__global__ __launch_bounds__(256) void col_final_kernel(const float* __restrict__ part,
                                                        float* __restrict__ normB) {
    int j = blockIdx.x * 256 + threadIdx.x;
    if (j >= G_B) return;
    float s = 0.f;
    for (int c = 0; c < 25; ++c) s += part[(size_t)c * G_B + j];
    normB[j] = (s == 0.f) ? 1.f : s;
}

// ---------------------------------------------------------------------------
// Merged x_A + x_B f32 -> bf16 convert with zero padding. grid 12288.
__global__ __launch_bounds__(256) void convert_pad2_kernel(const float* __restrict__ xA,
                                                           const float* __restrict__ xB,
                                                           u16* __restrict__ xAbf,
                                                           u16* __restrict__ xBbf) {
    const int half = (N_A * (KPAD / 8)) / 256;   // 6144 blocks per side
    const int side = blockIdx.x >= half;
    const float* in = side ? xB : xA;
    u16* out = side ? xBbf : xAbf;
    int idx = (blockIdx.x - (side ? half : 0)) * 256 + threadIdx.x;
    int cpr = KPAD >> 3;
    int r = idx / cpr, c0 = (idx % cpr) << 3;
    u16 res[8] = {0, 0, 0, 0, 0, 0, 0, 0};
    if (c0 + 8 <= G_A) {
        float4 v0 = *(const float4*)(in + (size_t)r * G_A + c0);
        float4 v1 = *(const float4*)(in + (size_t)r * G_A + c0 + 4);
        res[0] = f2bf(v0.x); res[1] = f2bf(v0.y); res[2] = f2bf(v0.z); res[3] = f2bf(v0.w);
        res[4] = f2bf(v1.x); res[5] = f2bf(v1.y); res[6] = f2bf(v1.z); res[7] = f2bf(v1.w);
    }
    uint4 pack;
    pack.x = (unsigned)res[0] | ((unsigned)res[1] << 16);
    pack.y = (unsigned)res[2] | ((unsigned)res[3] << 16);
    pack.z = (unsigned)res[4] | ((unsigned)res[5] << 16);
    pack.w = (unsigned)res[6] | ((unsigned)res[7] << 16);
    *(uint4*)(out + (size_t)r * KPAD + c0) = pack;
}

// G -> Gbf + Gt bf16 padded; ALSO per-tile partial row/col sums. G read once.
__global__ __launch_bounds__(256) void g_convert_dual_norm_kernel(const float* __restrict__ G,
                                                                  u16* __restrict__ Gbf,
                                                                  u16* __restrict__ Gt,
                                                                  float* __restrict__ rowpart,
                                                                  float* __restrict__ colpart2) {
    __shared__ float t[32][33];
    int j0 = blockIdx.x * 32, k0 = blockIdx.y * 32;
    int lx = threadIdx.x & 31, ly = threadIdx.x >> 5;
#pragma unroll
    for (int i = 0; i < 4; ++i) {
        int k = k0 + ly + i * 8, j = j0 + lx;
        float v = (k < G_A && j < G_B) ? G[(size_t)k * G_B + j] : 0.f;
        t[ly + i * 8][lx] = v;
        Gbf[(size_t)k * KPAD + j] = f2bf(v);
    }
    __syncthreads();
#pragma unroll
    for (int i = 0; i < 4; ++i) {
        int j = j0 + ly + i * 8, k = k0 + lx;
        Gt[(size_t)j * KPAD + k] = f2bf(t[lx][ly + i * 8]);
    }
    if (threadIdx.x < 32) {
        int kl = threadIdx.x;
        float s = 0.f;
#pragma unroll
        for (int j2 = 0; j2 < 32; ++j2) s += t[kl][j2];
        rowpart[(size_t)blockIdx.x * KPAD + k0 + kl] = s;
    } else if (threadIdx.x < 64) {
        int jl = threadIdx.x - 32;
        float s = 0.f;
#pragma unroll
        for (int k2 = 0; k2 < 32; ++k2) s += t[k2][jl];
        colpart2[(size_t)blockIdx.y * KPAD + j0 + jl] = s;
    }
}

// Merged normA + normB finalize. grid 24: blocks 0..11 -> A, 12..23 -> B.
__global__ __launch_bounds__(256) void norm_final_kernel(const float* __restrict__ rowpart,
                                                         const float* __restrict__ colpart2,
                                                         float* __restrict__ normA,
                                                         float* __restrict__ normB) {
    if (blockIdx.x < 12) {
        int k = blockIdx.x * 256 + threadIdx.x;
        if (k >= G_A) return;
        float s = 0.f;
        for (int jt = 0; jt < 96; ++jt) s += rowpart[(size_t)jt * KPAD + k];
        normA[k] = (s == 0.f) ? 1.f : s;
    } else {
        int j = (blockIdx.x - 12) * 256 + threadIdx.x;
        if (j >= G_B) return;
        float s = 0.f;
        for (int kt = 0; kt < 96; ++kt) s += colpart2[(size_t)kt * KPAD + j];
        normB[j] = (s == 0.f) ? 1.f : s;
    }
}

// W1 [6000][64] f32 -> W1t [64][KMLP] bf16
__global__ __launch_bounds__(256) void w1t_kernel(const float* __restrict__ W1,
                                                  u16* __restrict__ W1t) {
    int idx = blockIdx.x * 256 + threadIdx.x;
    int n = idx / KMLP, kp = idx % KMLP;
    int seg = kp >= KPAD;
    int k = kp - (seg ? KPAD : 0);
    float v = (k < 3000) ? W1[(size_t)(seg * 3000 + k) * 64 + n] : 0.f;
    W1t[(size_t)n * KMLP + kp] = f2bf(v);
}

// ---------------------------------------------------------------------------
// Merged bf16 MFMA imputation GEMM, both directions (linear tile mapping).
__global__ __launch_bounds__(256) void mfma_impute2_gemm(const u16* __restrict__ xAbf,
                                                         const u16* __restrict__ xBbf,
                                                         const u16* __restrict__ Gtbf,
                                                         const u16* __restrict__ Gbf,
                                                         const float* __restrict__ normB,
                                                         const float* __restrict__ normA,
                                                         u16* __restrict__ ximpAbf,
                                                         u16* __restrict__ ximpBbf) {
    const int side = blockIdx.z;
    const u16* A  = side ? xBbf : xAbf;
    const u16* Bt = side ? Gbf : Gtbf;
    const float* norm = side ? normA : normB;
    u16* outbf = side ? ximpBbf : ximpAbf;

    const int col_base = blockIdx.x * 128;
    const int row_base = blockIdx.y * 128;

    __shared__ __align__(16) u16 lAs[128 * 64];
    __shared__ __align__(16) u16 lBs[128 * 64];

    const int tid = threadIdx.x;
    const int w = tid >> 6, lane = tid & 63;
    const int wr = (w >> 1) * 64, wc = (w & 1) * 64;

    f32x4 acc[4][4] = {};

    int s_r[4], s_off[4];
#pragma unroll
    for (int i = 0; i < 4; ++i) {
        int slin = (w * 4 + i) * 64 + lane;
        int r = slin >> 3, s = slin & 7;
        s_r[i] = r;
        s_off[i] = (s ^ (r & 7)) * 8;
    }

    for (int k0 = 0; k0 < KPAD; k0 += 64) {
#pragma unroll
        for (int i = 0; i < 4; ++i) {
            const u16* ga = A + (size_t)(row_base + s_r[i]) * KPAD + k0 + s_off[i];
            __builtin_amdgcn_global_load_lds((as1_cvp)ga,
                (as3_vp)(lAs + (size_t)(w * 4 + i) * 512), 16, 0, 0);
        }
#pragma unroll
        for (int i = 0; i < 4; ++i) {
            const u16* gb = Bt + (size_t)(col_base + s_r[i]) * KPAD + k0 + s_off[i];
            __builtin_amdgcn_global_load_lds((as1_cvp)gb,
                (as3_vp)(lBs + (size_t)(w * 4 + i) * 512), 16, 0, 0);
        }
        __syncthreads();

#pragma unroll
        for (int kk = 0; kk < 2; ++kk) {
            bf16x8 a[4], b[4];
#pragma unroll
            for (int m = 0; m < 4; ++m) {
                int row = wr + m * 16 + (lane & 15);
                int slot = (kk * 4 + (lane >> 4)) ^ (row & 7);
                a[m] = *(const bf16x8*)(lAs + row * 64 + slot * 8);
            }
#pragma unroll
            for (int n = 0; n < 4; ++n) {
                int row = wc + n * 16 + (lane & 15);
                int slot = (kk * 4 + (lane >> 4)) ^ (row & 7);
                b[n] = *(const bf16x8*)(lBs + row * 64 + slot * 8);
            }
#pragma unroll
            for (int m = 0; m < 4; ++m)
#pragma unroll
                for (int n = 0; n < 4; ++n)
                    acc[m][n] = __builtin_amdgcn_mfma_f32_16x16x32_bf16(a[m], b[n], acc[m][n], 0, 0, 0);
        }
        __syncthreads();
    }

#pragma unroll
    for (int n = 0; n < 4; ++n) {
        int col = col_base + wc + n * 16 + (lane & 15);
        bool valid = col < G_B;
        float rn = valid ? 1.0f / norm[col] : 0.f;
#pragma unroll
        for (int m = 0; m < 4; ++m) {
            int row = row_base + wr + m * 16 + (lane >> 4) * 4;
#pragma unroll
            for (int r = 0; r < 4; ++r)
                outbf[(size_t)(row + r) * KPAD + col] = f2bf(acc[m][n][r] * rn);
        }
    }
}

// ---------------------------------------------------------------------------
// MLP layer 1 (bf16 MFMA, K-split)
__global__ __launch_bounds__(256) void mlp1_kernel(const u16* __restrict__ xAbf,
                                                   const u16* __restrict__ ximpAbf,
                                                   const u16* __restrict__ ximpBbf,
                                                   const u16* __restrict__ xBbf,
                                                   const u16* __restrict__ W1t,
                                                   float* __restrict__ partial) {
    const int chunk = blockIdx.x;
    const int rb = blockIdx.y;
    const int side = rb >> 6;
    const int r0 = (rb & 63) * 64;
    const int seg = chunk >> 1;
    const u16* src = side ? (seg ? xBbf : ximpBbf) : (seg ? ximpAbf : xAbf);
    const int k0base = (chunk & 1) * 1536;

    __shared__ __align__(16) u16 lAs[64 * 64];
    __shared__ __align__(16) u16 lBs[64 * 64];

    const int tid = threadIdx.x;
    const int w = tid >> 6, lane = tid & 63;

    int s_r[2], s_off[2];
#pragma unroll
    for (int i = 0; i < 2; ++i) {
        int slin = (w * 2 + i) * 64 + lane;
        int r = slin >> 3, s = slin & 7;
        s_r[i] = r;
        s_off[i] = (s ^ (r & 7)) * 8;
    }

    f32x4 acc[4] = {};

    for (int k0 = 0; k0 < 1536; k0 += 64) {
#pragma unroll
        for (int i = 0; i < 2; ++i) {
            const u16* ga = src + (size_t)(r0 + s_r[i]) * KPAD + k0base + k0 + s_off[i];
            __builtin_amdgcn_global_load_lds((as1_cvp)ga,
                (as3_vp)(lAs + (size_t)(w * 2 + i) * 512), 16, 0, 0);
        }
#pragma unroll
        for (int i = 0; i < 2; ++i) {
            const u16* gb = W1t + (size_t)s_r[i] * KMLP + chunk * 1536 + k0 + s_off[i];
            __builtin_amdgcn_global_load_lds((as1_cvp)gb,
                (as3_vp)(lBs + (size_t)(w * 2 + i) * 512), 16, 0, 0);
        }
        __syncthreads();

#pragma unroll
        for (int kk = 0; kk < 2; ++kk) {
            int arow = w * 16 + (lane & 15);
            int aslot = (kk * 4 + (lane >> 4)) ^ (arow & 7);
            bf16x8 a = *(const bf16x8*)(lAs + arow * 64 + aslot * 8);
#pragma unroll
            for (int n = 0; n < 4; ++n) {
                int brow = n * 16 + (lane & 15);
                int bslot = (kk * 4 + (lane >> 4)) ^ (brow & 7);
                bf16x8 b = *(const bf16x8*)(lBs + brow * 64 + bslot * 8);
                acc[n] = __builtin_amdgcn_mfma_f32_16x16x32_bf16(a, b, acc[n], 0, 0, 0);
            }
        }
        __syncthreads();
    }

    const size_t grow0 = (size_t)rb * 64;
#pragma unroll
    for (int n = 0; n < 4; ++n) {
        int col = n * 16 + (lane & 15);
        int rowl = w * 16 + (lane >> 4) * 4;
#pragma unroll
        for (int r = 0; r < 4; ++r)
            partial[((size_t)chunk * 8192 + grow0 + rowl + r) * 64 + col] = acc[n][r];
    }
}

// MLP reduce + layer 2 + fused sqnorm
__global__ __launch_bounds__(256) void mlp2_kernel(const float* __restrict__ partial,
                                                   const float* __restrict__ b1,
                                                   const float* __restrict__ W2,
                                                   const float* __restrict__ b2,
                                                   float* __restrict__ embA,
                                                   float* __restrict__ embB,
                                                   float* __restrict__ sqA,
                                                   float* __restrict__ sqB) {
    const int rb = blockIdx.x;
    const int side = rb >> 6;
    const size_t grow0 = (size_t)rb * 64;
    const int r0 = (rb & 63) * 64;
    float* emb = side ? embB : embA;
    float* sq = side ? sqB : sqA;

    __shared__ float Hs[64][65];
    __shared__ float W2s[64][32];
    const int tid = threadIdx.x;

    {
        const float4* srcw = (const float4*)W2;
        float4* dst = (float4*)&W2s[0][0];
        for (int i = tid; i < 512; i += 256) dst[i] = srcw[i];
    }

    for (int v = tid; v < 1024; v += 256) {
        int row = v >> 4, c4 = v & 15;
        float4 s = {0.f, 0.f, 0.f, 0.f};
#pragma unroll
        for (int c = 0; c < 4; ++c) {
            const float4 p = *(const float4*)(partial + ((size_t)c * 8192 + grow0 + row) * 64 + c4 * 4);
            s.x += p.x; s.y += p.y; s.z += p.z; s.w += p.w;
        }
        const float4 bb = *(const float4*)(b1 + c4 * 4);
        Hs[row][c4 * 4 + 0] = fmaxf(s.x + bb.x, 0.f);
        Hs[row][c4 * 4 + 1] = fmaxf(s.y + bb.y, 0.f);
        Hs[row][c4 * 4 + 2] = fmaxf(s.z + bb.z, 0.f);
        Hs[row][c4 * 4 + 3] = fmaxf(s.w + bb.w, 0.f);
    }
    __syncthreads();

    const int c2 = tid & 31, rg = tid >> 5;
    float acc2[8] = {};
    for (int k = 0; k < 64; ++k) {
        float wv = W2s[k][c2];
#pragma unroll
        for (int i = 0; i < 8; ++i) acc2[i] += Hs[rg * 8 + i][k] * wv;
    }
    float bb = b2[c2];
    float e[8];
#pragma unroll
    for (int i = 0; i < 8; ++i) {
        e[i] = fmaxf(acc2[i] + bb, 0.f);
        emb[(size_t)(r0 + rg * 8 + i) * 32 + c2] = e[i];
    }
#pragma unroll
    for (int i = 0; i < 8; ++i) {
        float v = e[i] * e[i];
#pragma unroll
        for (int off = 16; off > 0; off >>= 1) v += __shfl_xor(v, off, 32);
        if (c2 == 0) sq[r0 + rg * 8 + i] = v;
    }
}

// ---------------------------------------------------------------------------
// Fallback f32 GEMM
template <bool TRANSB>
__global__ __launch_bounds__(256) void impute_gemm(const float* __restrict__ X,
                                                   const float* __restrict__ G,
                                                   const float* __restrict__ norm,
                                                   float* __restrict__ out) {
    __shared__ float As[8][128];
    __shared__ float Bs[8][128];
    const int tid = threadIdx.x;
    const int col_base = blockIdx.x * 128;
    const int row_base = blockIdx.y * 128;
    const int tx = tid & 15;
    const int ty = tid >> 4;
    float acc[8][8] = {};
    const int a_row = tid >> 1;
    const int a_k   = (tid & 1) * 4;
    for (int k0 = 0; k0 < G_B; k0 += 8) {
        {
            float4 av = *(const float4*)(X + (size_t)(row_base + a_row) * G_B + k0 + a_k);
            As[a_k + 0][a_row] = av.x;
            As[a_k + 1][a_row] = av.y;
            As[a_k + 2][a_row] = av.z;
            As[a_k + 3][a_row] = av.w;
        }
        if (!TRANSB) {
            const int bk = tid >> 5;
            const int bc = (tid & 31) * 4;
            float4 bv = {0.f, 0.f, 0.f, 0.f};
            if (col_base + bc < G_B)
                bv = *(const float4*)(G + (size_t)(k0 + bk) * G_B + col_base + bc);
            *(float4*)&Bs[bk][bc] = bv;
        } else {
            const int bj = tid >> 1;
            const int bk = (tid & 1) * 4;
            float4 bv = {0.f, 0.f, 0.f, 0.f};
            if (col_base + bj < G_B)
                bv = *(const float4*)(G + (size_t)(col_base + bj) * G_B + k0 + bk);
            Bs[bk + 0][bj] = bv.x;
            Bs[bk + 1][bj] = bv.y;
            Bs[bk + 2][bj] = bv.z;
            Bs[bk + 3][bj] = bv.w;
        }
        __syncthreads();
#pragma unroll
        for (int kk = 0; kk < 8; ++kk) {
            float4 a0 = *(const float4*)&As[kk][ty * 8];
            float4 a1 = *(const float4*)&As[kk][ty * 8 + 4];
            float4 b0 = *(const float4*)&Bs[kk][tx * 8];
            float4 b1 = *(const float4*)&Bs[kk][tx * 8 + 4];
            float a_[8] = {a0.x, a0.y, a0.z, a0.w, a1.x, a1.y, a1.z, a1.w};
            float b_[8] = {b0.x, b0.y, b0.z, b0.w, b1.x, b1.y, b1.z, b1.w};
#pragma unroll
            for (int i = 0; i < 8; ++i)
#pragma unroll
                for (int j = 0; j < 8; ++j) acc[i][j] += a_[i] * b_[j];
        }
        __syncthreads();
    }
    const int cg = col_base + tx * 8;
    if (cg < G_B) {
        float rn[8];
#pragma unroll
        for (int j = 0; j < 8; ++j) rn[j] = 1.0f / norm[cg + j];
#pragma unroll
        for (int i = 0; i < 8; ++i) {
            float4 o0 = {acc[i][0] * rn[0], acc[i][1] * rn[1], acc[i][2] * rn[2], acc[i][3] * rn[3]};
            float4 o1 = {acc[i][4] * rn[4], acc[i][5] * rn[5], acc[i][6] * rn[6], acc[i][7] * rn[7]};
            size_t o = (size_t)(row_base + ty * 8 + i) * G_B + cg;
            *(float4*)(out + o) = o0;
            *(float4*)(out + o + 4) = o1;
        }
    }
}

// Fallback MLP (f32)
#define MLP_TK 24
__global__ __launch_bounds__(256) void mlp_kernel(const float* __restrict__ xA,
                                                  const float* __restrict__ ximpA,
                                                  const float* __restrict__ ximpB,
                                                  const float* __restrict__ xB,
                                                  const float* __restrict__ W1,
                                                  const float* __restrict__ b1,
                                                  const float* __restrict__ W2,
                                                  const float* __restrict__ b2,
                                                  float* __restrict__ embA,
                                                  float* __restrict__ embB) {
    __shared__ float Xs[MLP_TK][64];
    __shared__ float Ws[MLP_TK][64];
    __shared__ float Hs[64][65];
    __shared__ float W2s[64][32];

    const int side = blockIdx.x >> 6;
    const int row0 = (blockIdx.x & 63) * 64;
    const float* srcL = side ? ximpB : xA;
    const float* srcR = side ? xB : ximpA;
    float* emb = side ? embB : embA;

    const int tid = threadIdx.x;
    {
        const float4* src = (const float4*)W2;
        float4* dst = (float4*)&W2s[0][0];
        for (int i = tid; i < 512; i += 256) dst[i] = src[i];
    }

    const int tx = tid & 15;
    const int ty = tid >> 4;
    float acc[4][4] = {};
    const int lrow = tid >> 2;
    const int lk6  = (tid & 3) * 6;

    for (int k0 = 0; k0 < 6000; k0 += MLP_TK) {
        const float* src = (k0 < 3000) ? srcL : srcR;
        const int kbase = (k0 < 3000) ? k0 : (k0 - 3000);
        {
            const float* p = src + (size_t)(row0 + lrow) * 3000 + kbase + lk6;
#pragma unroll
            for (int e = 0; e < 6; ++e) Xs[lk6 + e][lrow] = p[e];
        }
        {
#pragma unroll
            for (int e = 0; e < 6; ++e) {
                int idx = tid * 6 + e;
                int kk = idx >> 6, cc = idx & 63;
                Ws[kk][cc] = W1[(size_t)(k0 + kk) * 64 + cc];
            }
        }
        __syncthreads();
#pragma unroll
        for (int kk = 0; kk < MLP_TK; ++kk) {
            float4 a = *(const float4*)&Xs[kk][ty * 4];
            float4 wv = *(const float4*)&Ws[kk][tx * 4];
            float a_[4] = {a.x, a.y, a.z, a.w};
            float w_[4] = {wv.x, wv.y, wv.z, wv.w};
#pragma unroll
            for (int i = 0; i < 4; ++i)
#pragma unroll
                for (int j = 0; j < 4; ++j) acc[i][j] += a_[i] * w_[j];
        }
        __syncthreads();
    }

#pragma unroll
    for (int j = 0; j < 4; ++j) {
        float bj = b1[tx * 4 + j];
#pragma unroll
        for (int i = 0; i < 4; ++i) {
            float h = acc[i][j] + bj;
            Hs[ty * 4 + i][tx * 4 + j] = h > 0.f ? h : 0.f;
        }
    }
    __syncthreads();

    const int c2 = tid & 31;
    const int rg = tid >> 5;
    float acc2[8] = {};
    for (int k = 0; k < 64; ++k) {
        float wv = W2s[k][c2];
#pragma unroll
        for (int i = 0; i < 8; ++i) acc2[i] += Hs[rg * 8 + i][k] * wv;
    }
    float bb = b2[c2];
#pragma unroll
    for (int i = 0; i < 8; ++i) {
        float h = acc2[i] + bb;
        emb[(size_t)(row0 + rg * 8 + i) * 32 + c2] = h > 0.f ? h : 0.f;
    }
}

__global__ __launch_bounds__(256) void sqnorm_kernel(const float* __restrict__ emb,
                                                     float* __restrict__ sq) {
    int i = blockIdx.x * 256 + threadIdx.x;
    if (i >= N_A) return;
    const float4* e = (const float4*)(emb + (size_t)i * 32);
    float s = 0.f;
#pragma unroll
    for (int q = 0; q < 8; ++q) {
        float4 v = e[q];
        s += v.x * v.x + v.y * v.y + v.z * v.z + v.w * v.w;
    }
    sq[i] = s;
}

// Merged class predictions (both sides) -> d_out. grid 880: 0..479 A, 480..879 B.
__global__ __launch_bounds__(256) void preds2_kernel(const float* __restrict__ embA,
                                                     const float* __restrict__ embB,
                                                     const float* __restrict__ WcA,
                                                     const float* __restrict__ bcA,
                                                     const float* __restrict__ WcB,
                                                     const float* __restrict__ bcB,
                                                     float* __restrict__ outp) {
    const int sideB = blockIdx.x >= 480;
    const float* emb = sideB ? embB : embA;
    const float* Wc = sideB ? WcB : WcA;
    const float* bc = sideB ? bcB : bcA;
    const int ncls = sideB ? NCB : NCA;
    float* out = outp + (sideB ? (size_t)N_A * NCA : 0);
    int idx = (blockIdx.x - (sideB ? 480 : 0)) * 256 + threadIdx.x;
    int row = idx / ncls, c = idx % ncls;
    const float* e = emb + (size_t)row * 32;
    float s = bc[c];
#pragma unroll
    for (int k = 0; k < 32; ++k) s += e[k] * Wc[k * ncls + c];
    out[idx] = s;
}

// fallback single-side preds
__global__ __launch_bounds__(256) void preds_kernel(const float* __restrict__ emb,
                                                    const float* __restrict__ Wc,
                                                    const float* __restrict__ bc,
                                                    float* __restrict__ out,
                                                    int ncls) {
    int idx = blockIdx.x * 256 + threadIdx.x;
    int row = idx / ncls, c = idx % ncls;
    const float* e = emb + (size_t)row * 32;
    float s = bc[c];
#pragma unroll
    for (int k = 0; k < 32; ++k) s += e[k] * Wc[k * ncls + c];
    out[idx] = s;
}

// ---------------------------------------------------------------------------
// Distance-key GEMM, both directions, u16 keys (top 16 bits of fkey).
// keys16[q][j] = fkey(sqC[j] - 2 * dot(embQ[q], embC[j])) >> 16
__global__ __launch_bounds__(256) void distkey2_gemm(const float* __restrict__ embA,
                                                     const float* __restrict__ embB,
                                                     const float* __restrict__ sqA,
                                                     const float* __restrict__ sqB,
                                                     u16* __restrict__ keyA,
                                                     u16* __restrict__ keyB) {
    const int side = blockIdx.z;
    const float* embQ = side ? embB : embA;
    const float* embC = side ? embA : embB;
    const float* sqC = side ? sqA : sqB;
    u16* keys = side ? keyB : keyA;

    __shared__ float As[32][132];
    __shared__ float Bs[32][132];

    const int tid = threadIdx.x;
    const int row_base = blockIdx.y * 128;
    const int col_base = blockIdx.x * 128;

#pragma unroll
    for (int i = 0; i < 4; ++i) {
        int idx = i * 256 + tid;
        int row = idx >> 3, k4 = (idx & 7) * 4;
        float4 a = *(const float4*)(embQ + (size_t)(row_base + row) * 32 + k4);
        As[k4 + 0][row] = a.x;
        As[k4 + 1][row] = a.y;
        As[k4 + 2][row] = a.z;
        As[k4 + 3][row] = a.w;
        float4 b = *(const float4*)(embC + (size_t)(col_base + row) * 32 + k4);
        Bs[k4 + 0][row] = b.x;
        Bs[k4 + 1][row] = b.y;
        Bs[k4 + 2][row] = b.z;
        Bs[k4 + 3][row] = b.w;
    }
    __syncthreads();

    const int tx = tid & 15, ty = tid >> 4;
    float acc[8][8] = {};
#pragma unroll
    for (int k = 0; k < 32; ++k) {
        float4 a0 = *(const float4*)&As[k][ty * 8];
        float4 a1 = *(const float4*)&As[k][ty * 8 + 4];
        float4 b0 = *(const float4*)&Bs[k][tx * 8];
        float4 b1 = *(const float4*)&Bs[k][tx * 8 + 4];
        float a_[8] = {a0.x, a0.y, a0.z, a0.w, a1.x, a1.y, a1.z, a1.w};
        float b_[8] = {b0.x, b0.y, b0.z, b0.w, b1.x, b1.y, b1.z, b1.w};
#pragma unroll
        for (int i = 0; i < 8; ++i)
#pragma unroll
            for (int j = 0; j < 8; ++j) acc[i][j] += a_[i] * b_[j];
    }

    const int cg = col_base + tx * 8;
    float sc[8];
#pragma unroll
    for (int j = 0; j < 8; ++j) sc[j] = sqC[cg + j];
#pragma unroll
    for (int i = 0; i < 8; ++i) {
        u32 k16[8];
#pragma unroll
        for (int j = 0; j < 8; ++j) k16[j] = fkey(sc[j] - 2.f * acc[i][j]) >> 16;
        uint4 o;
        o.x = k16[0] | (k16[1] << 16);
        o.y = k16[2] | (k16[3] << 16);
        o.z = k16[4] | (k16[5] << 16);
        o.w = k16[6] | (k16[7] << 16);
        *(uint4*)(keys + (size_t)(row_base + ty * 8 + i) * 4096 + cg) = o;
    }
}

// Per-query top-20 from u16 key row; composites (k16<<12)|j make ties exact
// (equal truncated keys -> smallest index, matching jax.lax.top_k). 1 wave/blk.
__global__ __launch_bounds__(64) void topk_select2(const u16* __restrict__ keyA,
                                                   const u16* __restrict__ keyB,
                                                   int* __restrict__ nnA,
                                                   int* __restrict__ nnB) {
    const int side = blockIdx.x >> 12;
    const int q = blockIdx.x & 4095;
    const u16* krow = (side ? keyB : keyA) + (size_t)q * 4096;
    int* nn = (side ? nnB : nnA) + (size_t)q * KNBR;

    __shared__ u32 kbuf[64 * 68];
    const int lane = threadIdx.x;

    // coalesced load: 16 x uint2 per lane (4 u16 keys each) -> composites
#pragma unroll
    for (int t = 0; t < 16; ++t) {
        int j0 = t * 256 + lane * 4;
        uint2 pk = *(const uint2*)(krow + j0);
        int g = j0 >> 6, idx = j0 & 63;
        u32* dst = &kbuf[g * 68 + idx];
        dst[0] = ((pk.x & 0xFFFFu) << 12) | (u32)(j0 + 0);
        dst[1] = ((pk.x >> 16) << 12) | (u32)(j0 + 1);
        dst[2] = ((pk.y & 0xFFFFu) << 12) | (u32)(j0 + 2);
        dst[3] = ((pk.y >> 16) << 12) | (u32)(j0 + 3);
    }

    volatile u32* kq = (volatile u32*)kbuf;

    // L1: lane l = min of group l (j in [64l, 64l+64))
    u32 l1;
    {
        const int base = lane * 68;
        u32 m0 = 0xFFFFFFFFu, m1 = 0xFFFFFFFFu, m2 = 0xFFFFFFFFu, m3 = 0xFFFFFFFFu;
#pragma unroll
        for (int t = 0; t < 64; t += 4) {
            u32 a = kq[base + t + 0];
            u32 b = kq[base + t + 1];
            u32 c = kq[base + t + 2];
            u32 d = kq[base + t + 3];
            m0 = a < m0 ? a : m0;
            m1 = b < m1 ? b : m1;
            m2 = c < m2 ? c : m2;
            m3 = d < m3 ? d : m3;
        }
        m0 = m1 < m0 ? m1 : m0;
        m2 = m3 < m2 ? m3 : m2;
        l1 = m2 < m0 ? m2 : m0;
    }

    int myj = 0;
    for (int r = 0; r < KNBR; ++r) {
        u32 m = wave_min_u32_bcast(l1);              // unique global min composite
        u64 gmask = __ballot(l1 == m);
        int g = __builtin_ctzll(gmask);
        u32 v = kq[g * 68 + lane];
        u64 wmask = __ballot(v == m);
        int jl = __builtin_ctzll(wmask);
        if (lane == jl) kq[g * 68 + jl] = 0xFFFFFFFFu;
        u32 v2 = (lane == jl) ? 0xFFFFFFFFu : v;
        u32 nm = wave_min_u32_bcast(v2);
        if (lane == g) l1 = nm;
        if (lane == r) myj = (int)(m & 0xFFFu);
    }
    if (lane < KNBR) nn[lane] = myj;
}

// Fallback (round-6) fused topk for the non-MFMA path.
__global__ __launch_bounds__(128) void topk_all_kernel(const float* __restrict__ embA,
                                                       const float* __restrict__ sqA,
                                                       const float* __restrict__ embB,
                                                       const float* __restrict__ sqB,
                                                       int* __restrict__ nnA,
                                                       int* __restrict__ nnB) {
    const int side = blockIdx.x >> 11;
    const int q0 = (blockIdx.x & 2047) * 2;
    const float* embQ = side ? embB : embA;
    const float* embC = side ? embA : embB;
    const float* sqCc = side ? sqA : sqB;
    int* nnOut = side ? nnB : nnA;

    __shared__ u32 keys[2][64 * 65];

    const int tid = threadIdx.x;
    const int lane = tid & 63, w = tid >> 6;

    float4 q0v[8], q1v[8];
    {
        const float4* e0 = (const float4*)(embQ + (size_t)q0 * 32);
        const float4* e1 = (const float4*)(embQ + (size_t)(q0 + 1) * 32);
#pragma unroll
        for (int c = 0; c < 8; ++c) { q0v[c] = e0[c]; q1v[c] = e1[c]; }
    }

    for (int i = 0; i < 32; ++i) {
        int j = (i << 7) + tid;
        const float4* ec = (const float4*)(embC + (size_t)j * 32);
        float d0 = 0.f, d1 = 0.f;
#pragma unroll
        for (int c = 0; c < 8; ++c) {
            float4 cv = ec[c];
            d0 += q0v[c].x * cv.x + q0v[c].y * cv.y + q0v[c].z * cv.z + q0v[c].w * cv.w;
            d1 += q1v[c].x * cv.x + q1v[c].y * cv.y + q1v[c].z * cv.z + q1v[c].w * cv.w;
        }
        float sc = sqCc[j];
        int off = (j >> 6) * 65 + (j & 63);
        keys[0][off] = fkey(sc - 2.f * d0);
        keys[1][off] = fkey(sc - 2.f * d1);
    }
    __syncthreads();

    volatile u32* kq = (volatile u32*)&keys[w][0];

    u32 l1;
    {
        const int base = lane * 65;
        u32 m0 = 0xFFFFFFFFu, m1 = 0xFFFFFFFFu, m2 = 0xFFFFFFFFu, m3 = 0xFFFFFFFFu;
#pragma unroll
        for (int t = 0; t < 64; t += 4) {
            u32 a = kq[base + t + 0];
            u32 b = kq[base + t + 1];
            u32 c = kq[base + t + 2];
            u32 d = kq[base + t + 3];
            m0 = a < m0 ? a : m0;
            m1 = b < m1 ? b : m1;
            m2 = c < m2 ? c : m2;
            m3 = d < m3 ? d : m3;
        }
        m0 = m1 < m0 ? m1 : m0;
        m2 = m3 < m2 ? m3 : m2;
        l1 = m2 < m0 ? m2 : m0;
    }

    int myj = 0;
    for (int r = 0; r < KNBR; ++r) {
        u32 m = wave_min_u32_bcast(l1);
        u64 gmask = __ballot(l1 == m);
        int g = __builtin_ctzll(gmask);
        u32 v = kq[g * 65 + lane];
        u64 wmask = __ballot(v == m);
        int jl = __builtin_ctzll(wmask);
        if (lane == jl) kq[g * 65 + jl] = 0xFFFFFFFFu;
        u32 v2 = (lane == jl) ? 0xFFFFFFFFu : v;
        u32 nm = wave_min_u32_bcast(v2);
        if (lane == g) l1 = nm;
        if (lane == r) myj = (g << 6) | jl;
    }
    if (lane < KNBR) nnOut[(size_t)(q0 + w) * KNBR + lane] = myj;
}

// ---------------------------------------------------------------------------
// Fused gather-mean + MSE partials, bf16 ximp, both sides in one launch.
__global__ __launch_bounds__(256) void predloss_bf16_kernel(const int* __restrict__ nnA,
                                                            const int* __restrict__ nnB,
                                                            const u16* __restrict__ ximpBbf,
                                                            const u16* __restrict__ ximpAbf,
                                                            const float* __restrict__ xA,
                                                            const float* __restrict__ xB,
                                                            float* __restrict__ partA,
                                                            float* __restrict__ partB) {
    const int side = blockIdx.x >> 12;
    const int q = blockIdx.x & 4095;
    const int* nn = (side ? nnB : nnA) + (size_t)q * KNBR;
    const u16* ximp = side ? ximpAbf : ximpBbf;
    const float* xtrue = (side ? xB : xA) + (size_t)q * 3000;
    float* partial = side ? partB : partA;

    __shared__ int nns[KNBR];
    __shared__ float red[256];
    if (threadIdx.x < KNBR) nns[threadIdx.x] = nn[threadIdx.x];
    __syncthreads();

    int nr[KNBR];
#pragma unroll
    for (int t = 0; t < KNBR; ++t) nr[t] = nns[t];

    const float inv = 1.0f / KNBR;
    float sse = 0.f;
    for (int v = threadIdx.x; v < 375; v += 256) {
        float acc[8] = {};
#pragma unroll
        for (int t = 0; t < KNBR; ++t) {
            uint4 pk = *(const uint4*)(ximp + (size_t)nr[t] * KPAD + v * 8);
            acc[0] += bf2f((u16)(pk.x & 0xFFFF));
            acc[1] += bf2f((u16)(pk.x >> 16));
            acc[2] += bf2f((u16)(pk.y & 0xFFFF));
            acc[3] += bf2f((u16)(pk.y >> 16));
            acc[4] += bf2f((u16)(pk.z & 0xFFFF));
            acc[5] += bf2f((u16)(pk.z >> 16));
            acc[6] += bf2f((u16)(pk.w & 0xFFFF));
            acc[7] += bf2f((u16)(pk.w >> 16));
        }
        const float4 x0 = *(const float4*)(xtrue + v * 8);
        const float4 x1 = *(const float4*)(xtrue + v * 8 + 4);
        float d0 = acc[0] * inv - x0.x;
        float d1 = acc[1] * inv - x0.y;
        float d2 = acc[2] * inv - x0.z;
        float d3 = acc[3] * inv - x0.w;
        float d4 = acc[4] * inv - x1.x;
        float d5 = acc[5] * inv - x1.y;
        float d6 = acc[6] * inv - x1.z;
        float d7 = acc[7] * inv - x1.w;
        sse += d0 * d0 + d1 * d1 + d2 * d2 + d3 * d3
             + d4 * d4 + d5 * d5 + d6 * d6 + d7 * d7;
    }
    red[threadIdx.x] = sse;
    __syncthreads();
    for (int off = 128; off > 0; off >>= 1) {
        if (threadIdx.x < off) red[threadIdx.x] += red[threadIdx.x + off];
        __syncthreads();
    }
    if (threadIdx.x == 0) partial[q] = red[0];
}

// Fallback f32 predloss
__global__ __launch_bounds__(256) void predloss_kernel(const int* __restrict__ nn,
                                                       const float* __restrict__ ximp,
                                                       const float* __restrict__ xtrue,
                                                       float* __restrict__ partial) {
    int q = blockIdx.x;
    __shared__ int nns[KNBR];
    __shared__ float red[256];
    if (threadIdx.x < KNBR) nns[threadIdx.x] = nn[(size_t)q * KNBR + threadIdx.x];
    __syncthreads();

    int nr[KNBR];
#pragma unroll
    for (int t = 0; t < KNBR; ++t) nr[t] = nns[t];

    const float inv = 1.0f / KNBR;
    float sse = 0.f;
    for (int v = threadIdx.x; v < 750; v += 256) {
        float4 acc = {0.f, 0.f, 0.f, 0.f};
#pragma unroll
        for (int t = 0; t < KNBR; ++t) {
            const float4 w = *(const float4*)(ximp + (size_t)nr[t] * 3000 + v * 4);
            acc.x += w.x; acc.y += w.y; acc.z += w.z; acc.w += w.w;
        }
        const float4 xt = *(const float4*)(xtrue + (size_t)q * 3000 + v * 4);
        float dx = acc.x * inv - xt.x;
        float dy = acc.y * inv - xt.y;
        float dz = acc.z * inv - xt.z;
        float dw = acc.w * inv - xt.w;
        sse += dx * dx + dy * dy + dz * dz + dw * dw;
    }
    red[threadIdx.x] = sse;
    __syncthreads();
    for (int off = 128; off > 0; off >>= 1) {
        if (threadIdx.x < off) red[threadIdx.x] += red[threadIdx.x + off];
        __syncthreads();
    }
    if (threadIdx.x == 0) partial[q] = red[0];
}

__global__ __launch_bounds__(256) void loss_final_kernel(const float* __restrict__ pA,
                                                         const float* __restrict__ pB,
                                                         float* __restrict__ out) {
    __shared__ double red[256];
    double sa = 0.0, sb = 0.0;
    for (int i = threadIdx.x; i < 4096; i += 256) {
        sa += (double)pA[i];
        sb += (double)pB[i];
    }
    red[threadIdx.x] = sa;
    __syncthreads();
    for (int off = 128; off > 0; off >>= 1) {
        if (threadIdx.x < off) red[threadIdx.x] += red[threadIdx.x + off];
        __syncthreads();
    }
    double totA = red[0];
    __syncthreads();
    red[threadIdx.x] = sb;
    __syncthreads();
    for (int off = 128; off > 0; off >>= 1) {
        if (threadIdx.x < off) red[threadIdx.x] += red[threadIdx.x + off];
        __syncthreads();
    }
    if (threadIdx.x == 0) {
        double denom = 4096.0 * 3000.0;
        out[0] = (float)(totA / denom + red[0] / denom);
    }
}

// ---------------------------------------------------------------------------
extern "C" void kernel_launch(void* const* d_in, const int* in_sizes, int n_in,
                              void* d_out, int out_size, void* d_ws, size_t ws_size,
                              hipStream_t stream) {
    const float* x_A = (const float*)d_in[0];
    const float* x_B = (const float*)d_in[1];
    const float* G   = (const float*)d_in[2];
    const float* W1  = (const float*)d_in[3];
    const float* b1  = (const float*)d_in[4];
    const float* W2  = (const float*)d_in[5];
    const float* b2  = (const float*)d_in[6];
    const float* WcA = (const float*)d_in[7];
    const float* bcA = (const float*)d_in[8];
    const float* WcB = (const float*)d_in[9];
    const float* bcB = (const float*)d_in[10];

    float* outp = (float*)d_out;

    size_t off = 0;
    char* base = (char*)d_ws;
    auto carve = [&](size_t bytes) -> void* {
        void* p = base + off;
        off = (off + bytes + 255) & ~(size_t)255;
        return p;
    };
    // f32 ximp: FALLBACK path only; on bf16 path this region hosts keyA (u16).
    float* ximpA = (float*)carve((size_t)N_A * G_B * 4);
    float* ximpB = (float*)carve((size_t)N_B * G_A * 4);
    float* normA = (float*)carve(G_A * 4);
    float* normB = (float*)carve(G_B * 4);
    float* colpart = (float*)carve(25 * G_B * 4);
    float* embA = (float*)carve((size_t)N_A * 32 * 4);
    float* embB = (float*)carve((size_t)N_B * 32 * 4);
    float* sqA = (float*)carve(N_A * 4);
    float* sqB = (float*)carve(N_B * 4);
    float* partA = (float*)carve(N_A * 4);
    float* partB = (float*)carve(N_B * 4);
    int* nnA = (int*)carve((size_t)N_A * KNBR * 4);
    int* nnB = (int*)carve((size_t)N_B * KNBR * 4);
    u16* xAbf = (u16*)carve((size_t)N_A * KPAD * 2);   // region start for keyB alias
    u16* xBbf = (u16*)carve((size_t)N_B * KPAD * 2);
    u16* Gbf  = (u16*)carve((size_t)KPAD * KPAD * 2);
    u16* Gtbf = (u16*)carve((size_t)KPAD * KPAD * 2);
    u16* ximpAbf = (u16*)carve((size_t)N_A * KPAD * 2);   // live until predloss
    u16* ximpBbf = (u16*)carve((size_t)N_B * KPAD * 2);   // live until predloss
    u16* W1tbf   = (u16*)carve((size_t)64 * KMLP * 2);
    float* mlppart = (float*)carve((size_t)4 * 8192 * 64 * 4);
    size_t full_needed = off;

    // Aliases (bf16 path only):
    // keyA (33.5 MB u16) over dead f32 ximpA/ximpB (98.4 MB).
    // keyB (33.5 MB u16) over dead xAbf..Gtbf (88.1 MB, dead after mlp1).
    // norm partials (2 x 1.2 MB) over mlppart (written later by mlp1).
    u16* keyA = (u16*)ximpA;
    u16* keyB = (u16*)xAbf;
    float* rowpart  = mlppart;                    // [96][KPAD]
    float* colpart2 = mlppart + 96 * KPAD;        // [96][KPAD]

    const bool use_mfma = (ws_size >= full_needed);

    if (use_mfma) {
        // 1) bf16 conversions; G read ONCE (dual layout + fused norm partials)
        convert_pad2_kernel<<<2 * (N_A * (KPAD / 8)) / 256, 256, 0, stream>>>(x_A, x_B, xAbf, xBbf);
        g_convert_dual_norm_kernel<<<dim3(96, 96), 256, 0, stream>>>(G, Gbf, Gtbf, rowpart, colpart2);
        norm_final_kernel<<<24, 256, 0, stream>>>(rowpart, colpart2, normA, normB);
        w1t_kernel<<<(64 * KMLP) / 256, 256, 0, stream>>>(W1, W1tbf);

        // 2) both imputation GEMMs in ONE launch (bf16 out, linear tiles)
        mfma_impute2_gemm<<<dim3(KPAD / 128, N_A / 128, 2), 256, 0, stream>>>(
            xAbf, xBbf, Gtbf, Gbf, normB, normA, ximpAbf, ximpBbf);

        // 3) MLP via MFMA + K-split (clobbers rowpart/colpart2 -> consumed)
        mlp1_kernel<<<dim3(4, 128), 256, 0, stream>>>(xAbf, ximpAbf, ximpBbf, xBbf, W1tbf, mlppart);
        mlp2_kernel<<<128, 256, 0, stream>>>(mlppart, b1, W2, b2, embA, embB, sqA, sqB);

        // 4) class predictions -> d_out (one launch)
        preds2_kernel<<<880, 256, 0, stream>>>(embA, embB, WcA, bcA, WcB, bcB, outp);

        // 5) top-20: u16 key GEMMs (one launch) + select (one launch)
        distkey2_gemm<<<dim3(32, 32, 2), 256, 0, stream>>>(embA, embB, sqA, sqB, keyA, keyB);
        topk_select2<<<8192, 64, 0, stream>>>(keyA, keyB, nnA, nnB);

        // 6) fused gather-mean + MSE partials (bf16 ximp, both sides)
        predloss_bf16_kernel<<<8192, 256, 0, stream>>>(nnA, nnB, ximpBbf, ximpAbf,
                                                       x_A, x_B, partA, partB);
    } else {
        row_sum_kernel<<<G_A, 256, 0, stream>>>(G, normA);
        col_partial_kernel<<<dim3(12, 25), 256, 0, stream>>>(G, colpart);
        col_final_kernel<<<12, 256, 0, stream>>>(colpart, normB);
        dim3 ggrid(24, 32);
        impute_gemm<false><<<ggrid, 256, 0, stream>>>(x_A, G, normB, ximpA);
        impute_gemm<true><<<ggrid, 256, 0, stream>>>(x_B, G, normA, ximpB);
        mlp_kernel<<<128, 256, 0, stream>>>(x_A, ximpA, ximpB, x_B, W1, b1, W2, b2, embA, embB);
        sqnorm_kernel<<<16, 256, 0, stream>>>(embA, sqA);
        sqnorm_kernel<<<16, 256, 0, stream>>>(embB, sqB);
        preds_kernel<<<(N_A * NCA) / 256, 256, 0, stream>>>(embA, WcA, bcA, outp, NCA);
        preds_kernel<<<(N_B * NCB) / 256, 256, 0, stream>>>(embB, WcB, bcB, outp + (size_t)N_A * NCA, NCB);
        topk_all_kernel<<<4096, 128, 0, stream>>>(embA, sqA, embB, sqB, nnA, nnB);
        predloss_kernel<<<N_A, 256, 0, stream>>>(nnA, ximpB, x_A, partA);
        predloss_kernel<<<N_B, 256, 0, stream>>>(nnB, ximpA, x_B, partB);
    }

    // 7) final loss
    loss_final_kernel<<<1, 256, 0, stream>>>(partA, partB, outp + (size_t)N_A * NCA + (size_t)N_B * NCB);

    (void)in_sizes; (void)n_in; (void)out_size;
}

// Round 11
// 465.424 us; speedup vs baseline: 3.4106x; 1.0117x over previous
//
#include <hip/hip_runtime.h>
#include <cfloat>
#include <cstddef>
#include <climits>

// Problem constants
#define N_A   4096
#define N_B   4096
#define G_A   3000
#define G_B   3000
#define NCA   30
#define NCB   25
#define KNBR  20
#define KPAD  3072   // K/N padding for MFMA tiles (multiple of 128)
#define KREAL 3008   // 47*64: real K (3000) rounded up to BK; tiles beyond are all-zero
#define KMLP  6144   // padded MLP K ( = 2*KPAD )

typedef unsigned short u16;
typedef unsigned int u32;
typedef unsigned long long u64;
typedef __bf16 bf16x8 __attribute__((ext_vector_type(8)));
typedef float f32x4 __attribute__((ext_vector_type(4)));
typedef __attribute__((address_space(1))) const void* as1_cvp;
typedef __attribute__((address_space(3))) void* as3_vp;

static __device__ __forceinline__ u16 f2bf(float f) {
    union { float f; unsigned u; } v; v.f = f;
    unsigned r = v.u + 0x7fffu + ((v.u >> 16) & 1u);   // RTNE
    return (u16)(r >> 16);
}

static __device__ __forceinline__ float bf2f(u16 h) {
    union { unsigned u; float f; } v; v.u = ((unsigned)h) << 16;
    return v.f;
}

// monotonic float -> u32 key (ascending float == ascending unsigned)
static __device__ __forceinline__ u32 fkey(float f) {
    union { float f; u32 u; } v; v.f = f;
    return (v.u & 0x80000000u) ? ~v.u : (v.u | 0x80000000u);
}

// 64-lane min-reduce via DPP + broadcast (lane 63 holds global min).
static __device__ __forceinline__ u32 wave_min_u32_bcast(u32 v) {
    u32 t;
    t = (u32)__builtin_amdgcn_update_dpp((int)v, (int)v, 0x111, 0xf, 0xf, false); v = t < v ? t : v;
    t = (u32)__builtin_amdgcn_update_dpp((int)v, (int)v, 0x112, 0xf, 0xf, false); v = t < v ? t : v;
    t = (u32)__builtin_amdgcn_update_dpp((int)v, (int)v, 0x114, 0xf, 0xf, false); v = t < v ? t : v;
    t = (u32)__builtin_amdgcn_update_dpp((int)v, (int)v, 0x118, 0xf, 0xf, false); v = t < v ? t : v;
    t = (u32)__builtin_amdgcn_update_dpp((int)v, (int)v, 0x142, 0xf, 0xf, false); v = t < v ? t : v;
    t = (u32)__builtin_amdgcn_update_dpp((int)v, (int)v, 0x143, 0xf, 0xf, false); v = t < v ? t : v;
    return (u32)__builtin_amdgcn_readlane((int)v, 63);
}

// ---------------------------------------------------------------------------
// normalizers (FALLBACK path only)
__global__ __launch_bounds__(256) void row_sum_kernel(const float* __restrict__ G,
                                                      float* __restrict__ normA) {
    int row = blockIdx.x;
    __shared__ float red[256];
    float s = 0.f;
    for (int j = threadIdx.x; j < G_B; j += 256) s += G[(size_t)row * G_B + j];
    red[threadIdx.x] = s;
    __syncthreads();
    for (int off = 128; off > 0; off >>= 1) {
        if (threadIdx.x < off) red[threadIdx.x] += red[threadIdx.x + off];
        __syncthreads();
    }
    if (threadIdx.x == 0) {
        float v = red[0];
        normA[row] = (v == 0.f) ? 1.f : v;
    }
}

__global__ __launch_bounds__(256) void col_partial_kernel(const float* __restrict__ G,
                                                          float* __restrict__ part) {
    int j = blockIdx.x * 256 + threadIdx.x;
    if (j >= G_B) return;
    int r0 = blockIdx.y * 120;
    float s = 0.f;
    for (int i = r0; i < r0 + 120; ++i) s += G[(size_t)i * G_B + j];
    part[(size_t)blockIdx.y * G_B + j] = s;
}

__global__ __launch_bounds__(256) void col_final_kernel(const float* __restrict__ part,
                                                        float* __restrict__ normB) {
    int j = blockIdx.x * 256 + threadIdx.x;
    if (j >= G_B) return;
    float s = 0.f;
    for (int c = 0; c < 25; ++c) s += part[(size_t)c * G_B + j];
    normB[j] = (s == 0.f) ? 1.f : s;
}

// ---------------------------------------------------------------------------
// Merged x_A + x_B f32 -> bf16 convert (zero pad) + W1 transpose-convert.
// grid 13824: [0,6144) xA, [6144,12288) xB, [12288,13824) W1t.
__global__ __launch_bounds__(256) void convert_pad2_kernel(const float* __restrict__ xA,
                                                           const float* __restrict__ xB,
                                                           const float* __restrict__ W1,
                                                           u16* __restrict__ xAbf,
                                                           u16* __restrict__ xBbf,
                                                           u16* __restrict__ W1t) {
    const int half = (N_A * (KPAD / 8)) / 256;   // 6144 blocks per x side
    if (blockIdx.x >= 2 * half) {
        // W1 [6000][64] f32 -> W1t [64][KMLP] bf16 (seg0 k<3072, seg1 k>=3072)
        int idx = (blockIdx.x - 2 * half) * 256 + threadIdx.x;   // 0..393215
        int n = idx / KMLP, kp = idx % KMLP;
        int seg = kp >= KPAD;
        int k = kp - (seg ? KPAD : 0);
        float v = (k < 3000) ? W1[(size_t)(seg * 3000 + k) * 64 + n] : 0.f;
        W1t[(size_t)n * KMLP + kp] = f2bf(v);
        return;
    }
    const int side = blockIdx.x >= half;
    const float* in = side ? xB : xA;
    u16* out = side ? xBbf : xAbf;
    int idx = (blockIdx.x - (side ? half : 0)) * 256 + threadIdx.x;
    int cpr = KPAD >> 3;
    int r = idx / cpr, c0 = (idx % cpr) << 3;
    u16 res[8] = {0, 0, 0, 0, 0, 0, 0, 0};
    if (c0 + 8 <= G_A) {
        float4 v0 = *(const float4*)(in + (size_t)r * G_A + c0);
        float4 v1 = *(const float4*)(in + (size_t)r * G_A + c0 + 4);
        res[0] = f2bf(v0.x); res[1] = f2bf(v0.y); res[2] = f2bf(v0.z); res[3] = f2bf(v0.w);
        res[4] = f2bf(v1.x); res[5] = f2bf(v1.y); res[6] = f2bf(v1.z); res[7] = f2bf(v1.w);
    }
    uint4 pack;
    pack.x = (unsigned)res[0] | ((unsigned)res[1] << 16);
    pack.y = (unsigned)res[2] | ((unsigned)res[3] << 16);
    pack.z = (unsigned)res[4] | ((unsigned)res[5] << 16);
    pack.w = (unsigned)res[6] | ((unsigned)res[7] << 16);
    *(uint4*)(out + (size_t)r * KPAD + c0) = pack;
}

// G -> Gbf + Gt bf16 padded; ALSO per-tile partial row/col sums. G read once.
__global__ __launch_bounds__(256) void g_convert_dual_norm_kernel(const float* __restrict__ G,
                                                                  u16* __restrict__ Gbf,
                                                                  u16* __restrict__ Gt,
                                                                  float* __restrict__ rowpart,
                                                                  float* __restrict__ colpart2) {
    __shared__ float t[32][33];
    int j0 = blockIdx.x * 32, k0 = blockIdx.y * 32;
    int lx = threadIdx.x & 31, ly = threadIdx.x >> 5;
#pragma unroll
    for (int i = 0; i < 4; ++i) {
        int k = k0 + ly + i * 8, j = j0 + lx;
        float v = (k < G_A && j < G_B) ? G[(size_t)k * G_B + j] : 0.f;
        t[ly + i * 8][lx] = v;
        Gbf[(size_t)k * KPAD + j] = f2bf(v);
    }
    __syncthreads();
#pragma unroll
    for (int i = 0; i < 4; ++i) {
        int j = j0 + ly + i * 8, k = k0 + lx;
        Gt[(size_t)j * KPAD + k] = f2bf(t[lx][ly + i * 8]);
    }
    if (threadIdx.x < 32) {
        int kl = threadIdx.x;
        float s = 0.f;
#pragma unroll
        for (int j2 = 0; j2 < 32; ++j2) s += t[kl][j2];
        rowpart[(size_t)blockIdx.x * KPAD + k0 + kl] = s;
    } else if (threadIdx.x < 64) {
        int jl = threadIdx.x - 32;
        float s = 0.f;
#pragma unroll
        for (int k2 = 0; k2 < 32; ++k2) s += t[k2][jl];
        colpart2[(size_t)blockIdx.y * KPAD + j0 + jl] = s;
    }
}

// Merged normA + normB finalize. grid 24: blocks 0..11 -> A, 12..23 -> B.
__global__ __launch_bounds__(256) void norm_final_kernel(const float* __restrict__ rowpart,
                                                         const float* __restrict__ colpart2,
                                                         float* __restrict__ normA,
                                                         float* __restrict__ normB) {
    if (blockIdx.x < 12) {
        int k = blockIdx.x * 256 + threadIdx.x;
        if (k >= G_A) return;
        float s = 0.f;
        for (int jt = 0; jt < 96; ++jt) s += rowpart[(size_t)jt * KPAD + k];
        normA[k] = (s == 0.f) ? 1.f : s;
    } else {
        int j = (blockIdx.x - 12) * 256 + threadIdx.x;
        if (j >= G_B) return;
        float s = 0.f;
        for (int kt = 0; kt < 96; ++kt) s += colpart2[(size_t)kt * KPAD + j];
        normB[j] = (s == 0.f) ? 1.f : s;
    }
}

// fallback W1t (non-fused path not used, kept for ws-size fallback clarity)
__global__ __launch_bounds__(256) void w1t_kernel(const float* __restrict__ W1,
                                                  u16* __restrict__ W1t) {
    int idx = blockIdx.x * 256 + threadIdx.x;
    int n = idx / KMLP, kp = idx % KMLP;
    int seg = kp >= KPAD;
    int k = kp - (seg ? KPAD : 0);
    float v = (k < 3000) ? W1[(size_t)(seg * 3000 + k) * 64 + n] : 0.f;
    W1t[(size_t)n * KMLP + kp] = f2bf(v);
}

// ---------------------------------------------------------------------------
// Merged bf16 MFMA imputation GEMM, both directions (linear tile mapping).
// K-loop runs to KREAL=3008 (47 tiles); tile [3008,3072) is all-zero pad.
__global__ __launch_bounds__(256) void mfma_impute2_gemm(const u16* __restrict__ xAbf,
                                                         const u16* __restrict__ xBbf,
                                                         const u16* __restrict__ Gtbf,
                                                         const u16* __restrict__ Gbf,
                                                         const float* __restrict__ normB,
                                                         const float* __restrict__ normA,
                                                         u16* __restrict__ ximpAbf,
                                                         u16* __restrict__ ximpBbf) {
    const int side = blockIdx.z;
    const u16* A  = side ? xBbf : xAbf;
    const u16* Bt = side ? Gbf : Gtbf;
    const float* norm = side ? normA : normB;
    u16* outbf = side ? ximpBbf : ximpAbf;

    const int col_base = blockIdx.x * 128;
    const int row_base = blockIdx.y * 128;

    __shared__ __align__(16) u16 lAs[128 * 64];
    __shared__ __align__(16) u16 lBs[128 * 64];

    const int tid = threadIdx.x;
    const int w = tid >> 6, lane = tid & 63;
    const int wr = (w >> 1) * 64, wc = (w & 1) * 64;

    f32x4 acc[4][4] = {};

    int s_r[4], s_off[4];
#pragma unroll
    for (int i = 0; i < 4; ++i) {
        int slin = (w * 4 + i) * 64 + lane;
        int r = slin >> 3, s = slin & 7;
        s_r[i] = r;
        s_off[i] = (s ^ (r & 7)) * 8;
    }

    for (int k0 = 0; k0 < KREAL; k0 += 64) {
#pragma unroll
        for (int i = 0; i < 4; ++i) {
            const u16* ga = A + (size_t)(row_base + s_r[i]) * KPAD + k0 + s_off[i];
            __builtin_amdgcn_global_load_lds((as1_cvp)ga,
                (as3_vp)(lAs + (size_t)(w * 4 + i) * 512), 16, 0, 0);
        }
#pragma unroll
        for (int i = 0; i < 4; ++i) {
            const u16* gb = Bt + (size_t)(col_base + s_r[i]) * KPAD + k0 + s_off[i];
            __builtin_amdgcn_global_load_lds((as1_cvp)gb,
                (as3_vp)(lBs + (size_t)(w * 4 + i) * 512), 16, 0, 0);
        }
        __syncthreads();

#pragma unroll
        for (int kk = 0; kk < 2; ++kk) {
            bf16x8 a[4], b[4];
#pragma unroll
            for (int m = 0; m < 4; ++m) {
                int row = wr + m * 16 + (lane & 15);
                int slot = (kk * 4 + (lane >> 4)) ^ (row & 7);
                a[m] = *(const bf16x8*)(lAs + row * 64 + slot * 8);
            }
#pragma unroll
            for (int n = 0; n < 4; ++n) {
                int row = wc + n * 16 + (lane & 15);
                int slot = (kk * 4 + (lane >> 4)) ^ (row & 7);
                b[n] = *(const bf16x8*)(lBs + row * 64 + slot * 8);
            }
#pragma unroll
            for (int m = 0; m < 4; ++m)
#pragma unroll
                for (int n = 0; n < 4; ++n)
                    acc[m][n] = __builtin_amdgcn_mfma_f32_16x16x32_bf16(a[m], b[n], acc[m][n], 0, 0, 0);
        }
        __syncthreads();
    }

#pragma unroll
    for (int n = 0; n < 4; ++n) {
        int col = col_base + wc + n * 16 + (lane & 15);
        bool valid = col < G_B;
        float rn = valid ? 1.0f / norm[col] : 0.f;
#pragma unroll
        for (int m = 0; m < 4; ++m) {
            int row = row_base + wr + m * 16 + (lane >> 4) * 4;
#pragma unroll
            for (int r = 0; r < 4; ++r)
                outbf[(size_t)(row + r) * KPAD + col] = f2bf(acc[m][n][r] * rn);
        }
    }
}

// ---------------------------------------------------------------------------
// MLP layer 1 (bf16 MFMA, K-split). Odd chunks cover global k [1536,3072);
// trim loop to 1472 so the all-zero region [3008,3072) is skipped.
__global__ __launch_bounds__(256) void mlp1_kernel(const u16* __restrict__ xAbf,
                                                   const u16* __restrict__ ximpAbf,
                                                   const u16* __restrict__ ximpBbf,
                                                   const u16* __restrict__ xBbf,
                                                   const u16* __restrict__ W1t,
                                                   float* __restrict__ partial) {
    const int chunk = blockIdx.x;
    const int rb = blockIdx.y;
    const int side = rb >> 6;
    const int r0 = (rb & 63) * 64;
    const int seg = chunk >> 1;
    const u16* src = side ? (seg ? xBbf : ximpBbf) : (seg ? ximpAbf : xAbf);
    const int k0base = (chunk & 1) * 1536;
    const int kend = (chunk & 1) ? 1472 : 1536;

    __shared__ __align__(16) u16 lAs[64 * 64];
    __shared__ __align__(16) u16 lBs[64 * 64];

    const int tid = threadIdx.x;
    const int w = tid >> 6, lane = tid & 63;

    int s_r[2], s_off[2];
#pragma unroll
    for (int i = 0; i < 2; ++i) {
        int slin = (w * 2 + i) * 64 + lane;
        int r = slin >> 3, s = slin & 7;
        s_r[i] = r;
        s_off[i] = (s ^ (r & 7)) * 8;
    }

    f32x4 acc[4] = {};

    for (int k0 = 0; k0 < kend; k0 += 64) {
#pragma unroll
        for (int i = 0; i < 2; ++i) {
            const u16* ga = src + (size_t)(r0 + s_r[i]) * KPAD + k0base + k0 + s_off[i];
            __builtin_amdgcn_global_load_lds((as1_cvp)ga,
                (as3_vp)(lAs + (size_t)(w * 2 + i) * 512), 16, 0, 0);
        }
#pragma unroll
        for (int i = 0; i < 2; ++i) {
            const u16* gb = W1t + (size_t)s_r[i] * KMLP + chunk * 1536 + k0 + s_off[i];
            __builtin_amdgcn_global_load_lds((as1_cvp)gb,
                (as3_vp)(lBs + (size_t)(w * 2 + i) * 512), 16, 0, 0);
        }
        __syncthreads();

#pragma unroll
        for (int kk = 0; kk < 2; ++kk) {
            int arow = w * 16 + (lane & 15);
            int aslot = (kk * 4 + (lane >> 4)) ^ (arow & 7);
            bf16x8 a = *(const bf16x8*)(lAs + arow * 64 + aslot * 8);
#pragma unroll
            for (int n = 0; n < 4; ++n) {
                int brow = n * 16 + (lane & 15);
                int bslot = (kk * 4 + (lane >> 4)) ^ (brow & 7);
                bf16x8 b = *(const bf16x8*)(lBs + brow * 64 + bslot * 8);
                acc[n] = __builtin_amdgcn_mfma_f32_16x16x32_bf16(a, b, acc[n], 0, 0, 0);
            }
        }
        __syncthreads();
    }

    const size_t grow0 = (size_t)rb * 64;
#pragma unroll
    for (int n = 0; n < 4; ++n) {
        int col = n * 16 + (lane & 15);
        int rowl = w * 16 + (lane >> 4) * 4;
#pragma unroll
        for (int r = 0; r < 4; ++r)
            partial[((size_t)chunk * 8192 + grow0 + rowl + r) * 64 + col] = acc[n][r];
    }
}

// MLP reduce + layer 2 + fused sqnorm
__global__ __launch_bounds__(256) void mlp2_kernel(const float* __restrict__ partial,
                                                   const float* __restrict__ b1,
                                                   const float* __restrict__ W2,
                                                   const float* __restrict__ b2,
                                                   float* __restrict__ embA,
                                                   float* __restrict__ embB,
                                                   float* __restrict__ sqA,
                                                   float* __restrict__ sqB) {
    const int rb = blockIdx.x;
    const int side = rb >> 6;
    const size_t grow0 = (size_t)rb * 64;
    const int r0 = (rb & 63) * 64;
    float* emb = side ? embB : embA;
    float* sq = side ? sqB : sqA;

    __shared__ float Hs[64][65];
    __shared__ float W2s[64][32];
    const int tid = threadIdx.x;

    {
        const float4* srcw = (const float4*)W2;
        float4* dst = (float4*)&W2s[0][0];
        for (int i = tid; i < 512; i += 256) dst[i] = srcw[i];
    }

    for (int v = tid; v < 1024; v += 256) {
        int row = v >> 4, c4 = v & 15;
        float4 s = {0.f, 0.f, 0.f, 0.f};
#pragma unroll
        for (int c = 0; c < 4; ++c) {
            const float4 p = *(const float4*)(partial + ((size_t)c * 8192 + grow0 + row) * 64 + c4 * 4);
            s.x += p.x; s.y += p.y; s.z += p.z; s.w += p.w;
        }
        const float4 bb = *(const float4*)(b1 + c4 * 4);
        Hs[row][c4 * 4 + 0] = fmaxf(s.x + bb.x, 0.f);
        Hs[row][c4 * 4 + 1] = fmaxf(s.y + bb.y, 0.f);
        Hs[row][c4 * 4 + 2] = fmaxf(s.z + bb.z, 0.f);
        Hs[row][c4 * 4 + 3] = fmaxf(s.w + bb.w, 0.f);
    }
    __syncthreads();

    const int c2 = tid & 31, rg = tid >> 5;
    float acc2[8] = {};
    for (int k = 0; k < 64; ++k) {
        float wv = W2s[k][c2];
#pragma unroll
        for (int i = 0; i < 8; ++i) acc2[i] += Hs[rg * 8 + i][k] * wv;
    }
    float bb = b2[c2];
    float e[8];
#pragma unroll
    for (int i = 0; i < 8; ++i) {
        e[i] = fmaxf(acc2[i] + bb, 0.f);
        emb[(size_t)(r0 + rg * 8 + i) * 32 + c2] = e[i];
    }
#pragma unroll
    for (int i = 0; i < 8; ++i) {
        float v = e[i] * e[i];
#pragma unroll
        for (int off = 16; off > 0; off >>= 1) v += __shfl_xor(v, off, 32);
        if (c2 == 0) sq[r0 + rg * 8 + i] = v;
    }
}

// ---------------------------------------------------------------------------
// Fallback f32 GEMM
template <bool TRANSB>
__global__ __launch_bounds__(256) void impute_gemm(const float* __restrict__ X,
                                                   const float* __restrict__ G,
                                                   const float* __restrict__ norm,
                                                   float* __restrict__ out) {
    __shared__ float As[8][128];
    __shared__ float Bs[8][128];
    const int tid = threadIdx.x;
    const int col_base = blockIdx.x * 128;
    const int row_base = blockIdx.y * 128;
    const int tx = tid & 15;
    const int ty = tid >> 4;
    float acc[8][8] = {};
    const int a_row = tid >> 1;
    const int a_k   = (tid & 1) * 4;
    for (int k0 = 0; k0 < G_B; k0 += 8) {
        {
            float4 av = *(const float4*)(X + (size_t)(row_base + a_row) * G_B + k0 + a_k);
            As[a_k + 0][a_row] = av.x;
            As[a_k + 1][a_row] = av.y;
            As[a_k + 2][a_row] = av.z;
            As[a_k + 3][a_row] = av.w;
        }
        if (!TRANSB) {
            const int bk = tid >> 5;
            const int bc = (tid & 31) * 4;
            float4 bv = {0.f, 0.f, 0.f, 0.f};
            if (col_base + bc < G_B)
                bv = *(const float4*)(G + (size_t)(k0 + bk) * G_B + col_base + bc);
            *(float4*)&Bs[bk][bc] = bv;
        } else {
            const int bj = tid >> 1;
            const int bk = (tid & 1) * 4;
            float4 bv = {0.f, 0.f, 0.f, 0.f};
            if (col_base + bj < G_B)
                bv = *(const float4*)(G + (size_t)(col_base + bj) * G_B + k0 + bk);
            Bs[bk + 0][bj] = bv.x;
            Bs[bk + 1][bj] = bv.y;
            Bs[bk + 2][bj] = bv.z;
            Bs[bk + 3][bj] = bv.w;
        }
        __syncthreads();
#pragma unroll
        for (int kk = 0; kk < 8; ++kk) {
            float4 a0 = *(const float4*)&As[kk][ty * 8];
            float4 a1 = *(const float4*)&As[kk][ty * 8 + 4];
            float4 b0 = *(const float4*)&Bs[kk][tx * 8];
            float4 b1 = *(const float4*)&Bs[kk][tx * 8 + 4];
            float a_[8] = {a0.x, a0.y, a0.z, a0.w, a1.x, a1.y, a1.z, a1.w};
            float b_[8] = {b0.x, b0.y, b0.z, b0.w, b1.x, b1.y, b1.z, b1.w};
#pragma unroll
            for (int i = 0; i < 8; ++i)
#pragma unroll
                for (int j = 0; j < 8; ++j) acc[i][j] += a_[i] * b_[j];
        }
        __syncthreads();
    }
    const int cg = col_base + tx * 8;
    if (cg < G_B) {
        float rn[8];
#pragma unroll
        for (int j = 0; j < 8; ++j) rn[j] = 1.0f / norm[cg + j];
#pragma unroll
        for (int i = 0; i < 8; ++i) {
            float4 o0 = {acc[i][0] * rn[0], acc[i][1] * rn[1], acc[i][2] * rn[2], acc[i][3] * rn[3]};
            float4 o1 = {acc[i][4] * rn[4], acc[i][5] * rn[5], acc[i][6] * rn[6], acc[i][7] * rn[7]};
            size_t o = (size_t)(row_base + ty * 8 + i) * G_B + cg;
            *(float4*)(out + o) = o0;
            *(float4*)(out + o + 4) = o1;
        }
    }
}

// Fallback MLP (f32)
#define MLP_TK 24
__global__ __launch_bounds__(256) void mlp_kernel(const float* __restrict__ xA,
                                                  const float* __restrict__ ximpA,
                                                  const float* __restrict__ ximpB,
                                                  const float* __restrict__ xB,
                                                  const float* __restrict__ W1,
                                                  const float* __restrict__ b1,
                                                  const float* __restrict__ W2,
                                                  const float* __restrict__ b2,
                                                  float* __restrict__ embA,
                                                  float* __restrict__ embB) {
    __shared__ float Xs[MLP_TK][64];
    __shared__ float Ws[MLP_TK][64];
    __shared__ float Hs[64][65];
    __shared__ float W2s[64][32];

    const int side = blockIdx.x >> 6;
    const int row0 = (blockIdx.x & 63) * 64;
    const float* srcL = side ? ximpB : xA;
    const float* srcR = side ? xB : ximpA;
    float* emb = side ? embB : embA;

    const int tid = threadIdx.x;
    {
        const float4* src = (const float4*)W2;
        float4* dst = (float4*)&W2s[0][0];
        for (int i = tid; i < 512; i += 256) dst[i] = src[i];
    }

    const int tx = tid & 15;
    const int ty = tid >> 4;
    float acc[4][4] = {};
    const int lrow = tid >> 2;
    const int lk6  = (tid & 3) * 6;

    for (int k0 = 0; k0 < 6000; k0 += MLP_TK) {
        const float* src = (k0 < 3000) ? srcL : srcR;
        const int kbase = (k0 < 3000) ? k0 : (k0 - 3000);
        {
            const float* p = src + (size_t)(row0 + lrow) * 3000 + kbase + lk6;
#pragma unroll
            for (int e = 0; e < 6; ++e) Xs[lk6 + e][lrow] = p[e];
        }
        {
#pragma unroll
            for (int e = 0; e < 6; ++e) {
                int idx = tid * 6 + e;
                int kk = idx >> 6, cc = idx & 63;
                Ws[kk][cc] = W1[(size_t)(k0 + kk) * 64 + cc];
            }
        }
        __syncthreads();
#pragma unroll
        for (int kk = 0; kk < MLP_TK; ++kk) {
            float4 a = *(const float4*)&Xs[kk][ty * 4];
            float4 wv = *(const float4*)&Ws[kk][tx * 4];
            float a_[4] = {a.x, a.y, a.z, a.w};
            float w_[4] = {wv.x, wv.y, wv.z, wv.w};
#pragma unroll
            for (int i = 0; i < 4; ++i)
#pragma unroll
                for (int j = 0; j < 4; ++j) acc[i][j] += a_[i] * w_[j];
        }
        __syncthreads();
    }

#pragma unroll
    for (int j = 0; j < 4; ++j) {
        float bj = b1[tx * 4 + j];
#pragma unroll
        for (int i = 0; i < 4; ++i) {
            float h = acc[i][j] + bj;
            Hs[ty * 4 + i][tx * 4 + j] = h > 0.f ? h : 0.f;
        }
    }
    __syncthreads();

    const int c2 = tid & 31;
    const int rg = tid >> 5;
    float acc2[8] = {};
    for (int k = 0; k < 64; ++k) {
        float wv = W2s[k][c2];
#pragma unroll
        for (int i = 0; i < 8; ++i) acc2[i] += Hs[rg * 8 + i][k] * wv;
    }
    float bb = b2[c2];
#pragma unroll
    for (int i = 0; i < 8; ++i) {
        float h = acc2[i] + bb;
        emb[(size_t)(row0 + rg * 8 + i) * 32 + c2] = h > 0.f ? h : 0.f;
    }
}

__global__ __launch_bounds__(256) void sqnorm_kernel(const float* __restrict__ emb,
                                                     float* __restrict__ sq) {
    int i = blockIdx.x * 256 + threadIdx.x;
    if (i >= N_A) return;
    const float4* e = (const float4*)(emb + (size_t)i * 32);
    float s = 0.f;
#pragma unroll
    for (int q = 0; q < 8; ++q) {
        float4 v = e[q];
        s += v.x * v.x + v.y * v.y + v.z * v.z + v.w * v.w;
    }
    sq[i] = s;
}

// Merged class predictions (both sides) -> d_out. grid 880: 0..479 A, 480..879 B.
__global__ __launch_bounds__(256) void preds2_kernel(const float* __restrict__ embA,
                                                     const float* __restrict__ embB,
                                                     const float* __restrict__ WcA,
                                                     const float* __restrict__ bcA,
                                                     const float* __restrict__ WcB,
                                                     const float* __restrict__ bcB,
                                                     float* __restrict__ outp) {
    const int sideB = blockIdx.x >= 480;
    const float* emb = sideB ? embB : embA;
    const float* Wc = sideB ? WcB : WcA;
    const float* bc = sideB ? bcB : bcA;
    const int ncls = sideB ? NCB : NCA;
    float* out = outp + (sideB ? (size_t)N_A * NCA : 0);
    int idx = (blockIdx.x - (sideB ? 480 : 0)) * 256 + threadIdx.x;
    int row = idx / ncls, c = idx % ncls;
    const float* e = emb + (size_t)row * 32;
    float s = bc[c];
#pragma unroll
    for (int k = 0; k < 32; ++k) s += e[k] * Wc[k * ncls + c];
    out[idx] = s;
}

// fallback single-side preds
__global__ __launch_bounds__(256) void preds_kernel(const float* __restrict__ emb,
                                                    const float* __restrict__ Wc,
                                                    const float* __restrict__ bc,
                                                    float* __restrict__ out,
                                                    int ncls) {
    int idx = blockIdx.x * 256 + threadIdx.x;
    int row = idx / ncls, c = idx % ncls;
    const float* e = emb + (size_t)row * 32;
    float s = bc[c];
#pragma unroll
    for (int k = 0; k < 32; ++k) s += e[k] * Wc[k * ncls + c];
    out[idx] = s;
}

// ---------------------------------------------------------------------------
// Distance-key GEMM, both directions, u16 keys (top 16 bits of fkey).
__global__ __launch_bounds__(256) void distkey2_gemm(const float* __restrict__ embA,
                                                     const float* __restrict__ embB,
                                                     const float* __restrict__ sqA,
                                                     const float* __restrict__ sqB,
                                                     u16* __restrict__ keyA,
                                                     u16* __restrict__ keyB) {
    const int side = blockIdx.z;
    const float* embQ = side ? embB : embA;
    const float* embC = side ? embA : embB;
    const float* sqC = side ? sqA : sqB;
    u16* keys = side ? keyB : keyA;

    __shared__ float As[32][132];
    __shared__ float Bs[32][132];

    const int tid = threadIdx.x;
    const int row_base = blockIdx.y * 128;
    const int col_base = blockIdx.x * 128;

#pragma unroll
    for (int i = 0; i < 4; ++i) {
        int idx = i * 256 + tid;
        int row = idx >> 3, k4 = (idx & 7) * 4;
        float4 a = *(const float4*)(embQ + (size_t)(row_base + row) * 32 + k4);
        As[k4 + 0][row] = a.x;
        As[k4 + 1][row] = a.y;
        As[k4 + 2][row] = a.z;
        As[k4 + 3][row] = a.w;
        float4 b = *(const float4*)(embC + (size_t)(col_base + row) * 32 + k4);
        Bs[k4 + 0][row] = b.x;
        Bs[k4 + 1][row] = b.y;
        Bs[k4 + 2][row] = b.z;
        Bs[k4 + 3][row] = b.w;
    }
    __syncthreads();

    const int tx = tid & 15, ty = tid >> 4;
    float acc[8][8] = {};
#pragma unroll
    for (int k = 0; k < 32; ++k) {
        float4 a0 = *(const float4*)&As[k][ty * 8];
        float4 a1 = *(const float4*)&As[k][ty * 8 + 4];
        float4 b0 = *(const float4*)&Bs[k][tx * 8];
        float4 b1 = *(const float4*)&Bs[k][tx * 8 + 4];
        float a_[8] = {a0.x, a0.y, a0.z, a0.w, a1.x, a1.y, a1.z, a1.w};
        float b_[8] = {b0.x, b0.y, b0.z, b0.w, b1.x, b1.y, b1.z, b1.w};
#pragma unroll
        for (int i = 0; i < 8; ++i)
#pragma unroll
            for (int j = 0; j < 8; ++j) acc[i][j] += a_[i] * b_[j];
    }

    const int cg = col_base + tx * 8;
    float sc[8];
#pragma unroll
    for (int j = 0; j < 8; ++j) sc[j] = sqC[cg + j];
#pragma unroll
    for (int i = 0; i < 8; ++i) {
        u32 k16[8];
#pragma unroll
        for (int j = 0; j < 8; ++j) k16[j] = fkey(sc[j] - 2.f * acc[i][j]) >> 16;
        uint4 o;
        o.x = k16[0] | (k16[1] << 16);
        o.y = k16[2] | (k16[3] << 16);
        o.z = k16[4] | (k16[5] << 16);
        o.w = k16[6] | (k16[7] << 16);
        *(uint4*)(keys + (size_t)(row_base + ty * 8 + i) * 4096 + cg) = o;
    }
}

// Per-query top-20 from u16 key row; composites (k16<<12)|j make ties exact.
__global__ __launch_bounds__(64) void topk_select2(const u16* __restrict__ keyA,
                                                   const u16* __restrict__ keyB,
                                                   int* __restrict__ nnA,
                                                   int* __restrict__ nnB) {
    const int side = blockIdx.x >> 12;
    const int q = blockIdx.x & 4095;
    const u16* krow = (side ? keyB : keyA) + (size_t)q * 4096;
    int* nn = (side ? nnB : nnA) + (size_t)q * KNBR;

    __shared__ u32 kbuf[64 * 68];
    const int lane = threadIdx.x;

#pragma unroll
    for (int t = 0; t < 16; ++t) {
        int j0 = t * 256 + lane * 4;
        uint2 pk = *(const uint2*)(krow + j0);
        int g = j0 >> 6, idx = j0 & 63;
        u32* dst = &kbuf[g * 68 + idx];
        dst[0] = ((pk.x & 0xFFFFu) << 12) | (u32)(j0 + 0);
        dst[1] = ((pk.x >> 16) << 12) | (u32)(j0 + 1);
        dst[2] = ((pk.y & 0xFFFFu) << 12) | (u32)(j0 + 2);
        dst[3] = ((pk.y >> 16) << 12) | (u32)(j0 + 3);
    }

    volatile u32* kq = (volatile u32*)kbuf;

    u32 l1;
    {
        const int base = lane * 68;
        u32 m0 = 0xFFFFFFFFu, m1 = 0xFFFFFFFFu, m2 = 0xFFFFFFFFu, m3 = 0xFFFFFFFFu;
#pragma unroll
        for (int t = 0; t < 64; t += 4) {
            u32 a = kq[base + t + 0];
            u32 b = kq[base + t + 1];
            u32 c = kq[base + t + 2];
            u32 d = kq[base + t + 3];
            m0 = a < m0 ? a : m0;
            m1 = b < m1 ? b : m1;
            m2 = c < m2 ? c : m2;
            m3 = d < m3 ? d : m3;
        }
        m0 = m1 < m0 ? m1 : m0;
        m2 = m3 < m2 ? m3 : m2;
        l1 = m2 < m0 ? m2 : m0;
    }

    int myj = 0;
    for (int r = 0; r < KNBR; ++r) {
        u32 m = wave_min_u32_bcast(l1);
        u64 gmask = __ballot(l1 == m);
        int g = __builtin_ctzll(gmask);
        u32 v = kq[g * 68 + lane];
        u64 wmask = __ballot(v == m);
        int jl = __builtin_ctzll(wmask);
        if (lane == jl) kq[g * 68 + jl] = 0xFFFFFFFFu;
        u32 v2 = (lane == jl) ? 0xFFFFFFFFu : v;
        u32 nm = wave_min_u32_bcast(v2);
        if (lane == g) l1 = nm;
        if (lane == r) myj = (int)(m & 0xFFFu);
    }
    if (lane < KNBR) nn[lane] = myj;
}

// Fallback (round-6) fused topk for the non-MFMA path.
__global__ __launch_bounds__(128) void topk_all_kernel(const float* __restrict__ embA,
                                                       const float* __restrict__ sqA,
                                                       const float* __restrict__ embB,
                                                       const float* __restrict__ sqB,
                                                       int* __restrict__ nnA,
                                                       int* __restrict__ nnB) {
    const int side = blockIdx.x >> 11;
    const int q0 = (blockIdx.x & 2047) * 2;
    const float* embQ = side ? embB : embA;
    const float* embC = side ? embA : embB;
    const float* sqCc = side ? sqA : sqB;
    int* nnOut = side ? nnB : nnA;

    __shared__ u32 keys[2][64 * 65];

    const int tid = threadIdx.x;
    const int lane = tid & 63, w = tid >> 6;

    float4 q0v[8], q1v[8];
    {
        const float4* e0 = (const float4*)(embQ + (size_t)q0 * 32);
        const float4* e1 = (const float4*)(embQ + (size_t)(q0 + 1) * 32);
#pragma unroll
        for (int c = 0; c < 8; ++c) { q0v[c] = e0[c]; q1v[c] = e1[c]; }
    }

    for (int i = 0; i < 32; ++i) {
        int j = (i << 7) + tid;
        const float4* ec = (const float4*)(embC + (size_t)j * 32);
        float d0 = 0.f, d1 = 0.f;
#pragma unroll
        for (int c = 0; c < 8; ++c) {
            float4 cv = ec[c];
            d0 += q0v[c].x * cv.x + q0v[c].y * cv.y + q0v[c].z * cv.z + q0v[c].w * cv.w;
            d1 += q1v[c].x * cv.x + q1v[c].y * cv.y + q1v[c].z * cv.z + q1v[c].w * cv.w;
        }
        float sc = sqCc[j];
        int off = (j >> 6) * 65 + (j & 63);
        keys[0][off] = fkey(sc - 2.f * d0);
        keys[1][off] = fkey(sc - 2.f * d1);
    }
    __syncthreads();

    volatile u32* kq = (volatile u32*)&keys[w][0];

    u32 l1;
    {
        const int base = lane * 65;
        u32 m0 = 0xFFFFFFFFu, m1 = 0xFFFFFFFFu, m2 = 0xFFFFFFFFu, m3 = 0xFFFFFFFFu;
#pragma unroll
        for (int t = 0; t < 64; t += 4) {
            u32 a = kq[base + t + 0];
            u32 b = kq[base + t + 1];
            u32 c = kq[base + t + 2];
            u32 d = kq[base + t + 3];
            m0 = a < m0 ? a : m0;
            m1 = b < m1 ? b : m1;
            m2 = c < m2 ? c : m2;
            m3 = d < m3 ? d : m3;
        }
        m0 = m1 < m0 ? m1 : m0;
        m2 = m3 < m2 ? m3 : m2;
        l1 = m2 < m0 ? m2 : m0;
    }

    int myj = 0;
    for (int r = 0; r < KNBR; ++r) {
        u32 m = wave_min_u32_bcast(l1);
        u64 gmask = __ballot(l1 == m);
        int g = __builtin_ctzll(gmask);
        u32 v = kq[g * 65 + lane];
        u64 wmask = __ballot(v == m);
        int jl = __builtin_ctzll(wmask);
        if (lane == jl) kq[g * 65 + jl] = 0xFFFFFFFFu;
        u32 v2 = (lane == jl) ? 0xFFFFFFFFu : v;
        u32 nm = wave_min_u32_bcast(v2);
        if (lane == g) l1 = nm;
        if (lane == r) myj = (g << 6) | jl;
    }
    if (lane < KNBR) nnOut[(size_t)(q0 + w) * KNBR + lane] = myj;
}

// ---------------------------------------------------------------------------
// Fused gather-mean + MSE partials, bf16 ximp, both sides in one launch.
__global__ __launch_bounds__(256) void predloss_bf16_kernel(const int* __restrict__ nnA,
                                                            const int* __restrict__ nnB,
                                                            const u16* __restrict__ ximpBbf,
                                                            const u16* __restrict__ ximpAbf,
                                                            const float* __restrict__ xA,
                                                            const float* __restrict__ xB,
                                                            float* __restrict__ partA,
                                                            float* __restrict__ partB) {
    const int side = blockIdx.x >> 12;
    const int q = blockIdx.x & 4095;
    const int* nn = (side ? nnB : nnA) + (size_t)q * KNBR;
    const u16* ximp = side ? ximpAbf : ximpBbf;
    const float* xtrue = (side ? xB : xA) + (size_t)q * 3000;
    float* partial = side ? partB : partA;

    __shared__ int nns[KNBR];
    __shared__ float red[256];
    if (threadIdx.x < KNBR) nns[threadIdx.x] = nn[threadIdx.x];
    __syncthreads();

    int nr[KNBR];
#pragma unroll
    for (int t = 0; t < KNBR; ++t) nr[t] = nns[t];

    const float inv = 1.0f / KNBR;
    float sse = 0.f;
    for (int v = threadIdx.x; v < 375; v += 256) {
        float acc[8] = {};
#pragma unroll
        for (int t = 0; t < KNBR; ++t) {
            uint4 pk = *(const uint4*)(ximp + (size_t)nr[t] * KPAD + v * 8);
            acc[0] += bf2f((u16)(pk.x & 0xFFFF));
            acc[1] += bf2f((u16)(pk.x >> 16));
            acc[2] += bf2f((u16)(pk.y & 0xFFFF));
            acc[3] += bf2f((u16)(pk.y >> 16));
            acc[4] += bf2f((u16)(pk.z & 0xFFFF));
            acc[5] += bf2f((u16)(pk.z >> 16));
            acc[6] += bf2f((u16)(pk.w & 0xFFFF));
            acc[7] += bf2f((u16)(pk.w >> 16));
        }
        const float4 x0 = *(const float4*)(xtrue + v * 8);
        const float4 x1 = *(const float4*)(xtrue + v * 8 + 4);
        float d0 = acc[0] * inv - x0.x;
        float d1 = acc[1] * inv - x0.y;
        float d2 = acc[2] * inv - x0.z;
        float d3 = acc[3] * inv - x0.w;
        float d4 = acc[4] * inv - x1.x;
        float d5 = acc[5] * inv - x1.y;
        float d6 = acc[6] * inv - x1.z;
        float d7 = acc[7] * inv - x1.w;
        sse += d0 * d0 + d1 * d1 + d2 * d2 + d3 * d3
             + d4 * d4 + d5 * d5 + d6 * d6 + d7 * d7;
    }
    red[threadIdx.x] = sse;
    __syncthreads();
    for (int off = 128; off > 0; off >>= 1) {
        if (threadIdx.x < off) red[threadIdx.x] += red[threadIdx.x + off];
        __syncthreads();
    }
    if (threadIdx.x == 0) partial[q] = red[0];
}

// Fallback f32 predloss
__global__ __launch_bounds__(256) void predloss_kernel(const int* __restrict__ nn,
                                                       const float* __restrict__ ximp,
                                                       const float* __restrict__ xtrue,
                                                       float* __restrict__ partial) {
    int q = blockIdx.x;
    __shared__ int nns[KNBR];
    __shared__ float red[256];
    if (threadIdx.x < KNBR) nns[threadIdx.x] = nn[(size_t)q * KNBR + threadIdx.x];
    __syncthreads();

    int nr[KNBR];
#pragma unroll
    for (int t = 0; t < KNBR; ++t) nr[t] = nns[t];

    const float inv = 1.0f / KNBR;
    float sse = 0.f;
    for (int v = threadIdx.x; v < 750; v += 256) {
        float4 acc = {0.f, 0.f, 0.f, 0.f};
#pragma unroll
        for (int t = 0; t < KNBR; ++t) {
            const float4 w = *(const float4*)(ximp + (size_t)nr[t] * 3000 + v * 4);
            acc.x += w.x; acc.y += w.y; acc.z += w.z; acc.w += w.w;
        }
        const float4 xt = *(const float4*)(xtrue + (size_t)q * 3000 + v * 4);
        float dx = acc.x * inv - xt.x;
        float dy = acc.y * inv - xt.y;
        float dz = acc.z * inv - xt.z;
        float dw = acc.w * inv - xt.w;
        sse += dx * dx + dy * dy + dz * dz + dw * dw;
    }
    red[threadIdx.x] = sse;
    __syncthreads();
    for (int off = 128; off > 0; off >>= 1) {
        if (threadIdx.x < off) red[threadIdx.x] += red[threadIdx.x + off];
        __syncthreads();
    }
    if (threadIdx.x == 0) partial[q] = red[0];
}

__global__ __launch_bounds__(256) void loss_final_kernel(const float* __restrict__ pA,
                                                         const float* __restrict__ pB,
                                                         float* __restrict__ out) {
    __shared__ double red[256];
    double sa = 0.0, sb = 0.0;
    for (int i = threadIdx.x; i < 4096; i += 256) {
        sa += (double)pA[i];
        sb += (double)pB[i];
    }
    red[threadIdx.x] = sa;
    __syncthreads();
    for (int off = 128; off > 0; off >>= 1) {
        if (threadIdx.x < off) red[threadIdx.x] += red[threadIdx.x + off];
        __syncthreads();
    }
    double totA = red[0];
    __syncthreads();
    red[threadIdx.x] = sb;
    __syncthreads();
    for (int off = 128; off > 0; off >>= 1) {
        if (threadIdx.x < off) red[threadIdx.x] += red[threadIdx.x + off];
        __syncthreads();
    }
    if (threadIdx.x == 0) {
        double denom = 4096.0 * 3000.0;
        out[0] = (float)(totA / denom + red[0] / denom);
    }
}

// ---------------------------------------------------------------------------
extern "C" void kernel_launch(void* const* d_in, const int* in_sizes, int n_in,
                              void* d_out, int out_size, void* d_ws, size_t ws_size,
                              hipStream_t stream) {
    const float* x_A = (const float*)d_in[0];
    const float* x_B = (const float*)d_in[1];
    const float* G   = (const float*)d_in[2];
    const float* W1  = (const float*)d_in[3];
    const float* b1  = (const float*)d_in[4];
    const float* W2  = (const float*)d_in[5];
    const float* b2  = (const float*)d_in[6];
    const float* WcA = (const float*)d_in[7];
    const float* bcA = (const float*)d_in[8];
    const float* WcB = (const float*)d_in[9];
    const float* bcB = (const float*)d_in[10];

    float* outp = (float*)d_out;

    size_t off = 0;
    char* base = (char*)d_ws;
    auto carve = [&](size_t bytes) -> void* {
        void* p = base + off;
        off = (off + bytes + 255) & ~(size_t)255;
        return p;
    };
    // f32 ximp: FALLBACK path only; on bf16 path this region hosts keyA (u16).
    float* ximpA = (float*)carve((size_t)N_A * G_B * 4);
    float* ximpB = (float*)carve((size_t)N_B * G_A * 4);
    float* normA = (float*)carve(G_A * 4);
    float* normB = (float*)carve(G_B * 4);
    float* colpart = (float*)carve(25 * G_B * 4);
    float* embA = (float*)carve((size_t)N_A * 32 * 4);
    float* embB = (float*)carve((size_t)N_B * 32 * 4);
    float* sqA = (float*)carve(N_A * 4);
    float* sqB = (float*)carve(N_B * 4);
    float* partA = (float*)carve(N_A * 4);
    float* partB = (float*)carve(N_B * 4);
    int* nnA = (int*)carve((size_t)N_A * KNBR * 4);
    int* nnB = (int*)carve((size_t)N_B * KNBR * 4);
    u16* xAbf = (u16*)carve((size_t)N_A * KPAD * 2);   // region start for keyB alias
    u16* xBbf = (u16*)carve((size_t)N_B * KPAD * 2);
    u16* Gbf  = (u16*)carve((size_t)KPAD * KPAD * 2);
    u16* Gtbf = (u16*)carve((size_t)KPAD * KPAD * 2);
    u16* ximpAbf = (u16*)carve((size_t)N_A * KPAD * 2);   // live until predloss
    u16* ximpBbf = (u16*)carve((size_t)N_B * KPAD * 2);   // live until predloss
    u16* W1tbf   = (u16*)carve((size_t)64 * KMLP * 2);
    float* mlppart = (float*)carve((size_t)4 * 8192 * 64 * 4);
    size_t full_needed = off;

    // Aliases (bf16 path only):
    // keyA (33.5 MB u16) over dead f32 ximpA/ximpB (98.4 MB).
    // keyB (33.5 MB u16) over dead xAbf..Gtbf (88.1 MB, dead after mlp1).
    // norm partials (2 x 1.2 MB) over mlppart (written later by mlp1).
    u16* keyA = (u16*)ximpA;
    u16* keyB = (u16*)xAbf;
    float* rowpart  = mlppart;                    // [96][KPAD]
    float* colpart2 = mlppart + 96 * KPAD;        // [96][KPAD]

    const bool use_mfma = (ws_size >= full_needed);

    if (use_mfma) {
        // 1) bf16 conversions; x + W1t in one launch; G read once (+ norm partials)
        convert_pad2_kernel<<<2 * (N_A * (KPAD / 8)) / 256 + (64 * KMLP) / 256, 256, 0, stream>>>(
            x_A, x_B, W1, xAbf, xBbf, W1tbf);
        g_convert_dual_norm_kernel<<<dim3(96, 96), 256, 0, stream>>>(G, Gbf, Gtbf, rowpart, colpart2);
        norm_final_kernel<<<24, 256, 0, stream>>>(rowpart, colpart2, normA, normB);

        // 2) both imputation GEMMs in ONE launch (bf16 out, K trimmed to 3008)
        mfma_impute2_gemm<<<dim3(KPAD / 128, N_A / 128, 2), 256, 0, stream>>>(
            xAbf, xBbf, Gtbf, Gbf, normB, normA, ximpAbf, ximpBbf);

        // 3) MLP via MFMA + K-split (clobbers rowpart/colpart2 -> consumed)
        mlp1_kernel<<<dim3(4, 128), 256, 0, stream>>>(xAbf, ximpAbf, ximpBbf, xBbf, W1tbf, mlppart);
        mlp2_kernel<<<128, 256, 0, stream>>>(mlppart, b1, W2, b2, embA, embB, sqA, sqB);

        // 4) class predictions -> d_out (one launch)
        preds2_kernel<<<880, 256, 0, stream>>>(embA, embB, WcA, bcA, WcB, bcB, outp);

        // 5) top-20: u16 key GEMMs (one launch) + select (one launch)
        distkey2_gemm<<<dim3(32, 32, 2), 256, 0, stream>>>(embA, embB, sqA, sqB, keyA, keyB);
        topk_select2<<<8192, 64, 0, stream>>>(keyA, keyB, nnA, nnB);

        // 6) fused gather-mean + MSE partials (bf16 ximp, both sides)
        predloss_bf16_kernel<<<8192, 256, 0, stream>>>(nnA, nnB, ximpBbf, ximpAbf,
                                                       x_A, x_B, partA, partB);
    } else {
        row_sum_kernel<<<G_A, 256, 0, stream>>>(G, normA);
        col_partial_kernel<<<dim3(12, 25), 256, 0, stream>>>(G, colpart);
        col_final_kernel<<<12, 256, 0, stream>>>(colpart, normB);
        dim3 ggrid(24, 32);
        impute_gemm<false><<<ggrid, 256, 0, stream>>>(x_A, G, normB, ximpA);
        impute_gemm<true><<<ggrid, 256, 0, stream>>>(x_B, G, normA, ximpB);
        mlp_kernel<<<128, 256, 0, stream>>>(x_A, ximpA, ximpB, x_B, W1, b1, W2, b2, embA, embB);
        sqnorm_kernel<<<16, 256, 0, stream>>>(embA, sqA);
        sqnorm_kernel<<<16, 256, 0, stream>>>(embB, sqB);
        preds_kernel<<<(N_A * NCA) / 256, 256, 0, stream>>>(embA, WcA, bcA, outp, NCA);
        preds_kernel<<<(N_B * NCB) / 256, 256, 0, stream>>>(embB, WcB, bcB, outp + (size_t)N_A * NCA, NCB);
        topk_all_kernel<<<4096, 128, 0, stream>>>(embA, sqA, embB, sqB, nnA, nnB);
        predloss_kernel<<<N_A, 256, 0, stream>>>(nnA, ximpB, x_A, partA);
        predloss_kernel<<<N_B, 256, 0, stream>>>(nnB, ximpA, x_B, partB);
    }

    // 7) final loss
    loss_final_kernel<<<1, 256, 0, stream>>>(partA, partB, outp + (size_t)N_A * NCA + (size_t)N_B * NCB);

    (void)in_sizes; (void)n_in; (void)out_size;
}

// Round 12
// 461.913 us; speedup vs baseline: 3.4365x; 1.0076x over previous
//
#include <hip/hip_runtime.h>
#include <cfloat>
#include <cstddef>
#include <climits>

// Problem constants
#define N_A   4096
#define N_B   4096
#define G_A   3000
#define G_B   3000
#define NCA   30
#define NCB   25
#define KNBR  20
#define KPAD  3072   // K/N padding for MFMA tiles (multiple of 128)
#define KREAL 3008   // 47*64: real K (3000) rounded up to BK; tiles beyond are all-zero
#define KMLP  6144   // padded MLP K ( = 2*KPAD )

typedef unsigned short u16;
typedef unsigned int u32;
typedef unsigned long long u64;
typedef __bf16 bf16x8 __attribute__((ext_vector_type(8)));
typedef float f32x4 __attribute__((ext_vector_type(4)));
typedef __attribute__((address_space(1))) const void* as1_cvp;
typedef __attribute__((address_space(3))) void* as3_vp;

static __device__ __forceinline__ u16 f2bf(float f) {
    union { float f; unsigned u; } v; v.f = f;
    unsigned r = v.u + 0x7fffu + ((v.u >> 16) & 1u);   // RTNE
    return (u16)(r >> 16);
}

static __device__ __forceinline__ float bf2f(u16 h) {
    union { unsigned u; float f; } v; v.u = ((unsigned)h) << 16;
    return v.f;
}

// monotonic float -> u32 key (ascending float == ascending unsigned)
static __device__ __forceinline__ u32 fkey(float f) {
    union { float f; u32 u; } v; v.f = f;
    return (v.u & 0x80000000u) ? ~v.u : (v.u | 0x80000000u);
}

// 64-lane min-reduce via DPP + broadcast (lane 63 holds global min).
static __device__ __forceinline__ u32 wave_min_u32_bcast(u32 v) {
    u32 t;
    t = (u32)__builtin_amdgcn_update_dpp((int)v, (int)v, 0x111, 0xf, 0xf, false); v = t < v ? t : v;
    t = (u32)__builtin_amdgcn_update_dpp((int)v, (int)v, 0x112, 0xf, 0xf, false); v = t < v ? t : v;
    t = (u32)__builtin_amdgcn_update_dpp((int)v, (int)v, 0x114, 0xf, 0xf, false); v = t < v ? t : v;
    t = (u32)__builtin_amdgcn_update_dpp((int)v, (int)v, 0x118, 0xf, 0xf, false); v = t < v ? t : v;
    t = (u32)__builtin_amdgcn_update_dpp((int)v, (int)v, 0x142, 0xf, 0xf, false); v = t < v ? t : v;
    t = (u32)__builtin_amdgcn_update_dpp((int)v, (int)v, 0x143, 0xf, 0xf, false); v = t < v ? t : v;
    return (u32)__builtin_amdgcn_readlane((int)v, 63);
}

// ---------------------------------------------------------------------------
// normalizers (FALLBACK path only)
__global__ __launch_bounds__(256) void row_sum_kernel(const float* __restrict__ G,
                                                      float* __restrict__ normA) {
    int row = blockIdx.x;
    __shared__ float red[256];
    float s = 0.f;
    for (int j = threadIdx.x; j < G_B; j += 256) s += G[(size_t)row * G_B + j];
    red[threadIdx.x] = s;
    __syncthreads();
    for (int off = 128; off > 0; off >>= 1) {
        if (threadIdx.x < off) red[threadIdx.x] += red[threadIdx.x + off];
        __syncthreads();
    }
    if (threadIdx.x == 0) {
        float v = red[0];
        normA[row] = (v == 0.f) ? 1.f : v;
    }
}

__global__ __launch_bounds__(256) void col_partial_kernel(const float* __restrict__ G,
                                                          float* __restrict__ part) {
    int j = blockIdx.x * 256 + threadIdx.x;
    if (j >= G_B) return;
    int r0 = blockIdx.y * 120;
    float s = 0.f;
    for (int i = r0; i < r0 + 120; ++i) s += G[(size_t)i * G_B + j];
    part[(size_t)blockIdx.y * G_B + j] = s;
}

__global__ __launch_bounds__(256) void col_final_kernel(const float* __restrict__ part,
                                                        float* __restrict__ normB) {
    int j = blockIdx.x * 256 + threadIdx.x;
    if (j >= G_B) return;
    float s = 0.f;
    for (int c = 0; c < 25; ++c) s += part[(size_t)c * G_B + j];
    normB[j] = (s == 0.f) ? 1.f : s;
}

// ---------------------------------------------------------------------------
// Merged x_A + x_B f32 -> bf16 convert (zero pad) + W1 transpose-convert.
// grid 13824: [0,6144) xA, [6144,12288) xB, [12288,13824) W1t.
__global__ __launch_bounds__(256) void convert_pad2_kernel(const float* __restrict__ xA,
                                                           const float* __restrict__ xB,
                                                           const float* __restrict__ W1,
                                                           u16* __restrict__ xAbf,
                                                           u16* __restrict__ xBbf,
                                                           u16* __restrict__ W1t) {
    const int half = (N_A * (KPAD / 8)) / 256;   // 6144 blocks per x side
    if (blockIdx.x >= 2 * half) {
        // W1 [6000][64] f32 -> W1t [64][KMLP] bf16 (seg0 k<3072, seg1 k>=3072)
        int idx = (blockIdx.x - 2 * half) * 256 + threadIdx.x;   // 0..393215
        int n = idx / KMLP, kp = idx % KMLP;
        int seg = kp >= KPAD;
        int k = kp - (seg ? KPAD : 0);
        float v = (k < 3000) ? W1[(size_t)(seg * 3000 + k) * 64 + n] : 0.f;
        W1t[(size_t)n * KMLP + kp] = f2bf(v);
        return;
    }
    const int side = blockIdx.x >= half;
    const float* in = side ? xB : xA;
    u16* out = side ? xBbf : xAbf;
    int idx = (blockIdx.x - (side ? half : 0)) * 256 + threadIdx.x;
    int cpr = KPAD >> 3;
    int r = idx / cpr, c0 = (idx % cpr) << 3;
    u16 res[8] = {0, 0, 0, 0, 0, 0, 0, 0};
    if (c0 + 8 <= G_A) {
        float4 v0 = *(const float4*)(in + (size_t)r * G_A + c0);
        float4 v1 = *(const float4*)(in + (size_t)r * G_A + c0 + 4);
        res[0] = f2bf(v0.x); res[1] = f2bf(v0.y); res[2] = f2bf(v0.z); res[3] = f2bf(v0.w);
        res[4] = f2bf(v1.x); res[5] = f2bf(v1.y); res[6] = f2bf(v1.z); res[7] = f2bf(v1.w);
    }
    uint4 pack;
    pack.x = (unsigned)res[0] | ((unsigned)res[1] << 16);
    pack.y = (unsigned)res[2] | ((unsigned)res[3] << 16);
    pack.z = (unsigned)res[4] | ((unsigned)res[5] << 16);
    pack.w = (unsigned)res[6] | ((unsigned)res[7] << 16);
    *(uint4*)(out + (size_t)r * KPAD + c0) = pack;
}

// G -> Gbf + Gt bf16 padded; ALSO per-tile partial row/col sums. G read once.
__global__ __launch_bounds__(256) void g_convert_dual_norm_kernel(const float* __restrict__ G,
                                                                  u16* __restrict__ Gbf,
                                                                  u16* __restrict__ Gt,
                                                                  float* __restrict__ rowpart,
                                                                  float* __restrict__ colpart2) {
    __shared__ float t[32][33];
    int j0 = blockIdx.x * 32, k0 = blockIdx.y * 32;
    int lx = threadIdx.x & 31, ly = threadIdx.x >> 5;
#pragma unroll
    for (int i = 0; i < 4; ++i) {
        int k = k0 + ly + i * 8, j = j0 + lx;
        float v = (k < G_A && j < G_B) ? G[(size_t)k * G_B + j] : 0.f;
        t[ly + i * 8][lx] = v;
        Gbf[(size_t)k * KPAD + j] = f2bf(v);
    }
    __syncthreads();
#pragma unroll
    for (int i = 0; i < 4; ++i) {
        int j = j0 + ly + i * 8, k = k0 + lx;
        Gt[(size_t)j * KPAD + k] = f2bf(t[lx][ly + i * 8]);
    }
    if (threadIdx.x < 32) {
        int kl = threadIdx.x;
        float s = 0.f;
#pragma unroll
        for (int j2 = 0; j2 < 32; ++j2) s += t[kl][j2];
        rowpart[(size_t)blockIdx.x * KPAD + k0 + kl] = s;
    } else if (threadIdx.x < 64) {
        int jl = threadIdx.x - 32;
        float s = 0.f;
#pragma unroll
        for (int k2 = 0; k2 < 32; ++k2) s += t[k2][jl];
        colpart2[(size_t)blockIdx.y * KPAD + j0 + jl] = s;
    }
}

// Merged normA + normB finalize. grid 24: blocks 0..11 -> A, 12..23 -> B.
__global__ __launch_bounds__(256) void norm_final_kernel(const float* __restrict__ rowpart,
                                                         const float* __restrict__ colpart2,
                                                         float* __restrict__ normA,
                                                         float* __restrict__ normB) {
    if (blockIdx.x < 12) {
        int k = blockIdx.x * 256 + threadIdx.x;
        if (k >= G_A) return;
        float s = 0.f;
        for (int jt = 0; jt < 96; ++jt) s += rowpart[(size_t)jt * KPAD + k];
        normA[k] = (s == 0.f) ? 1.f : s;
    } else {
        int j = (blockIdx.x - 12) * 256 + threadIdx.x;
        if (j >= G_B) return;
        float s = 0.f;
        for (int kt = 0; kt < 96; ++kt) s += colpart2[(size_t)kt * KPAD + j];
        normB[j] = (s == 0.f) ? 1.f : s;
    }
}

// fallback W1t
__global__ __launch_bounds__(256) void w1t_kernel(const float* __restrict__ W1,
                                                  u16* __restrict__ W1t) {
    int idx = blockIdx.x * 256 + threadIdx.x;
    int n = idx / KMLP, kp = idx % KMLP;
    int seg = kp >= KPAD;
    int k = kp - (seg ? KPAD : 0);
    float v = (k < 3000) ? W1[(size_t)(seg * 3000 + k) * 64 + n] : 0.f;
    W1t[(size_t)n * KMLP + kp] = f2bf(v);
}

// ---------------------------------------------------------------------------
// Merged bf16 MFMA imputation GEMM, both directions (linear tile mapping).
// K-loop runs to KREAL=3008 (47 tiles); tile [3008,3072) is all-zero pad.
__global__ __launch_bounds__(256) void mfma_impute2_gemm(const u16* __restrict__ xAbf,
                                                         const u16* __restrict__ xBbf,
                                                         const u16* __restrict__ Gtbf,
                                                         const u16* __restrict__ Gbf,
                                                         const float* __restrict__ normB,
                                                         const float* __restrict__ normA,
                                                         u16* __restrict__ ximpAbf,
                                                         u16* __restrict__ ximpBbf) {
    const int side = blockIdx.z;
    const u16* A  = side ? xBbf : xAbf;
    const u16* Bt = side ? Gbf : Gtbf;
    const float* norm = side ? normA : normB;
    u16* outbf = side ? ximpBbf : ximpAbf;

    const int col_base = blockIdx.x * 128;
    const int row_base = blockIdx.y * 128;

    __shared__ __align__(16) u16 lAs[128 * 64];
    __shared__ __align__(16) u16 lBs[128 * 64];

    const int tid = threadIdx.x;
    const int w = tid >> 6, lane = tid & 63;
    const int wr = (w >> 1) * 64, wc = (w & 1) * 64;

    f32x4 acc[4][4] = {};

    int s_r[4], s_off[4];
#pragma unroll
    for (int i = 0; i < 4; ++i) {
        int slin = (w * 4 + i) * 64 + lane;
        int r = slin >> 3, s = slin & 7;
        s_r[i] = r;
        s_off[i] = (s ^ (r & 7)) * 8;
    }

    for (int k0 = 0; k0 < KREAL; k0 += 64) {
#pragma unroll
        for (int i = 0; i < 4; ++i) {
            const u16* ga = A + (size_t)(row_base + s_r[i]) * KPAD + k0 + s_off[i];
            __builtin_amdgcn_global_load_lds((as1_cvp)ga,
                (as3_vp)(lAs + (size_t)(w * 4 + i) * 512), 16, 0, 0);
        }
#pragma unroll
        for (int i = 0; i < 4; ++i) {
            const u16* gb = Bt + (size_t)(col_base + s_r[i]) * KPAD + k0 + s_off[i];
            __builtin_amdgcn_global_load_lds((as1_cvp)gb,
                (as3_vp)(lBs + (size_t)(w * 4 + i) * 512), 16, 0, 0);
        }
        __syncthreads();

#pragma unroll
        for (int kk = 0; kk < 2; ++kk) {
            bf16x8 a[4], b[4];
#pragma unroll
            for (int m = 0; m < 4; ++m) {
                int row = wr + m * 16 + (lane & 15);
                int slot = (kk * 4 + (lane >> 4)) ^ (row & 7);
                a[m] = *(const bf16x8*)(lAs + row * 64 + slot * 8);
            }
#pragma unroll
            for (int n = 0; n < 4; ++n) {
                int row = wc + n * 16 + (lane & 15);
                int slot = (kk * 4 + (lane >> 4)) ^ (row & 7);
                b[n] = *(const bf16x8*)(lBs + row * 64 + slot * 8);
            }
#pragma unroll
            for (int m = 0; m < 4; ++m)
#pragma unroll
                for (int n = 0; n < 4; ++n)
                    acc[m][n] = __builtin_amdgcn_mfma_f32_16x16x32_bf16(a[m], b[n], acc[m][n], 0, 0, 0);
        }
        __syncthreads();
    }

#pragma unroll
    for (int n = 0; n < 4; ++n) {
        int col = col_base + wc + n * 16 + (lane & 15);
        bool valid = col < G_B;
        float rn = valid ? 1.0f / norm[col] : 0.f;
#pragma unroll
        for (int m = 0; m < 4; ++m) {
            int row = row_base + wr + m * 16 + (lane >> 4) * 4;
#pragma unroll
            for (int r = 0; r < 4; ++r)
                outbf[(size_t)(row + r) * KPAD + col] = f2bf(acc[m][n][r] * rn);
        }
    }
}

// ---------------------------------------------------------------------------
// MLP layer 1 (bf16 MFMA, K-split). Odd chunks trimmed to skip zero pad.
__global__ __launch_bounds__(256) void mlp1_kernel(const u16* __restrict__ xAbf,
                                                   const u16* __restrict__ ximpAbf,
                                                   const u16* __restrict__ ximpBbf,
                                                   const u16* __restrict__ xBbf,
                                                   const u16* __restrict__ W1t,
                                                   float* __restrict__ partial) {
    const int chunk = blockIdx.x;
    const int rb = blockIdx.y;
    const int side = rb >> 6;
    const int r0 = (rb & 63) * 64;
    const int seg = chunk >> 1;
    const u16* src = side ? (seg ? xBbf : ximpBbf) : (seg ? ximpAbf : xAbf);
    const int k0base = (chunk & 1) * 1536;
    const int kend = (chunk & 1) ? 1472 : 1536;

    __shared__ __align__(16) u16 lAs[64 * 64];
    __shared__ __align__(16) u16 lBs[64 * 64];

    const int tid = threadIdx.x;
    const int w = tid >> 6, lane = tid & 63;

    int s_r[2], s_off[2];
#pragma unroll
    for (int i = 0; i < 2; ++i) {
        int slin = (w * 2 + i) * 64 + lane;
        int r = slin >> 3, s = slin & 7;
        s_r[i] = r;
        s_off[i] = (s ^ (r & 7)) * 8;
    }

    f32x4 acc[4] = {};

    for (int k0 = 0; k0 < kend; k0 += 64) {
#pragma unroll
        for (int i = 0; i < 2; ++i) {
            const u16* ga = src + (size_t)(r0 + s_r[i]) * KPAD + k0base + k0 + s_off[i];
            __builtin_amdgcn_global_load_lds((as1_cvp)ga,
                (as3_vp)(lAs + (size_t)(w * 2 + i) * 512), 16, 0, 0);
        }
#pragma unroll
        for (int i = 0; i < 2; ++i) {
            const u16* gb = W1t + (size_t)s_r[i] * KMLP + chunk * 1536 + k0 + s_off[i];
            __builtin_amdgcn_global_load_lds((as1_cvp)gb,
                (as3_vp)(lBs + (size_t)(w * 2 + i) * 512), 16, 0, 0);
        }
        __syncthreads();

#pragma unroll
        for (int kk = 0; kk < 2; ++kk) {
            int arow = w * 16 + (lane & 15);
            int aslot = (kk * 4 + (lane >> 4)) ^ (arow & 7);
            bf16x8 a = *(const bf16x8*)(lAs + arow * 64 + aslot * 8);
#pragma unroll
            for (int n = 0; n < 4; ++n) {
                int brow = n * 16 + (lane & 15);
                int bslot = (kk * 4 + (lane >> 4)) ^ (brow & 7);
                bf16x8 b = *(const bf16x8*)(lBs + brow * 64 + bslot * 8);
                acc[n] = __builtin_amdgcn_mfma_f32_16x16x32_bf16(a, b, acc[n], 0, 0, 0);
            }
        }
        __syncthreads();
    }

    const size_t grow0 = (size_t)rb * 64;
#pragma unroll
    for (int n = 0; n < 4; ++n) {
        int col = n * 16 + (lane & 15);
        int rowl = w * 16 + (lane >> 4) * 4;
#pragma unroll
        for (int r = 0; r < 4; ++r)
            partial[((size_t)chunk * 8192 + grow0 + rowl + r) * 64 + col] = acc[n][r];
    }
}

// MLP reduce + layer 2 + fused sqnorm + FUSED class predictions.
__global__ __launch_bounds__(256) void mlp2_kernel(const float* __restrict__ partial,
                                                   const float* __restrict__ b1,
                                                   const float* __restrict__ W2,
                                                   const float* __restrict__ b2,
                                                   const float* __restrict__ WcA,
                                                   const float* __restrict__ bcA,
                                                   const float* __restrict__ WcB,
                                                   const float* __restrict__ bcB,
                                                   float* __restrict__ embA,
                                                   float* __restrict__ embB,
                                                   float* __restrict__ sqA,
                                                   float* __restrict__ sqB,
                                                   float* __restrict__ outp) {
    const int rb = blockIdx.x;
    const int side = rb >> 6;
    const size_t grow0 = (size_t)rb * 64;
    const int r0 = (rb & 63) * 64;
    float* emb = side ? embB : embA;
    float* sq = side ? sqB : sqA;

    __shared__ float Hs[64][65];
    __shared__ float W2s[64][32];
    const int tid = threadIdx.x;

    {
        const float4* srcw = (const float4*)W2;
        float4* dst = (float4*)&W2s[0][0];
        for (int i = tid; i < 512; i += 256) dst[i] = srcw[i];
    }

    for (int v = tid; v < 1024; v += 256) {
        int row = v >> 4, c4 = v & 15;
        float4 s = {0.f, 0.f, 0.f, 0.f};
#pragma unroll
        for (int c = 0; c < 4; ++c) {
            const float4 p = *(const float4*)(partial + ((size_t)c * 8192 + grow0 + row) * 64 + c4 * 4);
            s.x += p.x; s.y += p.y; s.z += p.z; s.w += p.w;
        }
        const float4 bb = *(const float4*)(b1 + c4 * 4);
        Hs[row][c4 * 4 + 0] = fmaxf(s.x + bb.x, 0.f);
        Hs[row][c4 * 4 + 1] = fmaxf(s.y + bb.y, 0.f);
        Hs[row][c4 * 4 + 2] = fmaxf(s.z + bb.z, 0.f);
        Hs[row][c4 * 4 + 3] = fmaxf(s.w + bb.w, 0.f);
    }
    __syncthreads();

    const int c2 = tid & 31, rg = tid >> 5;
    float acc2[8] = {};
    for (int k = 0; k < 64; ++k) {
        float wv = W2s[k][c2];
#pragma unroll
        for (int i = 0; i < 8; ++i) acc2[i] += Hs[rg * 8 + i][k] * wv;
    }
    float bb = b2[c2];
    float e[8];
#pragma unroll
    for (int i = 0; i < 8; ++i) {
        e[i] = fmaxf(acc2[i] + bb, 0.f);
        emb[(size_t)(r0 + rg * 8 + i) * 32 + c2] = e[i];
    }
#pragma unroll
    for (int i = 0; i < 8; ++i) {
        float v = e[i] * e[i];
#pragma unroll
        for (int off = 16; off > 0; off >>= 1) v += __shfl_xor(v, off, 32);
        if (c2 == 0) sq[r0 + rg * 8 + i] = v;
    }

    // ---- fused class predictions: stash emb block (64x32) into Hs, then
    // compute x_preds for these 64 rows (Hs reads from layer 2 are all done).
    __syncthreads();
#pragma unroll
    for (int i = 0; i < 8; ++i) Hs[rg * 8 + i][c2] = e[i];
    __syncthreads();

    const float* Wc = side ? WcB : WcA;
    const float* bc = side ? bcB : bcA;
    const int ncls = side ? NCB : NCA;
    float* po = outp + (side ? (size_t)N_A * NCA : 0) + (size_t)r0 * ncls;
    const int tot = 64 * ncls;
    for (int idx = tid; idx < tot; idx += 256) {
        int row = idx / ncls, c = idx % ncls;
        float s = bc[c];
#pragma unroll
        for (int k = 0; k < 32; ++k) s += Hs[row][k] * Wc[k * ncls + c];
        po[idx] = s;
    }
}

// ---------------------------------------------------------------------------
// Fallback f32 GEMM
template <bool TRANSB>
__global__ __launch_bounds__(256) void impute_gemm(const float* __restrict__ X,
                                                   const float* __restrict__ G,
                                                   const float* __restrict__ norm,
                                                   float* __restrict__ out) {
    __shared__ float As[8][128];
    __shared__ float Bs[8][128];
    const int tid = threadIdx.x;
    const int col_base = blockIdx.x * 128;
    const int row_base = blockIdx.y * 128;
    const int tx = tid & 15;
    const int ty = tid >> 4;
    float acc[8][8] = {};
    const int a_row = tid >> 1;
    const int a_k   = (tid & 1) * 4;
    for (int k0 = 0; k0 < G_B; k0 += 8) {
        {
            float4 av = *(const float4*)(X + (size_t)(row_base + a_row) * G_B + k0 + a_k);
            As[a_k + 0][a_row] = av.x;
            As[a_k + 1][a_row] = av.y;
            As[a_k + 2][a_row] = av.z;
            As[a_k + 3][a_row] = av.w;
        }
        if (!TRANSB) {
            const int bk = tid >> 5;
            const int bc = (tid & 31) * 4;
            float4 bv = {0.f, 0.f, 0.f, 0.f};
            if (col_base + bc < G_B)
                bv = *(const float4*)(G + (size_t)(k0 + bk) * G_B + col_base + bc);
            *(float4*)&Bs[bk][bc] = bv;
        } else {
            const int bj = tid >> 1;
            const int bk = (tid & 1) * 4;
            float4 bv = {0.f, 0.f, 0.f, 0.f};
            if (col_base + bj < G_B)
                bv = *(const float4*)(G + (size_t)(col_base + bj) * G_B + k0 + bk);
            Bs[bk + 0][bj] = bv.x;
            Bs[bk + 1][bj] = bv.y;
            Bs[bk + 2][bj] = bv.z;
            Bs[bk + 3][bj] = bv.w;
        }
        __syncthreads();
#pragma unroll
        for (int kk = 0; kk < 8; ++kk) {
            float4 a0 = *(const float4*)&As[kk][ty * 8];
            float4 a1 = *(const float4*)&As[kk][ty * 8 + 4];
            float4 b0 = *(const float4*)&Bs[kk][tx * 8];
            float4 b1 = *(const float4*)&Bs[kk][tx * 8 + 4];
            float a_[8] = {a0.x, a0.y, a0.z, a0.w, a1.x, a1.y, a1.z, a1.w};
            float b_[8] = {b0.x, b0.y, b0.z, b0.w, b1.x, b1.y, b1.z, b1.w};
#pragma unroll
            for (int i = 0; i < 8; ++i)
#pragma unroll
                for (int j = 0; j < 8; ++j) acc[i][j] += a_[i] * b_[j];
        }
        __syncthreads();
    }
    const int cg = col_base + tx * 8;
    if (cg < G_B) {
        float rn[8];
#pragma unroll
        for (int j = 0; j < 8; ++j) rn[j] = 1.0f / norm[cg + j];
#pragma unroll
        for (int i = 0; i < 8; ++i) {
            float4 o0 = {acc[i][0] * rn[0], acc[i][1] * rn[1], acc[i][2] * rn[2], acc[i][3] * rn[3]};
            float4 o1 = {acc[i][4] * rn[4], acc[i][5] * rn[5], acc[i][6] * rn[6], acc[i][7] * rn[7]};
            size_t o = (size_t)(row_base + ty * 8 + i) * G_B + cg;
            *(float4*)(out + o) = o0;
            *(float4*)(out + o + 4) = o1;
        }
    }
}

// Fallback MLP (f32)
#define MLP_TK 24
__global__ __launch_bounds__(256) void mlp_kernel(const float* __restrict__ xA,
                                                  const float* __restrict__ ximpA,
                                                  const float* __restrict__ ximpB,
                                                  const float* __restrict__ xB,
                                                  const float* __restrict__ W1,
                                                  const float* __restrict__ b1,
                                                  const float* __restrict__ W2,
                                                  const float* __restrict__ b2,
                                                  float* __restrict__ embA,
                                                  float* __restrict__ embB) {
    __shared__ float Xs[MLP_TK][64];
    __shared__ float Ws[MLP_TK][64];
    __shared__ float Hs[64][65];
    __shared__ float W2s[64][32];

    const int side = blockIdx.x >> 6;
    const int row0 = (blockIdx.x & 63) * 64;
    const float* srcL = side ? ximpB : xA;
    const float* srcR = side ? xB : ximpA;
    float* emb = side ? embB : embA;

    const int tid = threadIdx.x;
    {
        const float4* src = (const float4*)W2;
        float4* dst = (float4*)&W2s[0][0];
        for (int i = tid; i < 512; i += 256) dst[i] = src[i];
    }

    const int tx = tid & 15;
    const int ty = tid >> 4;
    float acc[4][4] = {};
    const int lrow = tid >> 2;
    const int lk6  = (tid & 3) * 6;

    for (int k0 = 0; k0 < 6000; k0 += MLP_TK) {
        const float* src = (k0 < 3000) ? srcL : srcR;
        const int kbase = (k0 < 3000) ? k0 : (k0 - 3000);
        {
            const float* p = src + (size_t)(row0 + lrow) * 3000 + kbase + lk6;
#pragma unroll
            for (int e = 0; e < 6; ++e) Xs[lk6 + e][lrow] = p[e];
        }
        {
#pragma unroll
            for (int e = 0; e < 6; ++e) {
                int idx = tid * 6 + e;
                int kk = idx >> 6, cc = idx & 63;
                Ws[kk][cc] = W1[(size_t)(k0 + kk) * 64 + cc];
            }
        }
        __syncthreads();
#pragma unroll
        for (int kk = 0; kk < MLP_TK; ++kk) {
            float4 a = *(const float4*)&Xs[kk][ty * 4];
            float4 wv = *(const float4*)&Ws[kk][tx * 4];
            float a_[4] = {a.x, a.y, a.z, a.w};
            float w_[4] = {wv.x, wv.y, wv.z, wv.w};
#pragma unroll
            for (int i = 0; i < 4; ++i)
#pragma unroll
                for (int j = 0; j < 4; ++j) acc[i][j] += a_[i] * w_[j];
        }
        __syncthreads();
    }

#pragma unroll
    for (int j = 0; j < 4; ++j) {
        float bj = b1[tx * 4 + j];
#pragma unroll
        for (int i = 0; i < 4; ++i) {
            float h = acc[i][j] + bj;
            Hs[ty * 4 + i][tx * 4 + j] = h > 0.f ? h : 0.f;
        }
    }
    __syncthreads();

    const int c2 = tid & 31;
    const int rg = tid >> 5;
    float acc2[8] = {};
    for (int k = 0; k < 64; ++k) {
        float wv = W2s[k][c2];
#pragma unroll
        for (int i = 0; i < 8; ++i) acc2[i] += Hs[rg * 8 + i][k] * wv;
    }
    float bb = b2[c2];
#pragma unroll
    for (int i = 0; i < 8; ++i) {
        float h = acc2[i] + bb;
        emb[(size_t)(row0 + rg * 8 + i) * 32 + c2] = h > 0.f ? h : 0.f;
    }
}

__global__ __launch_bounds__(256) void sqnorm_kernel(const float* __restrict__ emb,
                                                     float* __restrict__ sq) {
    int i = blockIdx.x * 256 + threadIdx.x;
    if (i >= N_A) return;
    const float4* e = (const float4*)(emb + (size_t)i * 32);
    float s = 0.f;
#pragma unroll
    for (int q = 0; q < 8; ++q) {
        float4 v = e[q];
        s += v.x * v.x + v.y * v.y + v.z * v.z + v.w * v.w;
    }
    sq[i] = s;
}

// fallback single-side preds
__global__ __launch_bounds__(256) void preds_kernel(const float* __restrict__ emb,
                                                    const float* __restrict__ Wc,
                                                    const float* __restrict__ bc,
                                                    float* __restrict__ out,
                                                    int ncls) {
    int idx = blockIdx.x * 256 + threadIdx.x;
    int row = idx / ncls, c = idx % ncls;
    const float* e = emb + (size_t)row * 32;
    float s = bc[c];
#pragma unroll
    for (int k = 0; k < 32; ++k) s += e[k] * Wc[k * ncls + c];
    out[idx] = s;
}

// ---------------------------------------------------------------------------
// Distance-key GEMM, both directions, u16 keys (top 16 bits of fkey).
__global__ __launch_bounds__(256) void distkey2_gemm(const float* __restrict__ embA,
                                                     const float* __restrict__ embB,
                                                     const float* __restrict__ sqA,
                                                     const float* __restrict__ sqB,
                                                     u16* __restrict__ keyA,
                                                     u16* __restrict__ keyB) {
    const int side = blockIdx.z;
    const float* embQ = side ? embB : embA;
    const float* embC = side ? embA : embB;
    const float* sqC = side ? sqA : sqB;
    u16* keys = side ? keyB : keyA;

    __shared__ float As[32][132];
    __shared__ float Bs[32][132];

    const int tid = threadIdx.x;
    const int row_base = blockIdx.y * 128;
    const int col_base = blockIdx.x * 128;

#pragma unroll
    for (int i = 0; i < 4; ++i) {
        int idx = i * 256 + tid;
        int row = idx >> 3, k4 = (idx & 7) * 4;
        float4 a = *(const float4*)(embQ + (size_t)(row_base + row) * 32 + k4);
        As[k4 + 0][row] = a.x;
        As[k4 + 1][row] = a.y;
        As[k4 + 2][row] = a.z;
        As[k4 + 3][row] = a.w;
        float4 b = *(const float4*)(embC + (size_t)(col_base + row) * 32 + k4);
        Bs[k4 + 0][row] = b.x;
        Bs[k4 + 1][row] = b.y;
        Bs[k4 + 2][row] = b.z;
        Bs[k4 + 3][row] = b.w;
    }
    __syncthreads();

    const int tx = tid & 15, ty = tid >> 4;
    float acc[8][8] = {};
#pragma unroll
    for (int k = 0; k < 32; ++k) {
        float4 a0 = *(const float4*)&As[k][ty * 8];
        float4 a1 = *(const float4*)&As[k][ty * 8 + 4];
        float4 b0 = *(const float4*)&Bs[k][tx * 8];
        float4 b1 = *(const float4*)&Bs[k][tx * 8 + 4];
        float a_[8] = {a0.x, a0.y, a0.z, a0.w, a1.x, a1.y, a1.z, a1.w};
        float b_[8] = {b0.x, b0.y, b0.z, b0.w, b1.x, b1.y, b1.z, b1.w};
#pragma unroll
        for (int i = 0; i < 8; ++i)
#pragma unroll
            for (int j = 0; j < 8; ++j) acc[i][j] += a_[i] * b_[j];
    }

    const int cg = col_base + tx * 8;
    float sc[8];
#pragma unroll
    for (int j = 0; j < 8; ++j) sc[j] = sqC[cg + j];
#pragma unroll
    for (int i = 0; i < 8; ++i) {
        u32 k16[8];
#pragma unroll
        for (int j = 0; j < 8; ++j) k16[j] = fkey(sc[j] - 2.f * acc[i][j]) >> 16;
        uint4 o;
        o.x = k16[0] | (k16[1] << 16);
        o.y = k16[2] | (k16[3] << 16);
        o.z = k16[4] | (k16[5] << 16);
        o.w = k16[6] | (k16[7] << 16);
        *(uint4*)(keys + (size_t)(row_base + ty * 8 + i) * 4096 + cg) = o;
    }
}

// Per-query top-20 from u16 key row; composites (k16<<12)|j make ties exact.
__global__ __launch_bounds__(64) void topk_select2(const u16* __restrict__ keyA,
                                                   const u16* __restrict__ keyB,
                                                   int* __restrict__ nnA,
                                                   int* __restrict__ nnB) {
    const int side = blockIdx.x >> 12;
    const int q = blockIdx.x & 4095;
    const u16* krow = (side ? keyB : keyA) + (size_t)q * 4096;
    int* nn = (side ? nnB : nnA) + (size_t)q * KNBR;

    __shared__ u32 kbuf[64 * 68];
    const int lane = threadIdx.x;

#pragma unroll
    for (int t = 0; t < 16; ++t) {
        int j0 = t * 256 + lane * 4;
        uint2 pk = *(const uint2*)(krow + j0);
        int g = j0 >> 6, idx = j0 & 63;
        u32* dst = &kbuf[g * 68 + idx];
        dst[0] = ((pk.x & 0xFFFFu) << 12) | (u32)(j0 + 0);
        dst[1] = ((pk.x >> 16) << 12) | (u32)(j0 + 1);
        dst[2] = ((pk.y & 0xFFFFu) << 12) | (u32)(j0 + 2);
        dst[3] = ((pk.y >> 16) << 12) | (u32)(j0 + 3);
    }

    volatile u32* kq = (volatile u32*)kbuf;

    u32 l1;
    {
        const int base = lane * 68;
        u32 m0 = 0xFFFFFFFFu, m1 = 0xFFFFFFFFu, m2 = 0xFFFFFFFFu, m3 = 0xFFFFFFFFu;
#pragma unroll
        for (int t = 0; t < 64; t += 4) {
            u32 a = kq[base + t + 0];
            u32 b = kq[base + t + 1];
            u32 c = kq[base + t + 2];
            u32 d = kq[base + t + 3];
            m0 = a < m0 ? a : m0;
            m1 = b < m1 ? b : m1;
            m2 = c < m2 ? c : m2;
            m3 = d < m3 ? d : m3;
        }
        m0 = m1 < m0 ? m1 : m0;
        m2 = m3 < m2 ? m3 : m2;
        l1 = m2 < m0 ? m2 : m0;
    }

    int myj = 0;
    for (int r = 0; r < KNBR; ++r) {
        u32 m = wave_min_u32_bcast(l1);
        u64 gmask = __ballot(l1 == m);
        int g = __builtin_ctzll(gmask);
        u32 v = kq[g * 68 + lane];
        u64 wmask = __ballot(v == m);
        int jl = __builtin_ctzll(wmask);
        if (lane == jl) kq[g * 68 + jl] = 0xFFFFFFFFu;
        u32 v2 = (lane == jl) ? 0xFFFFFFFFu : v;
        u32 nm = wave_min_u32_bcast(v2);
        if (lane == g) l1 = nm;
        if (lane == r) myj = (int)(m & 0xFFFu);
    }
    if (lane < KNBR) nn[lane] = myj;
}

// Fallback (round-6) fused topk for the non-MFMA path.
__global__ __launch_bounds__(128) void topk_all_kernel(const float* __restrict__ embA,
                                                       const float* __restrict__ sqA,
                                                       const float* __restrict__ embB,
                                                       const float* __restrict__ sqB,
                                                       int* __restrict__ nnA,
                                                       int* __restrict__ nnB) {
    const int side = blockIdx.x >> 11;
    const int q0 = (blockIdx.x & 2047) * 2;
    const float* embQ = side ? embB : embA;
    const float* embC = side ? embA : embB;
    const float* sqCc = side ? sqA : sqB;
    int* nnOut = side ? nnB : nnA;

    __shared__ u32 keys[2][64 * 65];

    const int tid = threadIdx.x;
    const int lane = tid & 63, w = tid >> 6;

    float4 q0v[8], q1v[8];
    {
        const float4* e0 = (const float4*)(embQ + (size_t)q0 * 32);
        const float4* e1 = (const float4*)(embQ + (size_t)(q0 + 1) * 32);
#pragma unroll
        for (int c = 0; c < 8; ++c) { q0v[c] = e0[c]; q1v[c] = e1[c]; }
    }

    for (int i = 0; i < 32; ++i) {
        int j = (i << 7) + tid;
        const float4* ec = (const float4*)(embC + (size_t)j * 32);
        float d0 = 0.f, d1 = 0.f;
#pragma unroll
        for (int c = 0; c < 8; ++c) {
            float4 cv = ec[c];
            d0 += q0v[c].x * cv.x + q0v[c].y * cv.y + q0v[c].z * cv.z + q0v[c].w * cv.w;
            d1 += q1v[c].x * cv.x + q1v[c].y * cv.y + q1v[c].z * cv.z + q1v[c].w * cv.w;
        }
        float sc = sqCc[j];
        int off = (j >> 6) * 65 + (j & 63);
        keys[0][off] = fkey(sc - 2.f * d0);
        keys[1][off] = fkey(sc - 2.f * d1);
    }
    __syncthreads();

    volatile u32* kq = (volatile u32*)&keys[w][0];

    u32 l1;
    {
        const int base = lane * 65;
        u32 m0 = 0xFFFFFFFFu, m1 = 0xFFFFFFFFu, m2 = 0xFFFFFFFFu, m3 = 0xFFFFFFFFu;
#pragma unroll
        for (int t = 0; t < 64; t += 4) {
            u32 a = kq[base + t + 0];
            u32 b = kq[base + t + 1];
            u32 c = kq[base + t + 2];
            u32 d = kq[base + t + 3];
            m0 = a < m0 ? a : m0;
            m1 = b < m1 ? b : m1;
            m2 = c < m2 ? c : m2;
            m3 = d < m3 ? d : m3;
        }
        m0 = m1 < m0 ? m1 : m0;
        m2 = m3 < m2 ? m3 : m2;
        l1 = m2 < m0 ? m2 : m0;
    }

    int myj = 0;
    for (int r = 0; r < KNBR; ++r) {
        u32 m = wave_min_u32_bcast(l1);
        u64 gmask = __ballot(l1 == m);
        int g = __builtin_ctzll(gmask);
        u32 v = kq[g * 65 + lane];
        u64 wmask = __ballot(v == m);
        int jl = __builtin_ctzll(wmask);
        if (lane == jl) kq[g * 65 + jl] = 0xFFFFFFFFu;
        u32 v2 = (lane == jl) ? 0xFFFFFFFFu : v;
        u32 nm = wave_min_u32_bcast(v2);
        if (lane == g) l1 = nm;
        if (lane == r) myj = (g << 6) | jl;
    }
    if (lane < KNBR) nnOut[(size_t)(q0 + w) * KNBR + lane] = myj;
}

// ---------------------------------------------------------------------------
// Fused gather-mean + MSE partials, bf16 ximp, both sides in one launch.
__global__ __launch_bounds__(256) void predloss_bf16_kernel(const int* __restrict__ nnA,
                                                            const int* __restrict__ nnB,
                                                            const u16* __restrict__ ximpBbf,
                                                            const u16* __restrict__ ximpAbf,
                                                            const float* __restrict__ xA,
                                                            const float* __restrict__ xB,
                                                            float* __restrict__ partA,
                                                            float* __restrict__ partB) {
    const int side = blockIdx.x >> 12;
    const int q = blockIdx.x & 4095;
    const int* nn = (side ? nnB : nnA) + (size_t)q * KNBR;
    const u16* ximp = side ? ximpAbf : ximpBbf;
    const float* xtrue = (side ? xB : xA) + (size_t)q * 3000;
    float* partial = side ? partB : partA;

    __shared__ int nns[KNBR];
    __shared__ float red[256];
    if (threadIdx.x < KNBR) nns[threadIdx.x] = nn[threadIdx.x];
    __syncthreads();

    int nr[KNBR];
#pragma unroll
    for (int t = 0; t < KNBR; ++t) nr[t] = nns[t];

    const float inv = 1.0f / KNBR;
    float sse = 0.f;
    for (int v = threadIdx.x; v < 375; v += 256) {
        float acc[8] = {};
#pragma unroll
        for (int t = 0; t < KNBR; ++t) {
            uint4 pk = *(const uint4*)(ximp + (size_t)nr[t] * KPAD + v * 8);
            acc[0] += bf2f((u16)(pk.x & 0xFFFF));
            acc[1] += bf2f((u16)(pk.x >> 16));
            acc[2] += bf2f((u16)(pk.y & 0xFFFF));
            acc[3] += bf2f((u16)(pk.y >> 16));
            acc[4] += bf2f((u16)(pk.z & 0xFFFF));
            acc[5] += bf2f((u16)(pk.z >> 16));
            acc[6] += bf2f((u16)(pk.w & 0xFFFF));
            acc[7] += bf2f((u16)(pk.w >> 16));
        }
        const float4 x0 = *(const float4*)(xtrue + v * 8);
        const float4 x1 = *(const float4*)(xtrue + v * 8 + 4);
        float d0 = acc[0] * inv - x0.x;
        float d1 = acc[1] * inv - x0.y;
        float d2 = acc[2] * inv - x0.z;
        float d3 = acc[3] * inv - x0.w;
        float d4 = acc[4] * inv - x1.x;
        float d5 = acc[5] * inv - x1.y;
        float d6 = acc[6] * inv - x1.z;
        float d7 = acc[7] * inv - x1.w;
        sse += d0 * d0 + d1 * d1 + d2 * d2 + d3 * d3
             + d4 * d4 + d5 * d5 + d6 * d6 + d7 * d7;
    }
    red[threadIdx.x] = sse;
    __syncthreads();
    for (int off = 128; off > 0; off >>= 1) {
        if (threadIdx.x < off) red[threadIdx.x] += red[threadIdx.x + off];
        __syncthreads();
    }
    if (threadIdx.x == 0) partial[q] = red[0];
}

// Fallback f32 predloss
__global__ __launch_bounds__(256) void predloss_kernel(const int* __restrict__ nn,
                                                       const float* __restrict__ ximp,
                                                       const float* __restrict__ xtrue,
                                                       float* __restrict__ partial) {
    int q = blockIdx.x;
    __shared__ int nns[KNBR];
    __shared__ float red[256];
    if (threadIdx.x < KNBR) nns[threadIdx.x] = nn[(size_t)q * KNBR + threadIdx.x];
    __syncthreads();

    int nr[KNBR];
#pragma unroll
    for (int t = 0; t < KNBR; ++t) nr[t] = nns[t];

    const float inv = 1.0f / KNBR;
    float sse = 0.f;
    for (int v = threadIdx.x; v < 750; v += 256) {
        float4 acc = {0.f, 0.f, 0.f, 0.f};
#pragma unroll
        for (int t = 0; t < KNBR; ++t) {
            const float4 w = *(const float4*)(ximp + (size_t)nr[t] * 3000 + v * 4);
            acc.x += w.x; acc.y += w.y; acc.z += w.z; acc.w += w.w;
        }
        const float4 xt = *(const float4*)(xtrue + (size_t)q * 3000 + v * 4);
        float dx = acc.x * inv - xt.x;
        float dy = acc.y * inv - xt.y;
        float dz = acc.z * inv - xt.z;
        float dw = acc.w * inv - xt.w;
        sse += dx * dx + dy * dy + dz * dz + dw * dw;
    }
    red[threadIdx.x] = sse;
    __syncthreads();
    for (int off = 128; off > 0; off >>= 1) {
        if (threadIdx.x < off) red[threadIdx.x] += red[threadIdx.x + off];
        __syncthreads();
    }
    if (threadIdx.x == 0) partial[q] = red[0];
}

__global__ __launch_bounds__(256) void loss_final_kernel(const float* __restrict__ pA,
                                                         const float* __restrict__ pB,
                                                         float* __restrict__ out) {
    __shared__ double red[256];
    double sa = 0.0, sb = 0.0;
    for (int i = threadIdx.x; i < 4096; i += 256) {
        sa += (double)pA[i];
        sb += (double)pB[i];
    }
    red[threadIdx.x] = sa;
    __syncthreads();
    for (int off = 128; off > 0; off >>= 1) {
        if (threadIdx.x < off) red[threadIdx.x] += red[threadIdx.x + off];
        __syncthreads();
    }
    double totA = red[0];
    __syncthreads();
    red[threadIdx.x] = sb;
    __syncthreads();
    for (int off = 128; off > 0; off >>= 1) {
        if (threadIdx.x < off) red[threadIdx.x] += red[threadIdx.x + off];
        __syncthreads();
    }
    if (threadIdx.x == 0) {
        double denom = 4096.0 * 3000.0;
        out[0] = (float)(totA / denom + red[0] / denom);
    }
}

// ---------------------------------------------------------------------------
extern "C" void kernel_launch(void* const* d_in, const int* in_sizes, int n_in,
                              void* d_out, int out_size, void* d_ws, size_t ws_size,
                              hipStream_t stream) {
    const float* x_A = (const float*)d_in[0];
    const float* x_B = (const float*)d_in[1];
    const float* G   = (const float*)d_in[2];
    const float* W1  = (const float*)d_in[3];
    const float* b1  = (const float*)d_in[4];
    const float* W2  = (const float*)d_in[5];
    const float* b2  = (const float*)d_in[6];
    const float* WcA = (const float*)d_in[7];
    const float* bcA = (const float*)d_in[8];
    const float* WcB = (const float*)d_in[9];
    const float* bcB = (const float*)d_in[10];

    float* outp = (float*)d_out;

    size_t off = 0;
    char* base = (char*)d_ws;
    auto carve = [&](size_t bytes) -> void* {
        void* p = base + off;
        off = (off + bytes + 255) & ~(size_t)255;
        return p;
    };
    // f32 ximp: FALLBACK path only; on bf16 path this region hosts keyA (u16).
    float* ximpA = (float*)carve((size_t)N_A * G_B * 4);
    float* ximpB = (float*)carve((size_t)N_B * G_A * 4);
    float* normA = (float*)carve(G_A * 4);
    float* normB = (float*)carve(G_B * 4);
    float* colpart = (float*)carve(25 * G_B * 4);
    float* embA = (float*)carve((size_t)N_A * 32 * 4);
    float* embB = (float*)carve((size_t)N_B * 32 * 4);
    float* sqA = (float*)carve(N_A * 4);
    float* sqB = (float*)carve(N_B * 4);
    float* partA = (float*)carve(N_A * 4);
    float* partB = (float*)carve(N_B * 4);
    int* nnA = (int*)carve((size_t)N_A * KNBR * 4);
    int* nnB = (int*)carve((size_t)N_B * KNBR * 4);
    u16* xAbf = (u16*)carve((size_t)N_A * KPAD * 2);   // region start for keyB alias
    u16* xBbf = (u16*)carve((size_t)N_B * KPAD * 2);
    u16* Gbf  = (u16*)carve((size_t)KPAD * KPAD * 2);
    u16* Gtbf = (u16*)carve((size_t)KPAD * KPAD * 2);
    u16* ximpAbf = (u16*)carve((size_t)N_A * KPAD * 2);   // live until predloss
    u16* ximpBbf = (u16*)carve((size_t)N_B * KPAD * 2);   // live until predloss
    u16* W1tbf   = (u16*)carve((size_t)64 * KMLP * 2);
    float* mlppart = (float*)carve((size_t)4 * 8192 * 64 * 4);
    size_t full_needed = off;

    // Aliases (bf16 path only):
    // keyA (33.5 MB u16) over dead f32 ximpA/ximpB (98.4 MB).
    // keyB (33.5 MB u16) over dead xAbf..Gtbf (88.1 MB, dead after mlp1).
    // norm partials (2 x 1.2 MB) over mlppart (written later by mlp1).
    u16* keyA = (u16*)ximpA;
    u16* keyB = (u16*)xAbf;
    float* rowpart  = mlppart;                    // [96][KPAD]
    float* colpart2 = mlppart + 96 * KPAD;        // [96][KPAD]

    const bool use_mfma = (ws_size >= full_needed);

    if (use_mfma) {
        // 1) bf16 conversions; x + W1t in one launch; G read once (+ norm partials)
        convert_pad2_kernel<<<2 * (N_A * (KPAD / 8)) / 256 + (64 * KMLP) / 256, 256, 0, stream>>>(
            x_A, x_B, W1, xAbf, xBbf, W1tbf);
        g_convert_dual_norm_kernel<<<dim3(96, 96), 256, 0, stream>>>(G, Gbf, Gtbf, rowpart, colpart2);
        norm_final_kernel<<<24, 256, 0, stream>>>(rowpart, colpart2, normA, normB);

        // 2) both imputation GEMMs in ONE launch (bf16 out, K trimmed to 3008)
        mfma_impute2_gemm<<<dim3(KPAD / 128, N_A / 128, 2), 256, 0, stream>>>(
            xAbf, xBbf, Gtbf, Gbf, normB, normA, ximpAbf, ximpBbf);

        // 3) MLP via MFMA + K-split; mlp2 fuses layer2 + sqnorm + class preds
        mlp1_kernel<<<dim3(4, 128), 256, 0, stream>>>(xAbf, ximpAbf, ximpBbf, xBbf, W1tbf, mlppart);
        mlp2_kernel<<<128, 256, 0, stream>>>(mlppart, b1, W2, b2, WcA, bcA, WcB, bcB,
                                             embA, embB, sqA, sqB, outp);

        // 4) top-20: u16 key GEMMs (one launch) + select (one launch)
        distkey2_gemm<<<dim3(32, 32, 2), 256, 0, stream>>>(embA, embB, sqA, sqB, keyA, keyB);
        topk_select2<<<8192, 64, 0, stream>>>(keyA, keyB, nnA, nnB);

        // 5) fused gather-mean + MSE partials (bf16 ximp, both sides)
        predloss_bf16_kernel<<<8192, 256, 0, stream>>>(nnA, nnB, ximpBbf, ximpAbf,
                                                       x_A, x_B, partA, partB);
    } else {
        row_sum_kernel<<<G_A, 256, 0, stream>>>(G, normA);
        col_partial_kernel<<<dim3(12, 25), 256, 0, stream>>>(G, colpart);
        col_final_kernel<<<12, 256, 0, stream>>>(colpart, normB);
        dim3 ggrid(24, 32);
        impute_gemm<false><<<ggrid, 256, 0, stream>>>(x_A, G, normB, ximpA);
        impute_gemm<true><<<ggrid, 256, 0, stream>>>(x_B, G, normA, ximpB);
        mlp_kernel<<<128, 256, 0, stream>>>(x_A, ximpA, ximpB, x_B, W1, b1, W2, b2, embA, embB);
        sqnorm_kernel<<<16, 256, 0, stream>>>(embA, sqA);
        sqnorm_kernel<<<16, 256, 0, stream>>>(embB, sqB);
        preds_kernel<<<(N_A * NCA) / 256, 256, 0, stream>>>(embA, WcA, bcA, outp, NCA);
        preds_kernel<<<(N_B * NCB) / 256, 256, 0, stream>>>(embB, WcB, bcB, outp + (size_t)N_A * NCA, NCB);
        topk_all_kernel<<<4096, 128, 0, stream>>>(embA, sqA, embB, sqB, nnA, nnB);
        predloss_kernel<<<N_A, 256, 0, stream>>>(nnA, ximpB, x_A, partA);
        predloss_kernel<<<N_B, 256, 0, stream>>>(nnB, ximpA, x_B, partB);
    }

    // 6) final loss
    loss_final_kernel<<<1, 256, 0, stream>>>(partA, partB, outp + (size_t)N_A * NCA + (size_t)N_B * NCB);

    (void)in_sizes; (void)n_in; (void)out_size;
}